// Round 8
// baseline (304.533 us; speedup 1.0000x reference)
//
#include <hip/hip_runtime.h>
#include <math.h>

#define SF 16
#define ED 32
#define LTOK 20
#define DIN 176
#define KP1 192   // DIN padded to multiple of 32
#define HC 128

typedef _Float16 f16x8 __attribute__((ext_vector_type(8)));
typedef float f32x4 __attribute__((ext_vector_type(4)));

static __device__ __forceinline__ float leaky02(float x) { return x >= 0.f ? x : 0.2f * x; }
static __device__ __forceinline__ float eluf(float x)    { return x > 0.f ? x : expm1f(x); }
static __device__ __forceinline__ unsigned short f2h(float f)
{
  _Float16 h = (_Float16)f;
  return __builtin_bit_cast(unsigned short, h);
}
static __device__ __forceinline__ float h2f(unsigned short u)
{
  return (float)__builtin_bit_cast(_Float16, u);
}
static __device__ __forceinline__ float readlane_f(float v, int j)
{
  return __int_as_float(__builtin_amdgcn_readlane(__float_as_int(v), j));
}

// ---------- 0a. pack W [K][Nc] fp32 -> Wt [Nc][KPad] f16 (zero pad) ----------
__global__ void pack_wt_kernel(const float* __restrict__ W, unsigned short* __restrict__ Wt,
                               int K, int Nc, int KPad)
{
  int i = blockIdx.x * blockDim.x + threadIdx.x;
  if (i < Nc * KPad) {
    int n = i / KPad;
    int k = i - n * KPad;
    float v = (k < K) ? W[(size_t)k * Nc + n] : 0.f;
    Wt[i] = f2h(v);
  }
}

// ---------- 0b. v_s[k][h] = sum_c W1[k][h*128+c]*a_s[h][c] (and v_d) ----------
__global__ __launch_bounds__(256)
void prep_attn_kernel(const float* __restrict__ W1, const float* __restrict__ as1,
                      const float* __restrict__ ad1,
                      float* __restrict__ vs, float* __restrict__ vd)
{
  int k = blockIdx.x;                 // 0..175
  int h = threadIdx.x >> 6, lane = threadIdx.x & 63;
  const float* row = W1 + (size_t)k * 512 + h * HC;
  float s = row[lane] * as1[h * HC + lane] + row[lane + 64] * as1[h * HC + lane + 64];
  float d = row[lane] * ad1[h * HC + lane] + row[lane + 64] * ad1[h * HC + lane + 64];
  #pragma unroll
  for (int off = 32; off; off >>= 1) { s += __shfl_down(s, off); d += __shfl_down(d, off); }
  if (lane == 0) { vs[k * 4 + h] = s; vd[k * 4 + h] = d; }
}

// ---------- 1. features + LayerNorm + fused logits; ONE WAVE PER NODE ----------
__global__ __launch_bounds__(256)
void feat_ln_kernel(const float* __restrict__ xs,
                    const int* __restrict__ i0, const int* __restrict__ i1,
                    const int* __restrict__ i2, const int* __restrict__ i3,
                    const int* __restrict__ i4,
                    const float* __restrict__ e0, const float* __restrict__ e1,
                    const float* __restrict__ e2, const float* __restrict__ e3,
                    const float* __restrict__ e4,
                    const float* __restrict__ g, const float* __restrict__ b,
                    const float4* __restrict__ vs, const float4* __restrict__ vd,
                    unsigned short* __restrict__ out,
                    float* __restrict__ als, float* __restrict__ ald, int N)
{
  __shared__ int toks[4][5 * LTOK];
  int w = threadIdx.x >> 6, l = threadIdx.x & 63;
  int n = blockIdx.x * 4 + w;
  if (n >= N) return;

  for (int q = l; q < 5 * LTOK; q += 64) {
    int f = q / LTOK, j = q - f * LTOK;
    const int* ip = (f == 0) ? i0 : (f == 1) ? i1 : (f == 2) ? i2 : (f == 3) ? i3 : i4;
    toks[w][q] = ip[n * LTOK + j];
  }

  float v[3];
  #pragma unroll
  for (int r = 0; r < 3; ++r) {
    int c = l + r * 64;
    float val = 0.f;
    if (c < SF) {
      val = xs[n * SF + c];
    } else if (c < DIN) {
      int f  = (c - SF) >> 5;
      int ch = (c - SF) & 31;
      const float* ep = (f == 0) ? e0 : (f == 1) ? e1 : (f == 2) ? e2 : (f == 3) ? e3 : e4;
      float vals[LTOK];
      #pragma unroll
      for (int j = 0; j < LTOK; ++j)
        vals[j] = ep[toks[w][f * LTOK + j] * ED + ch];
      float sum = 0.f, cnt = 0.f;
      #pragma unroll
      for (int j = 0; j < LTOK; ++j)
        if (toks[w][f * LTOK + j] != 0) { sum += vals[j]; cnt += 1.f; }
      val = sum / (cnt + 1e-9f);
    }
    v[r] = val;
  }

  float p  = v[0] + v[1] + v[2];
  float p2 = v[0] * v[0] + v[1] * v[1] + v[2] * v[2];
  #pragma unroll
  for (int off = 32; off; off >>= 1) { p += __shfl_xor(p, off); p2 += __shfl_xor(p2, off); }
  float mu   = p * (1.f / DIN);
  float var  = fmaxf(p2 * (1.f / DIN) - mu * mu, 0.f);
  float rstd = rsqrtf(var + 1e-5f);

  float pr[8] = {0.f, 0.f, 0.f, 0.f, 0.f, 0.f, 0.f, 0.f};
  #pragma unroll
  for (int r = 0; r < 3; ++r) {
    int c = l + r * 64;
    float y = 0.f;
    if (c < DIN) {
      y = (v[r] - mu) * rstd * g[c] + b[c];
      float4 s4 = vs[c], d4 = vd[c];
      pr[0] += y * s4.x; pr[1] += y * s4.y; pr[2] += y * s4.z; pr[3] += y * s4.w;
      pr[4] += y * d4.x; pr[5] += y * d4.y; pr[6] += y * d4.z; pr[7] += y * d4.w;
    }
    if (c < KP1) out[(size_t)n * KP1 + c] = f2h(y);
  }
  #pragma unroll
  for (int j = 0; j < 8; ++j)
    #pragma unroll
    for (int off = 32; off; off >>= 1) pr[j] += __shfl_xor(pr[j], off);
  if (l == 0) {
    als[n * 4 + 0] = pr[0]; als[n * 4 + 1] = pr[1];
    als[n * 4 + 2] = pr[2]; als[n * 4 + 3] = pr[3];
    ald[n * 4 + 0] = pr[4]; ald[n * 4 + 1] = pr[5];
    ald[n * 4 + 2] = pr[6]; ald[n * 4 + 3] = pr[7];
  }
}

// ---------- 2. CSR build ----------
__global__ void zero_kernel(int* __restrict__ p, int n)
{
  int i = blockIdx.x * blockDim.x + threadIdx.x;
  if (i < n) p[i] = 0;
}

__global__ void count_kernel(const int* __restrict__ ei, int E, int N, int* __restrict__ deg)
{
  int e = blockIdx.x * blockDim.x + threadIdx.x;
  if (e < E + N) {
    int dst = (e < E) ? ei[E + e] : (e - E);
    atomicAdd(&deg[dst], 1);
  }
}

__global__ __launch_bounds__(1024)
void scan_kernel(const int* __restrict__ deg, int* __restrict__ rowptr,
                 int* __restrict__ fill, int N)
{
  __shared__ int sums[1024];
  int t = threadIdx.x;
  int CH = (N + 1023) >> 10;
  int base = t * CH;
  int s = 0;
  for (int i = 0; i < CH; ++i) if (base + i < N) s += deg[base + i];
  sums[t] = s;
  __syncthreads();
  for (int off = 1; off < 1024; off <<= 1) {
    int v = (t >= off) ? sums[t - off] : 0;
    __syncthreads();
    sums[t] += v;
    __syncthreads();
  }
  int run = sums[t] - s;  // exclusive prefix
  for (int i = 0; i < CH; ++i) {
    if (base + i < N) {
      rowptr[base + i] = run;
      fill[base + i]   = run;
      run += deg[base + i];
    }
  }
  if (t == 1023) rowptr[N] = run;
}

__global__ void scatter_kernel(const int* __restrict__ ei, int E, int N,
                               int* __restrict__ fill, int* __restrict__ csr_src)
{
  int e = blockIdx.x * blockDim.x + threadIdx.x;
  if (e < E + N) {
    int src, dst;
    if (e < E) { src = ei[e]; dst = ei[E + e]; }
    else       { src = dst = e - E; }
    int pos = atomicAdd(&fill[dst], 1);
    csr_src[pos] = src;
  }
}

// ---------- 3. layer-1 aggregation via MFMA ----------
// One wave per node. Per 32-edge chunk: G[4][192] += W_f16[4x32] @ Fg[32x192]
// A-frag: one cond ds_read_b128 from wl. B-frag: 2x ds_read_b64_tr_b16 per
// 16-ch tile from the subtiled Fg layout (m162 mapping). 12 MFMA per chunk.
__global__ __launch_bounds__(256)
void agg_feat_kernel(const unsigned short* __restrict__ F,   // [N][KP1] f16
                     const float4* __restrict__ als, const float4* __restrict__ ald,
                     const int* __restrict__ rowptr, const int* __restrict__ csr_src,
                     unsigned short* __restrict__ G, int N)  // [4][N][KP1] f16
{
  // per-wave: Fg subtiled (12 tiles x 2 khalf x 256 elems) + w chunks
  __shared__ __align__(16) unsigned short Fg_s[4][6144];
  __shared__ __align__(16) unsigned short Wl_s[4][2][4][32];

  int wv = threadIdx.x >> 6, lane = threadIdx.x & 63;
  int n = blockIdx.x * 4 + wv;
  if (n >= N) return;
  unsigned short* fg = Fg_s[wv];
  unsigned short (*wl)[4][32] = Wl_s[wv];

  // zero Fg once: stale-LDS could be f16-NaN; 0 * NaN would poison padded edges
  #pragma unroll
  for (int i = 0; i < 12; ++i)
    *(int4*)&fg[(i * 64 + lane) * 8] = make_int4(0, 0, 0, 0);

  int rs = __builtin_amdgcn_readfirstlane(rowptr[n]);
  int re = __builtin_amdgcn_readfirstlane(rowptr[n + 1]);
  int cnt = re - rs;
  float4 ad4 = ald[n];
  float aldv[4] = { ad4.x, ad4.y, ad4.z, ad4.w };

  f32x4 acc[12];
  #pragma unroll
  for (int t = 0; t < 12; ++t) acc[t] = (f32x4){0.f, 0.f, 0.f, 0.f};

  int half = lane >> 5, sub = lane & 31;
  int t_s  = sub >> 1, hi8 = sub & 1;   // staging: tile, which-8-of-16-ch
  bool sact = sub < 24;                 // 24 lanes/half cover 192 ch
  int arow = lane & 15, ag = lane >> 4;
  unsigned ldsb = (unsigned)(size_t)fg; // low 32 bits of flat shared addr = LDS offset

  auto do_chunk = [&](int srcA, int c2, int ccnt) {
    // stage ccnt edges (2 per iter via half-split) into tr-subtile layout
    for (int i = 0; i < ccnt; i += 2) {
      bool has1 = (i + 1) < ccnt;
      int s0 = __builtin_amdgcn_readlane(srcA, c2 * 32 + i);
      int s1 = has1 ? __builtin_amdgcn_readlane(srcA, c2 * 32 + i + 1) : s0;
      int e   = half ? (i + 1) : i;
      int src = half ? s1 : s0;
      bool act = sact && (!half || has1);
      if (act) {
        int4 v = *(const int4*)(F + (size_t)src * KP1 + sub * 8);
        int ae = (t_s * 2 + ((e >> 2) & 1)) * 256 + (e >> 3) * 64 + (e & 3) * 16 + hi8 * 8;
        *(int4*)&fg[ae] = v;
      }
    }
    asm volatile("s_waitcnt lgkmcnt(0)" ::: "memory");
    // A fragment: rows 0-3 = heads, rows 4-15 = zero
    f16x8 af = (f16x8){0, 0, 0, 0, 0, 0, 0, 0};
    if (arow < 4) af = *(const f16x8*)&wl[c2][arow][ag * 8];
    // tiles in groups of 4: issue 8 tr-reads, wait, 4 mfma
    #pragma unroll
    for (int tg = 0; tg < 3; ++tg) {
      unsigned long long r1[4], r2[4];
      #pragma unroll
      for (int q = 0; q < 4; ++q) {
        int t = tg * 4 + q;
        unsigned a1 = ldsb + (unsigned)((t * 2 + 0) * 512) + lane * 8;
        unsigned a2 = ldsb + (unsigned)((t * 2 + 1) * 512) + lane * 8;
        asm volatile("ds_read_b64_tr_b16 %0, %1" : "=v"(r1[q]) : "v"(a1) : "memory");
        asm volatile("ds_read_b64_tr_b16 %0, %1" : "=v"(r2[q]) : "v"(a2) : "memory");
      }
      asm volatile("s_waitcnt lgkmcnt(0)" ::: "memory");
      __builtin_amdgcn_sched_barrier(0);
      #pragma unroll
      for (int q = 0; q < 4; ++q) {
        int t = tg * 4 + q;
        f16x8 bf;
        ((unsigned long long*)&bf)[0] = r1[q];
        ((unsigned long long*)&bf)[1] = r2[q];
        acc[t] = __builtin_amdgcn_mfma_f32_16x16x32_f16(af, bf, acc[t], 0, 0, 0);
      }
    }
  };

  if (cnt <= 64) {
    // fast path: lane j owns edge j
    int srcA = 0;
    float e[4] = { -1e30f, -1e30f, -1e30f, -1e30f };
    if (lane < cnt) {
      srcA = csr_src[rs + lane];
      float4 a4 = als[srcA];
      e[0] = leaky02(a4.x + aldv[0]); e[1] = leaky02(a4.y + aldv[1]);
      e[2] = leaky02(a4.z + aldv[2]); e[3] = leaky02(a4.w + aldv[3]);
    }
    float m[4] = { e[0], e[1], e[2], e[3] };
    #pragma unroll
    for (int off = 32; off; off >>= 1)
      #pragma unroll
      for (int h = 0; h < 4; ++h) m[h] = fmaxf(m[h], __shfl_xor(m[h], off));
    float ex[4];
    #pragma unroll
    for (int h = 0; h < 4; ++h) ex[h] = (lane < cnt) ? __expf(e[h] - m[h]) : 0.f;
    float den[4] = { ex[0], ex[1], ex[2], ex[3] };
    #pragma unroll
    for (int off = 32; off; off >>= 1)
      #pragma unroll
      for (int h = 0; h < 4; ++h) den[h] += __shfl_xor(den[h], off);
    int c2w = lane >> 5, jw = lane & 31;
    #pragma unroll
    for (int h = 0; h < 4; ++h)
      wl[c2w][h][jw] = f2h(ex[h] / (den[h] + 1e-16f));
    do_chunk(srcA, 0, min(cnt, 32));
    if (cnt > 32) do_chunk(srcA, 1, cnt - 32);
  } else {
    // slow path: streaming online softmax for m/den, then 64-edge blocks
    float m[4], s[4];
    #pragma unroll
    for (int h = 0; h < 4; ++h) { m[h] = -1e30f; s[h] = 0.f; }
    for (int i = rs + lane; i < re; i += 64) {
      int src = csr_src[i];
      float4 a4 = als[src];
      float av[4] = { a4.x, a4.y, a4.z, a4.w };
      #pragma unroll
      for (int h = 0; h < 4; ++h) {
        float e = leaky02(av[h] + aldv[h]);
        float Mx = fmaxf(m[h], e);
        s[h] = s[h] * __expf(m[h] - Mx) + __expf(e - Mx);
        m[h] = Mx;
      }
    }
    #pragma unroll
    for (int off = 32; off; off >>= 1) {
      #pragma unroll
      for (int h = 0; h < 4; ++h) {
        float m2 = __shfl_xor(m[h], off);
        float s2 = __shfl_xor(s[h], off);
        float Mx = fmaxf(m[h], m2);
        s[h] = s[h] * __expf(m[h] - Mx) + s2 * __expf(m2 - Mx);
        m[h] = Mx;
      }
    }
    float inv[4];
    #pragma unroll
    for (int h = 0; h < 4; ++h) inv[h] = 1.f / (s[h] + 1e-16f);
    int c2w = lane >> 5, jw = lane & 31;
    for (int b0 = rs; b0 < re; b0 += 64) {
      int bcnt = min(64, re - b0);
      int srcA = 0;
      float w[4] = {0.f, 0.f, 0.f, 0.f};
      if (lane < bcnt) {
        srcA = csr_src[b0 + lane];
        float4 a4 = als[srcA];
        #pragma unroll
        for (int h = 0; h < 4; ++h) {
          float av = (h == 0) ? a4.x : (h == 1) ? a4.y : (h == 2) ? a4.z : a4.w;
          w[h] = __expf(leaky02(av + aldv[h]) - m[h]) * inv[h];
        }
      }
      #pragma unroll
      for (int h = 0; h < 4; ++h) wl[c2w][h][jw] = f2h(w[h]);
      do_chunk(srcA, 0, min(bcnt, 32));
      if (bcnt > 32) do_chunk(srcA, 1, bcnt - 32);
    }
  }

  // C write: lanes 0-15 hold rows 0-3 (the 4 heads), col = lane
  if (ag == 0) {
    #pragma unroll
    for (int t = 0; t < 12; ++t)
      #pragma unroll
      for (int h = 0; h < 4; ++h)
        G[((size_t)h * N + n) * KP1 + t * 16 + arow] = f2h(acc[t][h]);
  }
}

// ---------- 4. MFMA f16 GEMM: C[:, zcols] = A_z[M,KPad] @ Bt_z[128,KPad]^T (+bias, ELU) ----------
template<int KPad>
__global__ __launch_bounds__(256)
void gemm_f16_kernel(const unsigned short* __restrict__ A, const unsigned short* __restrict__ Bt,
                     unsigned short* __restrict__ C, int M, int Nc,
                     size_t aStrideZ, size_t bStrideZ, int cColStrideZ,
                     const float* __restrict__ bias, int act)
{
  A  += blockIdx.z * aStrideZ;
  Bt += blockIdx.z * bStrideZ;
  int colZ = blockIdx.z * cColStrideZ;

  __shared__ __align__(16) unsigned short As[4][128][8];
  __shared__ __align__(16) unsigned short Bs[4][128][8];
  int tid  = threadIdx.x;
  int lane = tid & 63, wave = tid >> 6;
  int wm = (wave >> 1) << 6, wn = (wave & 1) << 6;
  int bm = blockIdx.y << 7, bn = blockIdx.x << 7;

  int srow = tid >> 1;
  int skc  = (tid & 1) << 1;
  const unsigned short* Arow = A  + (size_t)(bm + srow) * KPad + skc * 8;
  const unsigned short* Brow = Bt + (size_t)(bn + srow) * KPad + skc * 8;
  bool aok = (bm + srow) < M;

  f32x4 acc[4][4];
  #pragma unroll
  for (int m = 0; m < 4; ++m)
    #pragma unroll
    for (int n2 = 0; n2 < 4; ++n2) acc[m][n2] = (f32x4){0.f, 0.f, 0.f, 0.f};

  int kc  = lane >> 4;
  int r16 = lane & 15;

  for (int k0 = 0; k0 < KPad; k0 += 32) {
    int4 av0 = make_int4(0, 0, 0, 0), av1 = make_int4(0, 0, 0, 0);
    if (aok) {
      av0 = *(const int4*)(Arow + k0);
      av1 = *(const int4*)(Arow + k0 + 8);
    }
    int4 bv0 = *(const int4*)(Brow + k0);
    int4 bv1 = *(const int4*)(Brow + k0 + 8);
    __syncthreads();
    *(int4*)&As[skc][srow][0]     = av0;
    *(int4*)&As[skc + 1][srow][0] = av1;
    *(int4*)&Bs[skc][srow][0]     = bv0;
    *(int4*)&Bs[skc + 1][srow][0] = bv1;
    __syncthreads();

    f16x8 af[4], bfr[4];
    #pragma unroll
    for (int m = 0; m < 4; ++m)  af[m]  = *(const f16x8*)&As[kc][wm + m * 16 + r16][0];
    #pragma unroll
    for (int n2 = 0; n2 < 4; ++n2) bfr[n2] = *(const f16x8*)&Bs[kc][wn + n2 * 16 + r16][0];
    #pragma unroll
    for (int m = 0; m < 4; ++m)
      #pragma unroll
      for (int n2 = 0; n2 < 4; ++n2)
        acc[m][n2] = __builtin_amdgcn_mfma_f32_16x16x32_f16(af[m], bfr[n2], acc[m][n2], 0, 0, 0);
  }

  int rq = lane >> 4;
  #pragma unroll
  for (int m = 0; m < 4; ++m) {
    #pragma unroll
    for (int r = 0; r < 4; ++r) {
      int row = bm + wm + m * 16 + rq * 4 + r;
      if (row < M) {
        #pragma unroll
        for (int n2 = 0; n2 < 4; ++n2) {
          int col = colZ + bn + wn + n2 * 16 + r16;
          float val = acc[m][n2][r];
          if (bias) val += bias[col];
          if (act)  val = eluf(val);
          C[(size_t)row * Nc + col] = f2h(val);
        }
      }
    }
  }
}

// ---------- 5. layer-2 attention logits from f16 H2 ----------
__global__ __launch_bounds__(128)
void logits2_kernel(const unsigned short* __restrict__ H,
                    const float* __restrict__ a_s, const float* __restrict__ a_d,
                    float* __restrict__ al_s, float* __restrict__ al_d, int N)
{
  int n = blockIdx.x, t = threadIdx.x;
  int wv = t >> 6, lane = t & 63;
  __shared__ float tmp[2][2];
  float hv = h2f(H[(size_t)n * HC + t]);
  float ps = hv * a_s[t];
  float pd = hv * a_d[t];
  #pragma unroll
  for (int off = 32; off; off >>= 1) { ps += __shfl_down(ps, off); pd += __shfl_down(pd, off); }
  if (lane == 0) { tmp[0][wv] = ps; tmp[1][wv] = pd; }
  __syncthreads();
  if (t == 0) {
    al_s[n] = tmp[0][0] + tmp[0][1];
    al_d[n] = tmp[1][0] + tmp[1][1];
  }
}

// ---------- 6. layer-2 aggregation; fast-path softmax + 2-edge pass B ----------
__global__ __launch_bounds__(256)
void agg_h2_kernel(const unsigned short* __restrict__ H,
                   const float* __restrict__ al_s, const float* __restrict__ al_d,
                   const int* __restrict__ rowptr, const int* __restrict__ csr_src,
                   const float* __restrict__ bias, unsigned short* __restrict__ out, int N)
{
  int wv = threadIdx.x >> 6, lane = threadIdx.x & 63;
  int n = blockIdx.x * 4 + wv;
  if (n >= N) return;
  int rs = __builtin_amdgcn_readfirstlane(rowptr[n]);
  int re = __builtin_amdgcn_readfirstlane(rowptr[n + 1]);
  int cnt = re - rs;
  float ald = al_d[n];
  int half = lane >> 5, sub = lane & 31;
  float acc[4] = {0.f, 0.f, 0.f, 0.f};

  auto passB = [&](int c2, int srcA, float wAl) {
    for (int j = 0; j < c2; j += 2) {
      int j1 = j + 1;
      bool has1 = j1 < c2;
      int s0 = __builtin_amdgcn_readlane(srcA, j);
      int s1 = has1 ? __builtin_amdgcn_readlane(srcA, j1) : s0;
      float w0 = readlane_f(wAl, j);
      float w1 = has1 ? readlane_f(wAl, j1) : 0.f;
      float wgt = half ? w1 : w0;
      int src = half ? s1 : s0;
      int2 vv = *(const int2*)(H + (size_t)src * HC + sub * 4);
      acc[0] += wgt * h2f((unsigned short)(vv.x & 0xffff));
      acc[1] += wgt * h2f((unsigned short)((unsigned)vv.x >> 16));
      acc[2] += wgt * h2f((unsigned short)(vv.y & 0xffff));
      acc[3] += wgt * h2f((unsigned short)((unsigned)vv.y >> 16));
    }
  };

  if (cnt <= 64) {
    int srcA = 0;
    float e = -1e30f;
    if (lane < cnt) {
      srcA = csr_src[rs + lane];
      e = leaky02(al_s[srcA] + ald);
    }
    float m = e;
    #pragma unroll
    for (int off = 32; off; off >>= 1) m = fmaxf(m, __shfl_xor(m, off));
    float ex = (lane < cnt) ? __expf(e - m) : 0.f;
    float den = ex;
    #pragma unroll
    for (int off = 32; off; off >>= 1) den += __shfl_xor(den, off);
    passB(cnt, srcA, ex / (den + 1e-16f));
  } else {
    float m = -1e30f, s = 0.f;
    for (int i = rs + lane; i < re; i += 64) {
      int src = csr_src[i];
      float e = leaky02(al_s[src] + ald);
      float Mx = fmaxf(m, e);
      s = s * __expf(m - Mx) + __expf(e - Mx);
      m = Mx;
    }
    #pragma unroll
    for (int off = 32; off; off >>= 1) {
      float m2 = __shfl_xor(m, off);
      float s2 = __shfl_xor(s, off);
      float Mx = fmaxf(m, m2);
      s = s * __expf(m - Mx) + s2 * __expf(m2 - Mx);
      m = Mx;
    }
    float inv_den = 1.f / (s + 1e-16f);
    for (int c0 = rs; c0 < re; c0 += 64) {
      int ccnt = min(64, re - c0);
      int srcA = 0;
      float wAl = 0.f;
      if (lane < ccnt) {
        srcA = csr_src[c0 + lane];
        wAl = __expf(leaky02(al_s[srcA] + ald) - m) * inv_den;
      }
      passB(ccnt, srcA, wAl);
    }
  }

  #pragma unroll
  for (int c = 0; c < 4; ++c) acc[c] += __shfl_xor(acc[c], 32);
  if (lane < 32) {
    float o0 = eluf(acc[0] + bias[sub * 4 + 0]);
    float o1 = eluf(acc[1] + bias[sub * 4 + 1]);
    float o2 = eluf(acc[2] + bias[sub * 4 + 2]);
    float o3 = eluf(acc[3] + bias[sub * 4 + 3]);
    int2 o;
    o.x = (int)f2h(o0) | ((int)f2h(o1) << 16);
    o.y = (int)f2h(o2) | ((int)f2h(o3) << 16);
    *(int2*)&out[(size_t)n * HC + sub * 4] = o;
  }
}

// ---------- 7. global max pool (segmented over sorted batch) ----------
static __device__ __forceinline__ unsigned enc_f(float f)
{
  unsigned u = __float_as_uint(f);
  return (u & 0x80000000u) ? ~u : (u | 0x80000000u);
}
static __device__ __forceinline__ float dec_f(unsigned u)
{
  return (u & 0x80000000u) ? __uint_as_float(u & 0x7fffffffu) : __uint_as_float(~u);
}

__global__ void pool_init_kernel(unsigned* __restrict__ p, int n)
{
  int i = blockIdx.x * blockDim.x + threadIdx.x;
  if (i < n) p[i] = 0x00800000u;  // enc(-FLT_MAX)
}

#define PNPB 128   // nodes per pool block
__global__ __launch_bounds__(256)
void pool_seg_kernel(const unsigned short* __restrict__ x, const int* __restrict__ batch,
                     unsigned* __restrict__ pool, int N)
{
  int cp = (threadIdx.x & 63) * 2;     // channel pair
  int g  = threadIdx.x >> 6;           // node group 0..3
  int n0 = blockIdx.x * PNPB;
  int n1 = min(n0 + PNPB, N);
  int curb = -1;
  float m0 = 0.f, m1 = 0.f;
  for (int n = n0 + g; n < n1; n += 4) {
    int bg = batch[n];
    ushort2 v = *(const ushort2*)&x[(size_t)n * HC + cp];
    float v0 = h2f(v.x), v1 = h2f(v.y);
    if (bg != curb) {
      if (curb >= 0) {
        atomicMax(&pool[curb * HC + cp],     enc_f(m0));
        atomicMax(&pool[curb * HC + cp + 1], enc_f(m1));
      }
      curb = bg; m0 = v0; m1 = v1;
    } else {
      m0 = fmaxf(m0, v0);
      m1 = fmaxf(m1, v1);
    }
  }
  if (curb >= 0) {
    atomicMax(&pool[curb * HC + cp],     enc_f(m0));
    atomicMax(&pool[curb * HC + cp + 1], enc_f(m1));
  }
}

__global__ void pool_final_kernel(const unsigned* __restrict__ pool, float* __restrict__ out, int n)
{
  int i = blockIdx.x * blockDim.x + threadIdx.x;
  if (i < n) out[i] = dec_f(pool[i]);
}

// ---------- launch ----------
extern "C" void kernel_launch(void* const* d_in, const int* in_sizes, int n_in,
                              void* d_out, int out_size, void* d_ws, size_t ws_size,
                              hipStream_t stream)
{
  const float* x_scalar = (const float*)d_in[0];
  const int* i0 = (const int*)d_in[1];
  const int* i1 = (const int*)d_in[2];
  const int* i2 = (const int*)d_in[3];
  const int* i3 = (const int*)d_in[4];
  const int* i4 = (const int*)d_in[5];
  const int* ei = (const int*)d_in[6];
  const int* batch = (const int*)d_in[7];
  const float* e0 = (const float*)d_in[8];
  const float* e1 = (const float*)d_in[9];
  const float* e2 = (const float*)d_in[10];
  const float* e3 = (const float*)d_in[11];
  const float* e4 = (const float*)d_in[12];
  const float* ln_g = (const float*)d_in[13];
  const float* ln_b = (const float*)d_in[14];
  const float* W1 = (const float*)d_in[15];
  const float* as1 = (const float*)d_in[16];
  const float* ad1 = (const float*)d_in[17];
  const float* b1 = (const float*)d_in[18];
  const float* W2 = (const float*)d_in[19];
  const float* as2 = (const float*)d_in[20];
  const float* ad2 = (const float*)d_in[21];
  const float* b2 = (const float*)d_in[22];

  const int N  = in_sizes[0] / SF;
  const int E  = in_sizes[6] / 2;
  const int Et = E + N;
  const int Bg = out_size / HC;
  const int MT = (N + 127) / 128;

  char* w = (char*)d_ws;
  auto alloc = [&](size_t bytes) -> char* {
    char* p = w;
    w += (bytes + 255) & ~(size_t)255;
    return p;
  };
  unsigned short* featsb = (unsigned short*)alloc((size_t)N * KP1 * 2);
  unsigned short* G      = (unsigned short*)alloc((size_t)4 * N * KP1 * 2);
  unsigned short* X2b    = (unsigned short*)alloc((size_t)N * 512 * 2);
  unsigned short* H2b    = (unsigned short*)alloc((size_t)N * HC * 2);
  unsigned short* X3b    = (unsigned short*)alloc((size_t)N * HC * 2);
  unsigned short* W1t    = (unsigned short*)alloc((size_t)512 * KP1 * 2);
  unsigned short* W2t    = (unsigned short*)alloc((size_t)HC * 512 * 2);
  float* vs      = (float*)alloc((size_t)KP1 * 4 * 4);
  float* vd      = (float*)alloc((size_t)KP1 * 4 * 4);
  float* als1    = (float*)alloc((size_t)N * 4 * 4);
  float* ald1    = (float*)alloc((size_t)N * 4 * 4);
  float* als2    = (float*)alloc((size_t)N * 4);
  float* ald2    = (float*)alloc((size_t)N * 4);
  int*   deg     = (int*)alloc((size_t)N * 4);
  int*   rowptr  = (int*)alloc((size_t)(N + 1) * 4);
  int*   fill    = (int*)alloc((size_t)N * 4);
  int*   csr_src = (int*)alloc((size_t)Et * 4);
  unsigned* pool = (unsigned*)alloc((size_t)Bg * HC * 4);

  // constants per call
  pack_wt_kernel<<<(512 * KP1 + 255) / 256, 256, 0, stream>>>(W1, W1t, DIN, 512, KP1);
  pack_wt_kernel<<<(HC * 512 + 255) / 256, 256, 0, stream>>>(W2, W2t, 512, HC, 512);
  prep_attn_kernel<<<DIN, 256, 0, stream>>>(W1, as1, ad1, vs, vd);

  // features + LN + fused layer-1 logits (one wave per node, 4 nodes/block)
  feat_ln_kernel<<<(N + 3) / 4, 256, 0, stream>>>(x_scalar, i0, i1, i2, i3, i4,
                                                  e0, e1, e2, e3, e4, ln_g, ln_b,
                                                  (const float4*)vs, (const float4*)vd,
                                                  featsb, als1, ald1, N);

  // CSR
  zero_kernel<<<(N + 255) / 256, 256, 0, stream>>>(deg, N);
  count_kernel<<<(Et + 255) / 256, 256, 0, stream>>>(ei, E, N, deg);
  scan_kernel<<<1, 1024, 0, stream>>>(deg, rowptr, fill, N);
  scatter_kernel<<<(Et + 255) / 256, 256, 0, stream>>>(ei, E, N, fill, csr_src);

  // layer 1: MFMA aggregation, then per-head GEMM (+b1, ELU)
  agg_feat_kernel<<<(N + 3) / 4, 256, 0, stream>>>(featsb, (const float4*)als1,
                                                   (const float4*)ald1,
                                                   rowptr, csr_src, G, N);
  gemm_f16_kernel<KP1><<<dim3(1, MT, 4), 256, 0, stream>>>(
      G, W1t, X2b, N, 512, (size_t)N * KP1, (size_t)HC * KP1, HC, b1, 1);

  // layer 2: GEMM (raw H2), logits, aggregate (+b2, ELU)
  gemm_f16_kernel<512><<<dim3(1, MT, 1), 256, 0, stream>>>(
      X2b, W2t, H2b, N, HC, 0, 0, 0, nullptr, 0);
  logits2_kernel<<<N, 128, 0, stream>>>(H2b, as2, ad2, als2, ald2, N);
  agg_h2_kernel<<<(N + 3) / 4, 256, 0, stream>>>(H2b, als2, ald2, rowptr, csr_src, b2, X3b, N);

  // pool
  pool_init_kernel<<<(Bg * HC + 255) / 256, 256, 0, stream>>>(pool, Bg * HC);
  pool_seg_kernel<<<(N + PNPB - 1) / PNPB, 256, 0, stream>>>(X3b, batch, pool, N);
  pool_final_kernel<<<(Bg * HC + 255) / 256, 256, 0, stream>>>(pool, (float*)d_out, Bg * HC);
}

// Round 9
// 258.931 us; speedup vs baseline: 1.1761x; 1.1761x over previous
//
#include <hip/hip_runtime.h>
#include <math.h>

#define SF 16
#define ED 32
#define LTOK 20
#define DIN 176
#define KP1 192   // DIN padded to multiple of 32
#define HC 128

typedef _Float16 f16x8 __attribute__((ext_vector_type(8)));
typedef float f32x4 __attribute__((ext_vector_type(4)));

static __device__ __forceinline__ float leaky02(float x) { return x >= 0.f ? x : 0.2f * x; }
static __device__ __forceinline__ float eluf(float x)    { return x > 0.f ? x : expm1f(x); }
static __device__ __forceinline__ unsigned short f2h(float f)
{
  _Float16 h = (_Float16)f;
  return __builtin_bit_cast(unsigned short, h);
}
static __device__ __forceinline__ float h2f(unsigned short u)
{
  return (float)__builtin_bit_cast(_Float16, u);
}
static __device__ __forceinline__ float readlane_f(float v, int j)
{
  return __int_as_float(__builtin_amdgcn_readlane(__float_as_int(v), j));
}

// ---------- 0. combined prep: pack W1t/W2t, vs/vd, zero deg, init pool ----------
__global__ __launch_bounds__(256)
void prep_combined_kernel(const float* __restrict__ W1, const float* __restrict__ W2,
                          unsigned short* __restrict__ W1t, unsigned short* __restrict__ W2t,
                          const float* __restrict__ as1, const float* __restrict__ ad1,
                          float* __restrict__ vs, float* __restrict__ vd,
                          int* __restrict__ deg, unsigned* __restrict__ pool,
                          int N, int poolN)
{
  const int nb1 = (512 * KP1 + 255) / 256;
  const int nb2 = (HC * 512 + 255) / 256;
  const int nb3 = (N + 255) / 256;
  const int nb4 = (poolN + 255) / 256;
  int bid = blockIdx.x;
  if (bid < nb1) {                       // W1t [512][KP1] <- W1 [DIN][512]
    int i = bid * 256 + threadIdx.x;
    if (i < 512 * KP1) {
      int n = i / KP1, k = i - n * KP1;
      W1t[i] = f2h((k < DIN) ? W1[(size_t)k * 512 + n] : 0.f);
    }
    return;
  }
  bid -= nb1;
  if (bid < nb2) {                       // W2t [HC][512] <- W2 [512][HC]
    int i = bid * 256 + threadIdx.x;
    if (i < HC * 512) {
      int n = i / 512, k = i - n * 512;
      W2t[i] = f2h(W2[(size_t)k * HC + n]);
    }
    return;
  }
  bid -= nb2;
  if (bid < nb3) {                       // deg = 0
    int i = bid * 256 + threadIdx.x;
    if (i < N) deg[i] = 0;
    return;
  }
  bid -= nb3;
  if (bid < nb4) {                       // pool = enc(-FLT_MAX)
    int i = bid * 256 + threadIdx.x;
    if (i < poolN) pool[i] = 0x00800000u;
    return;
  }
  bid -= nb4;
  {                                      // vs/vd row bid (0..DIN-1)
    int k = bid;
    int h = threadIdx.x >> 6, lane = threadIdx.x & 63;
    const float* row = W1 + (size_t)k * 512 + h * HC;
    float s = row[lane] * as1[h * HC + lane] + row[lane + 64] * as1[h * HC + lane + 64];
    float d = row[lane] * ad1[h * HC + lane] + row[lane + 64] * ad1[h * HC + lane + 64];
    #pragma unroll
    for (int off = 32; off; off >>= 1) { s += __shfl_down(s, off); d += __shfl_down(d, off); }
    if (lane == 0) { vs[k * 4 + h] = s; vd[k * 4 + h] = d; }
  }
}

// ---------- 1. features + LayerNorm + fused logits; ONE WAVE PER NODE ----------
__global__ __launch_bounds__(256)
void feat_ln_kernel(const float* __restrict__ xs,
                    const int* __restrict__ i0, const int* __restrict__ i1,
                    const int* __restrict__ i2, const int* __restrict__ i3,
                    const int* __restrict__ i4,
                    const float* __restrict__ e0, const float* __restrict__ e1,
                    const float* __restrict__ e2, const float* __restrict__ e3,
                    const float* __restrict__ e4,
                    const float* __restrict__ g, const float* __restrict__ b,
                    const float4* __restrict__ vs, const float4* __restrict__ vd,
                    unsigned short* __restrict__ out,
                    float* __restrict__ als, float* __restrict__ ald, int N)
{
  __shared__ int toks[4][5 * LTOK];
  int w = threadIdx.x >> 6, l = threadIdx.x & 63;
  int n = blockIdx.x * 4 + w;
  if (n >= N) return;

  for (int q = l; q < 5 * LTOK; q += 64) {
    int f = q / LTOK, j = q - f * LTOK;
    const int* ip = (f == 0) ? i0 : (f == 1) ? i1 : (f == 2) ? i2 : (f == 3) ? i3 : i4;
    toks[w][q] = ip[n * LTOK + j];
  }

  float v[3];
  #pragma unroll
  for (int r = 0; r < 3; ++r) {
    int c = l + r * 64;
    float val = 0.f;
    if (c < SF) {
      val = xs[n * SF + c];
    } else if (c < DIN) {
      int f  = (c - SF) >> 5;
      int ch = (c - SF) & 31;
      const float* ep = (f == 0) ? e0 : (f == 1) ? e1 : (f == 2) ? e2 : (f == 3) ? e3 : e4;
      float vals[LTOK];
      #pragma unroll
      for (int j = 0; j < LTOK; ++j)
        vals[j] = ep[toks[w][f * LTOK + j] * ED + ch];
      float sum = 0.f, cnt = 0.f;
      #pragma unroll
      for (int j = 0; j < LTOK; ++j)
        if (toks[w][f * LTOK + j] != 0) { sum += vals[j]; cnt += 1.f; }
      val = sum / (cnt + 1e-9f);
    }
    v[r] = val;
  }

  float p  = v[0] + v[1] + v[2];
  float p2 = v[0] * v[0] + v[1] * v[1] + v[2] * v[2];
  #pragma unroll
  for (int off = 32; off; off >>= 1) { p += __shfl_xor(p, off); p2 += __shfl_xor(p2, off); }
  float mu   = p * (1.f / DIN);
  float var  = fmaxf(p2 * (1.f / DIN) - mu * mu, 0.f);
  float rstd = rsqrtf(var + 1e-5f);

  float pr[8] = {0.f, 0.f, 0.f, 0.f, 0.f, 0.f, 0.f, 0.f};
  #pragma unroll
  for (int r = 0; r < 3; ++r) {
    int c = l + r * 64;
    float y = 0.f;
    if (c < DIN) {
      y = (v[r] - mu) * rstd * g[c] + b[c];
      float4 s4 = vs[c], d4 = vd[c];
      pr[0] += y * s4.x; pr[1] += y * s4.y; pr[2] += y * s4.z; pr[3] += y * s4.w;
      pr[4] += y * d4.x; pr[5] += y * d4.y; pr[6] += y * d4.z; pr[7] += y * d4.w;
    }
    if (c < KP1) out[(size_t)n * KP1 + c] = f2h(y);
  }
  #pragma unroll
  for (int j = 0; j < 8; ++j)
    #pragma unroll
    for (int off = 32; off; off >>= 1) pr[j] += __shfl_xor(pr[j], off);
  if (l == 0) {
    als[n * 4 + 0] = pr[0]; als[n * 4 + 1] = pr[1];
    als[n * 4 + 2] = pr[2]; als[n * 4 + 3] = pr[3];
    ald[n * 4 + 0] = pr[4]; ald[n * 4 + 1] = pr[5];
    ald[n * 4 + 2] = pr[6]; ald[n * 4 + 3] = pr[7];
  }
}

// ---------- 2. CSR build ----------
__global__ void count_kernel(const int* __restrict__ ei, int E, int N, int* __restrict__ deg)
{
  int e = blockIdx.x * blockDim.x + threadIdx.x;
  if (e < E + N) {
    int dst = (e < E) ? ei[E + e] : (e - E);
    atomicAdd(&deg[dst], 1);
  }
}

__global__ __launch_bounds__(1024)
void scan_kernel(const int* __restrict__ deg, int* __restrict__ rowptr,
                 int* __restrict__ fill, int N)
{
  __shared__ int sums[1024];
  int t = threadIdx.x;
  int CH = (N + 1023) >> 10;
  int base = t * CH;
  int s = 0;
  for (int i = 0; i < CH; ++i) if (base + i < N) s += deg[base + i];
  sums[t] = s;
  __syncthreads();
  for (int off = 1; off < 1024; off <<= 1) {
    int v = (t >= off) ? sums[t - off] : 0;
    __syncthreads();
    sums[t] += v;
    __syncthreads();
  }
  int run = sums[t] - s;  // exclusive prefix
  for (int i = 0; i < CH; ++i) {
    if (base + i < N) {
      rowptr[base + i] = run;
      fill[base + i]   = run;
      run += deg[base + i];
    }
  }
  if (t == 1023) rowptr[N] = run;
}

__global__ void scatter_kernel(const int* __restrict__ ei, int E, int N,
                               int* __restrict__ fill, int* __restrict__ csr_src)
{
  int e = blockIdx.x * blockDim.x + threadIdx.x;
  if (e < E + N) {
    int src, dst;
    if (e < E) { src = ei[e]; dst = ei[E + e]; }
    else       { src = dst = e - E; }
    int pos = atomicAdd(&fill[dst], 1);
    csr_src[pos] = src;
  }
}

// ---------- pass B helper: 2 edges/iter, halves combine later ----------
// half = lane>>5, sub = lane&31; lanes sub<24 carry 8 channels each (16B).
static __device__ __forceinline__ void agg_passB(
    const unsigned short* __restrict__ F, int cnt, int srcA, float4 wA,
    int half, int sub, float acc[4][8])
{
  for (int j = 0; j < cnt; j += 2) {
    int j1 = j + 1;
    bool has1 = j1 < cnt;             // wave-uniform
    int s0 = __builtin_amdgcn_readlane(srcA, j);
    int s1 = has1 ? __builtin_amdgcn_readlane(srcA, j1) : s0;
    float w[4];
    float w0x = readlane_f(wA.x, j), w0y = readlane_f(wA.y, j);
    float w0z = readlane_f(wA.z, j), w0w = readlane_f(wA.w, j);
    float w1x = 0.f, w1y = 0.f, w1z = 0.f, w1w = 0.f;
    if (has1) {
      w1x = readlane_f(wA.x, j1); w1y = readlane_f(wA.y, j1);
      w1z = readlane_f(wA.z, j1); w1w = readlane_f(wA.w, j1);
    }
    w[0] = half ? w1x : w0x;  w[1] = half ? w1y : w0y;
    w[2] = half ? w1z : w0z;  w[3] = half ? w1w : w0w;
    int src = half ? s1 : s0;
    if (sub < 24) {
      int4 vv = *(const int4*)(F + (size_t)src * KP1 + sub * 8);
      float f[8];
      f[0] = h2f((unsigned short)(vv.x & 0xffff)); f[1] = h2f((unsigned short)((unsigned)vv.x >> 16));
      f[2] = h2f((unsigned short)(vv.y & 0xffff)); f[3] = h2f((unsigned short)((unsigned)vv.y >> 16));
      f[4] = h2f((unsigned short)(vv.z & 0xffff)); f[5] = h2f((unsigned short)((unsigned)vv.z >> 16));
      f[6] = h2f((unsigned short)(vv.w & 0xffff)); f[7] = h2f((unsigned short)((unsigned)vv.w >> 16));
      #pragma unroll
      for (int h = 0; h < 4; ++h)
        #pragma unroll
        for (int c = 0; c < 8; ++c)
          acc[h][c] += w[h] * f[c];
    }
  }
}

// ---------- 3. layer-1 aggregation over FEATURES ----------
// 4 waves/block (one node per wave). Single-chunk fast path (deg<=64):
// lane j owns edge j -> direct butterfly softmax, no streaming pass.
__global__ __launch_bounds__(256)
void agg_feat_kernel(const unsigned short* __restrict__ F,   // [N][KP1] f16
                     const float4* __restrict__ als, const float4* __restrict__ ald,
                     const int* __restrict__ rowptr, const int* __restrict__ csr_src,
                     unsigned short* __restrict__ G, int N)  // [4][N][KP1] f16
{
  int wv = threadIdx.x >> 6, lane = threadIdx.x & 63;
  int n = blockIdx.x * 4 + wv;
  if (n >= N) return;
  int rs = __builtin_amdgcn_readfirstlane(rowptr[n]);
  int re = __builtin_amdgcn_readfirstlane(rowptr[n + 1]);
  int cnt = re - rs;
  float4 ad4 = ald[n];
  float aldv[4] = { ad4.x, ad4.y, ad4.z, ad4.w };
  int half = lane >> 5, sub = lane & 31;
  float acc[4][8] = {};

  if (cnt <= 64) {
    // ---- fast path: one edge per lane ----
    int srcA = 0;
    float e[4] = { -1e30f, -1e30f, -1e30f, -1e30f };
    if (lane < cnt) {
      srcA = csr_src[rs + lane];
      float4 a4 = als[srcA];
      e[0] = leaky02(a4.x + aldv[0]); e[1] = leaky02(a4.y + aldv[1]);
      e[2] = leaky02(a4.z + aldv[2]); e[3] = leaky02(a4.w + aldv[3]);
    }
    float m[4] = { e[0], e[1], e[2], e[3] };
    #pragma unroll
    for (int off = 32; off; off >>= 1)
      #pragma unroll
      for (int h = 0; h < 4; ++h) m[h] = fmaxf(m[h], __shfl_xor(m[h], off));
    float ex[4];
    #pragma unroll
    for (int h = 0; h < 4; ++h) ex[h] = (lane < cnt) ? __expf(e[h] - m[h]) : 0.f;
    float den[4] = { ex[0], ex[1], ex[2], ex[3] };
    #pragma unroll
    for (int off = 32; off; off >>= 1)
      #pragma unroll
      for (int h = 0; h < 4; ++h) den[h] += __shfl_xor(den[h], off);
    float4 wA;
    wA.x = ex[0] / (den[0] + 1e-16f); wA.y = ex[1] / (den[1] + 1e-16f);
    wA.z = ex[2] / (den[2] + 1e-16f); wA.w = ex[3] / (den[3] + 1e-16f);
    agg_passB(F, cnt, srcA, wA, half, sub, acc);
  } else {
    // ---- slow path: streaming online softmax, then chunked ----
    float m[4], s[4];
    #pragma unroll
    for (int h = 0; h < 4; ++h) { m[h] = -1e30f; s[h] = 0.f; }
    for (int i = rs + lane; i < re; i += 64) {
      int src = csr_src[i];
      float4 a4 = als[src];
      float av[4] = { a4.x, a4.y, a4.z, a4.w };
      #pragma unroll
      for (int h = 0; h < 4; ++h) {
        float e = leaky02(av[h] + aldv[h]);
        float Mx = fmaxf(m[h], e);
        s[h] = s[h] * __expf(m[h] - Mx) + __expf(e - Mx);
        m[h] = Mx;
      }
    }
    #pragma unroll
    for (int off = 32; off; off >>= 1) {
      #pragma unroll
      for (int h = 0; h < 4; ++h) {
        float m2 = __shfl_xor(m[h], off);
        float s2 = __shfl_xor(s[h], off);
        float Mx = fmaxf(m[h], m2);
        s[h] = s[h] * __expf(m[h] - Mx) + s2 * __expf(m2 - Mx);
        m[h] = Mx;
      }
    }
    float inv[4];
    #pragma unroll
    for (int h = 0; h < 4; ++h) inv[h] = 1.f / (s[h] + 1e-16f);
    for (int c0 = rs; c0 < re; c0 += 64) {
      int ccnt = min(64, re - c0);
      int srcA = 0;
      float4 wA = make_float4(0.f, 0.f, 0.f, 0.f);
      if (lane < ccnt) {
        srcA = csr_src[c0 + lane];
        float4 a4 = als[srcA];
        wA.x = __expf(leaky02(a4.x + aldv[0]) - m[0]) * inv[0];
        wA.y = __expf(leaky02(a4.y + aldv[1]) - m[1]) * inv[1];
        wA.z = __expf(leaky02(a4.z + aldv[2]) - m[2]) * inv[2];
        wA.w = __expf(leaky02(a4.w + aldv[3]) - m[3]) * inv[3];
      }
      agg_passB(F, ccnt, srcA, wA, half, sub, acc);
    }
  }

  // combine halves; lanes 0..23 write 8 channels each
  #pragma unroll
  for (int h = 0; h < 4; ++h)
    #pragma unroll
    for (int c = 0; c < 8; ++c)
      acc[h][c] += __shfl_xor(acc[h][c], 32);
  if (lane < 24) {
    #pragma unroll
    for (int h = 0; h < 4; ++h) {
      int4 o;
      o.x = (int)f2h(acc[h][0]) | ((int)f2h(acc[h][1]) << 16);
      o.y = (int)f2h(acc[h][2]) | ((int)f2h(acc[h][3]) << 16);
      o.z = (int)f2h(acc[h][4]) | ((int)f2h(acc[h][5]) << 16);
      o.w = (int)f2h(acc[h][6]) | ((int)f2h(acc[h][7]) << 16);
      *(int4*)&G[((size_t)h * N + n) * KP1 + lane * 8] = o;
    }
  }
}

// ---------- 4. MFMA f16 GEMM (+bias/ELU, optional fused row-logits) ----------
template<int KPad>
__global__ __launch_bounds__(256)
void gemm_f16_kernel(const unsigned short* __restrict__ A, const unsigned short* __restrict__ Bt,
                     unsigned short* __restrict__ C, int M, int Nc,
                     size_t aStrideZ, size_t bStrideZ, int cColStrideZ,
                     const float* __restrict__ bias, int act,
                     const float* __restrict__ la_s, const float* __restrict__ la_d,
                     float* __restrict__ lout_s, float* __restrict__ lout_d)
{
  A  += blockIdx.z * aStrideZ;
  Bt += blockIdx.z * bStrideZ;
  int colZ = blockIdx.z * cColStrideZ;

  __shared__ __align__(16) unsigned short As[4][128][8];
  __shared__ __align__(16) unsigned short Bs[4][128][8];
  __shared__ float ls[128][2];
  int tid  = threadIdx.x;
  int lane = tid & 63, wave = tid >> 6;
  int wm = (wave >> 1) << 6, wn = (wave & 1) << 6;
  int bm = blockIdx.y << 7, bn = blockIdx.x << 7;

  int srow = tid >> 1;
  int skc  = (tid & 1) << 1;
  const unsigned short* Arow = A  + (size_t)(bm + srow) * KPad + skc * 8;
  const unsigned short* Brow = Bt + (size_t)(bn + srow) * KPad + skc * 8;
  bool aok = (bm + srow) < M;

  f32x4 acc[4][4];
  #pragma unroll
  for (int m = 0; m < 4; ++m)
    #pragma unroll
    for (int n2 = 0; n2 < 4; ++n2) acc[m][n2] = (f32x4){0.f, 0.f, 0.f, 0.f};

  int kc  = lane >> 4;
  int r16 = lane & 15;

  for (int k0 = 0; k0 < KPad; k0 += 32) {
    int4 av0 = make_int4(0, 0, 0, 0), av1 = make_int4(0, 0, 0, 0);
    if (aok) {
      av0 = *(const int4*)(Arow + k0);
      av1 = *(const int4*)(Arow + k0 + 8);
    }
    int4 bv0 = *(const int4*)(Brow + k0);
    int4 bv1 = *(const int4*)(Brow + k0 + 8);
    __syncthreads();
    *(int4*)&As[skc][srow][0]     = av0;
    *(int4*)&As[skc + 1][srow][0] = av1;
    *(int4*)&Bs[skc][srow][0]     = bv0;
    *(int4*)&Bs[skc + 1][srow][0] = bv1;
    __syncthreads();

    f16x8 af[4], bfr[4];
    #pragma unroll
    for (int m = 0; m < 4; ++m)  af[m]  = *(const f16x8*)&As[kc][wm + m * 16 + r16][0];
    #pragma unroll
    for (int n2 = 0; n2 < 4; ++n2) bfr[n2] = *(const f16x8*)&Bs[kc][wn + n2 * 16 + r16][0];
    #pragma unroll
    for (int m = 0; m < 4; ++m)
      #pragma unroll
      for (int n2 = 0; n2 < 4; ++n2)
        acc[m][n2] = __builtin_amdgcn_mfma_f32_16x16x32_f16(af[m], bfr[n2], acc[m][n2], 0, 0, 0);
  }

  int rq = lane >> 4;
  #pragma unroll
  for (int m = 0; m < 4; ++m) {
    #pragma unroll
    for (int r = 0; r < 4; ++r) {
      int row = bm + wm + m * 16 + rq * 4 + r;
      if (row < M) {
        #pragma unroll
        for (int n2 = 0; n2 < 4; ++n2) {
          int col = colZ + bn + wn + n2 * 16 + r16;
          float val = acc[m][n2][r];
          if (bias) val += bias[col];
          if (act)  val = eluf(val);
          C[(size_t)row * Nc + col] = f2h(val);
        }
      }
    }
  }

  // fused per-row logits (gemm2 only; raw pre-bias values, Nc==128, 1 x-block)
  if (lout_s) {
    float ps[4][4] = {}, pd[4][4] = {};
    #pragma unroll
    for (int m = 0; m < 4; ++m)
      #pragma unroll
      for (int r = 0; r < 4; ++r)
        #pragma unroll
        for (int n2 = 0; n2 < 4; ++n2) {
          int col = wn + n2 * 16 + r16;
          float val = acc[m][n2][r];
          ps[m][r] += val * la_s[col];
          pd[m][r] += val * la_d[col];
        }
    #pragma unroll
    for (int off = 1; off < 16; off <<= 1)
      #pragma unroll
      for (int m = 0; m < 4; ++m)
        #pragma unroll
        for (int r = 0; r < 4; ++r) {
          ps[m][r] += __shfl_xor(ps[m][r], off);
          pd[m][r] += __shfl_xor(pd[m][r], off);
        }
    if (r16 == 0 && wn == 0) {
      #pragma unroll
      for (int m = 0; m < 4; ++m)
        #pragma unroll
        for (int r = 0; r < 4; ++r) {
          int rl = wm + m * 16 + rq * 4 + r;
          ls[rl][0] = ps[m][r];
          ls[rl][1] = pd[m][r];
        }
    }
    __syncthreads();
    if (r16 == 0 && wn != 0) {
      #pragma unroll
      for (int m = 0; m < 4; ++m)
        #pragma unroll
        for (int r = 0; r < 4; ++r) {
          int rl = wm + m * 16 + rq * 4 + r;
          int row = bm + rl;
          if (row < M) {
            lout_s[row] = ls[rl][0] + ps[m][r];
            lout_d[row] = ls[rl][1] + pd[m][r];
          }
        }
    }
  }
}

// ---------- 6. layer-2 aggregation; fast-path softmax + 2-edge pass B ----------
__global__ __launch_bounds__(256)
void agg_h2_kernel(const unsigned short* __restrict__ H,
                   const float* __restrict__ al_s, const float* __restrict__ al_d,
                   const int* __restrict__ rowptr, const int* __restrict__ csr_src,
                   const float* __restrict__ bias, unsigned short* __restrict__ out, int N)
{
  int wv = threadIdx.x >> 6, lane = threadIdx.x & 63;
  int n = blockIdx.x * 4 + wv;
  if (n >= N) return;
  int rs = __builtin_amdgcn_readfirstlane(rowptr[n]);
  int re = __builtin_amdgcn_readfirstlane(rowptr[n + 1]);
  int cnt = re - rs;
  float ald = al_d[n];
  int half = lane >> 5, sub = lane & 31;
  float acc[4] = {0.f, 0.f, 0.f, 0.f};

  auto passB = [&](int c2, int srcA, float wAl) {
    for (int j = 0; j < c2; j += 2) {
      int j1 = j + 1;
      bool has1 = j1 < c2;
      int s0 = __builtin_amdgcn_readlane(srcA, j);
      int s1 = has1 ? __builtin_amdgcn_readlane(srcA, j1) : s0;
      float w0 = readlane_f(wAl, j);
      float w1 = has1 ? readlane_f(wAl, j1) : 0.f;
      float wgt = half ? w1 : w0;
      int src = half ? s1 : s0;
      int2 vv = *(const int2*)(H + (size_t)src * HC + sub * 4);
      acc[0] += wgt * h2f((unsigned short)(vv.x & 0xffff));
      acc[1] += wgt * h2f((unsigned short)((unsigned)vv.x >> 16));
      acc[2] += wgt * h2f((unsigned short)(vv.y & 0xffff));
      acc[3] += wgt * h2f((unsigned short)((unsigned)vv.y >> 16));
    }
  };

  if (cnt <= 64) {
    int srcA = 0;
    float e = -1e30f;
    if (lane < cnt) {
      srcA = csr_src[rs + lane];
      e = leaky02(al_s[srcA] + ald);
    }
    float m = e;
    #pragma unroll
    for (int off = 32; off; off >>= 1) m = fmaxf(m, __shfl_xor(m, off));
    float ex = (lane < cnt) ? __expf(e - m) : 0.f;
    float den = ex;
    #pragma unroll
    for (int off = 32; off; off >>= 1) den += __shfl_xor(den, off);
    passB(cnt, srcA, ex / (den + 1e-16f));
  } else {
    float m = -1e30f, s = 0.f;
    for (int i = rs + lane; i < re; i += 64) {
      int src = csr_src[i];
      float e = leaky02(al_s[src] + ald);
      float Mx = fmaxf(m, e);
      s = s * __expf(m - Mx) + __expf(e - Mx);
      m = Mx;
    }
    #pragma unroll
    for (int off = 32; off; off >>= 1) {
      float m2 = __shfl_xor(m, off);
      float s2 = __shfl_xor(s, off);
      float Mx = fmaxf(m, m2);
      s = s * __expf(m - Mx) + s2 * __expf(m2 - Mx);
      m = Mx;
    }
    float inv_den = 1.f / (s + 1e-16f);
    for (int c0 = rs; c0 < re; c0 += 64) {
      int ccnt = min(64, re - c0);
      int srcA = 0;
      float wAl = 0.f;
      if (lane < ccnt) {
        srcA = csr_src[c0 + lane];
        wAl = __expf(leaky02(al_s[srcA] + ald) - m) * inv_den;
      }
      passB(ccnt, srcA, wAl);
    }
  }

  #pragma unroll
  for (int c = 0; c < 4; ++c) acc[c] += __shfl_xor(acc[c], 32);
  if (lane < 32) {
    float o0 = eluf(acc[0] + bias[sub * 4 + 0]);
    float o1 = eluf(acc[1] + bias[sub * 4 + 1]);
    float o2 = eluf(acc[2] + bias[sub * 4 + 2]);
    float o3 = eluf(acc[3] + bias[sub * 4 + 3]);
    int2 o;
    o.x = (int)f2h(o0) | ((int)f2h(o1) << 16);
    o.y = (int)f2h(o2) | ((int)f2h(o3) << 16);
    *(int2*)&out[(size_t)n * HC + sub * 4] = o;
  }
}

// ---------- 7. global max pool (segmented over sorted batch) ----------
static __device__ __forceinline__ unsigned enc_f(float f)
{
  unsigned u = __float_as_uint(f);
  return (u & 0x80000000u) ? ~u : (u | 0x80000000u);
}
static __device__ __forceinline__ float dec_f(unsigned u)
{
  return (u & 0x80000000u) ? __uint_as_float(u & 0x7fffffffu) : __uint_as_float(~u);
}

#define PNPB 128   // nodes per pool block
__global__ __launch_bounds__(256)
void pool_seg_kernel(const unsigned short* __restrict__ x, const int* __restrict__ batch,
                     unsigned* __restrict__ pool, int N)
{
  int cp = (threadIdx.x & 63) * 2;     // channel pair
  int g  = threadIdx.x >> 6;           // node group 0..3
  int n0 = blockIdx.x * PNPB;
  int n1 = min(n0 + PNPB, N);
  int curb = -1;
  float m0 = 0.f, m1 = 0.f;
  for (int n = n0 + g; n < n1; n += 4) {
    int bg = batch[n];
    ushort2 v = *(const ushort2*)&x[(size_t)n * HC + cp];
    float v0 = h2f(v.x), v1 = h2f(v.y);
    if (bg != curb) {
      if (curb >= 0) {
        atomicMax(&pool[curb * HC + cp],     enc_f(m0));
        atomicMax(&pool[curb * HC + cp + 1], enc_f(m1));
      }
      curb = bg; m0 = v0; m1 = v1;
    } else {
      m0 = fmaxf(m0, v0);
      m1 = fmaxf(m1, v1);
    }
  }
  if (curb >= 0) {
    atomicMax(&pool[curb * HC + cp],     enc_f(m0));
    atomicMax(&pool[curb * HC + cp + 1], enc_f(m1));
  }
}

__global__ void pool_final_kernel(const unsigned* __restrict__ pool, float* __restrict__ out, int n)
{
  int i = blockIdx.x * blockDim.x + threadIdx.x;
  if (i < n) out[i] = dec_f(pool[i]);
}

// ---------- launch ----------
extern "C" void kernel_launch(void* const* d_in, const int* in_sizes, int n_in,
                              void* d_out, int out_size, void* d_ws, size_t ws_size,
                              hipStream_t stream)
{
  const float* x_scalar = (const float*)d_in[0];
  const int* i0 = (const int*)d_in[1];
  const int* i1 = (const int*)d_in[2];
  const int* i2 = (const int*)d_in[3];
  const int* i3 = (const int*)d_in[4];
  const int* i4 = (const int*)d_in[5];
  const int* ei = (const int*)d_in[6];
  const int* batch = (const int*)d_in[7];
  const float* e0 = (const float*)d_in[8];
  const float* e1 = (const float*)d_in[9];
  const float* e2 = (const float*)d_in[10];
  const float* e3 = (const float*)d_in[11];
  const float* e4 = (const float*)d_in[12];
  const float* ln_g = (const float*)d_in[13];
  const float* ln_b = (const float*)d_in[14];
  const float* W1 = (const float*)d_in[15];
  const float* as1 = (const float*)d_in[16];
  const float* ad1 = (const float*)d_in[17];
  const float* b1 = (const float*)d_in[18];
  const float* W2 = (const float*)d_in[19];
  const float* as2 = (const float*)d_in[20];
  const float* ad2 = (const float*)d_in[21];
  const float* b2 = (const float*)d_in[22];

  const int N  = in_sizes[0] / SF;
  const int E  = in_sizes[6] / 2;
  const int Et = E + N;
  const int Bg = out_size / HC;
  const int MT = (N + 127) / 128;

  char* w = (char*)d_ws;
  auto alloc = [&](size_t bytes) -> char* {
    char* p = w;
    w += (bytes + 255) & ~(size_t)255;
    return p;
  };
  unsigned short* featsb = (unsigned short*)alloc((size_t)N * KP1 * 2);
  unsigned short* G      = (unsigned short*)alloc((size_t)4 * N * KP1 * 2);
  unsigned short* X2b    = (unsigned short*)alloc((size_t)N * 512 * 2);
  unsigned short* H2b    = (unsigned short*)alloc((size_t)N * HC * 2);
  unsigned short* X3b    = (unsigned short*)alloc((size_t)N * HC * 2);
  unsigned short* W1t    = (unsigned short*)alloc((size_t)512 * KP1 * 2);
  unsigned short* W2t    = (unsigned short*)alloc((size_t)HC * 512 * 2);
  float* vs      = (float*)alloc((size_t)KP1 * 4 * 4);
  float* vd      = (float*)alloc((size_t)KP1 * 4 * 4);
  float* als1    = (float*)alloc((size_t)N * 4 * 4);
  float* ald1    = (float*)alloc((size_t)N * 4 * 4);
  float* als2    = (float*)alloc((size_t)N * 4);
  float* ald2    = (float*)alloc((size_t)N * 4);
  int*   deg     = (int*)alloc((size_t)N * 4);
  int*   rowptr  = (int*)alloc((size_t)(N + 1) * 4);
  int*   fill    = (int*)alloc((size_t)N * 4);
  int*   csr_src = (int*)alloc((size_t)Et * 4);
  unsigned* pool = (unsigned*)alloc((size_t)Bg * HC * 4);

  // combined prep: W packs, vs/vd, deg zero, pool init (one launch)
  {
    int nb1 = (512 * KP1 + 255) / 256;
    int nb2 = (HC * 512 + 255) / 256;
    int nb3 = (N + 255) / 256;
    int nb4 = (Bg * HC + 255) / 256;
    prep_combined_kernel<<<nb1 + nb2 + nb3 + nb4 + DIN, 256, 0, stream>>>(
        W1, W2, W1t, W2t, as1, ad1, vs, vd, deg, pool, N, Bg * HC);
  }

  // features + LN + fused layer-1 logits (one wave per node, 4 nodes/block)
  feat_ln_kernel<<<(N + 3) / 4, 256, 0, stream>>>(x_scalar, i0, i1, i2, i3, i4,
                                                  e0, e1, e2, e3, e4, ln_g, ln_b,
                                                  (const float4*)vs, (const float4*)vd,
                                                  featsb, als1, ald1, N);

  // CSR
  count_kernel<<<(Et + 255) / 256, 256, 0, stream>>>(ei, E, N, deg);
  scan_kernel<<<1, 1024, 0, stream>>>(deg, rowptr, fill, N);
  scatter_kernel<<<(Et + 255) / 256, 256, 0, stream>>>(ei, E, N, fill, csr_src);

  // layer 1: aggregate feats (4 heads share gather), then per-head GEMM (+b1, ELU)
  agg_feat_kernel<<<(N + 3) / 4, 256, 0, stream>>>(featsb, (const float4*)als1,
                                                   (const float4*)ald1,
                                                   rowptr, csr_src, G, N);
  gemm_f16_kernel<KP1><<<dim3(1, MT, 4), 256, 0, stream>>>(
      G, W1t, X2b, N, 512, (size_t)N * KP1, (size_t)HC * KP1, HC, b1, 1,
      nullptr, nullptr, nullptr, nullptr);

  // layer 2: GEMM with fused logits, then aggregate (+b2, ELU)
  gemm_f16_kernel<512><<<dim3(1, MT, 1), 256, 0, stream>>>(
      X2b, W2t, H2b, N, HC, 0, 0, 0, nullptr, 0,
      as2, ad2, als2, ald2);
  agg_h2_kernel<<<(N + 3) / 4, 256, 0, stream>>>(H2b, als2, ald2, rowptr, csr_src, b2, X3b, N);

  // pool
  pool_seg_kernel<<<(N + PNPB - 1) / PNPB, 256, 0, stream>>>(X3b, batch, pool, N);
  pool_final_kernel<<<(Bg * HC + 255) / 256, 256, 0, stream>>>(pool, (float*)d_out, Bg * HC);
}

// Round 10
// 244.880 us; speedup vs baseline: 1.2436x; 1.0574x over previous
//
#include <hip/hip_runtime.h>
#include <math.h>

#define SF 16
#define ED 32
#define LTOK 20
#define DIN 176
#define KP1 192   // DIN padded to multiple of 32
#define HC 128

typedef _Float16 f16x8 __attribute__((ext_vector_type(8)));
typedef _Float16 f16x2 __attribute__((ext_vector_type(2)));
typedef float f32x4 __attribute__((ext_vector_type(4)));

#if defined(__has_builtin)
#if __has_builtin(__builtin_amdgcn_fdot2)
#define HAVE_FDOT2 1
#endif
#endif

static __device__ __forceinline__ float leaky02(float x) { return x >= 0.f ? x : 0.2f * x; }
static __device__ __forceinline__ float eluf(float x)    { return x > 0.f ? x : expm1f(x); }
static __device__ __forceinline__ unsigned short f2h(float f)
{
  _Float16 h = (_Float16)f;
  return __builtin_bit_cast(unsigned short, h);
}
static __device__ __forceinline__ float h2f(unsigned short u)
{
  return (float)__builtin_bit_cast(_Float16, u);
}
static __device__ __forceinline__ float readlane_f(float v, int j)
{
  return __int_as_float(__builtin_amdgcn_readlane(__float_as_int(v), j));
}
static __device__ __forceinline__ unsigned readlane_u(unsigned v, int j)
{
  return (unsigned)__builtin_amdgcn_readlane((int)v, j);
}
#ifdef HAVE_FDOT2
static __device__ __forceinline__ float dot2(unsigned w, unsigned f, float c)
{
  return __builtin_amdgcn_fdot2(__builtin_bit_cast(f16x2, w),
                                __builtin_bit_cast(f16x2, f), c, false);
}
#endif

// ---------- 0. combined prep: pack W1t/W2t, vs/vd, zero deg, init pool ----------
__global__ __launch_bounds__(256)
void prep_combined_kernel(const float* __restrict__ W1, const float* __restrict__ W2,
                          unsigned short* __restrict__ W1t, unsigned short* __restrict__ W2t,
                          const float* __restrict__ as1, const float* __restrict__ ad1,
                          float* __restrict__ vs, float* __restrict__ vd,
                          int* __restrict__ deg, unsigned* __restrict__ pool,
                          int N, int poolN)
{
  const int nb1 = (512 * KP1 + 255) / 256;
  const int nb2 = (HC * 512 + 255) / 256;
  const int nb3 = (N + 255) / 256;
  const int nb4 = (poolN + 255) / 256;
  int bid = blockIdx.x;
  if (bid < nb1) {                       // W1t [512][KP1] <- W1 [DIN][512]
    int i = bid * 256 + threadIdx.x;
    if (i < 512 * KP1) {
      int n = i / KP1, k = i - n * KP1;
      W1t[i] = f2h((k < DIN) ? W1[(size_t)k * 512 + n] : 0.f);
    }
    return;
  }
  bid -= nb1;
  if (bid < nb2) {                       // W2t [HC][512] <- W2 [512][HC]
    int i = bid * 256 + threadIdx.x;
    if (i < HC * 512) {
      int n = i / 512, k = i - n * 512;
      W2t[i] = f2h(W2[(size_t)k * HC + n]);
    }
    return;
  }
  bid -= nb2;
  if (bid < nb3) {                       // deg = 0
    int i = bid * 256 + threadIdx.x;
    if (i < N) deg[i] = 0;
    return;
  }
  bid -= nb3;
  if (bid < nb4) {                       // pool = enc(-FLT_MAX)
    int i = bid * 256 + threadIdx.x;
    if (i < poolN) pool[i] = 0x00800000u;
    return;
  }
  bid -= nb4;
  {                                      // vs/vd row bid (0..DIN-1)
    int k = bid;
    int h = threadIdx.x >> 6, lane = threadIdx.x & 63;
    const float* row = W1 + (size_t)k * 512 + h * HC;
    float s = row[lane] * as1[h * HC + lane] + row[lane + 64] * as1[h * HC + lane + 64];
    float d = row[lane] * ad1[h * HC + lane] + row[lane + 64] * ad1[h * HC + lane + 64];
    #pragma unroll
    for (int off = 32; off; off >>= 1) { s += __shfl_down(s, off); d += __shfl_down(d, off); }
    if (lane == 0) { vs[k * 4 + h] = s; vd[k * 4 + h] = d; }
  }
}

// ---------- 1. features + LayerNorm + fused logits; ONE WAVE PER NODE ----------
__global__ __launch_bounds__(256)
void feat_ln_kernel(const float* __restrict__ xs,
                    const int* __restrict__ i0, const int* __restrict__ i1,
                    const int* __restrict__ i2, const int* __restrict__ i3,
                    const int* __restrict__ i4,
                    const float* __restrict__ e0, const float* __restrict__ e1,
                    const float* __restrict__ e2, const float* __restrict__ e3,
                    const float* __restrict__ e4,
                    const float* __restrict__ g, const float* __restrict__ b,
                    const float4* __restrict__ vs, const float4* __restrict__ vd,
                    unsigned short* __restrict__ out,
                    float* __restrict__ als, float* __restrict__ ald, int N)
{
  __shared__ int toks[4][5 * LTOK];
  int w = threadIdx.x >> 6, l = threadIdx.x & 63;
  int n = blockIdx.x * 4 + w;
  if (n >= N) return;

  for (int q = l; q < 5 * LTOK; q += 64) {
    int f = q / LTOK, j = q - f * LTOK;
    const int* ip = (f == 0) ? i0 : (f == 1) ? i1 : (f == 2) ? i2 : (f == 3) ? i3 : i4;
    toks[w][q] = ip[n * LTOK + j];
  }

  float v[3];
  #pragma unroll
  for (int r = 0; r < 3; ++r) {
    int c = l + r * 64;
    float val = 0.f;
    if (c < SF) {
      val = xs[n * SF + c];
    } else if (c < DIN) {
      int f  = (c - SF) >> 5;
      int ch = (c - SF) & 31;
      const float* ep = (f == 0) ? e0 : (f == 1) ? e1 : (f == 2) ? e2 : (f == 3) ? e3 : e4;
      float vals[LTOK];
      #pragma unroll
      for (int j = 0; j < LTOK; ++j)
        vals[j] = ep[toks[w][f * LTOK + j] * ED + ch];
      float sum = 0.f, cnt = 0.f;
      #pragma unroll
      for (int j = 0; j < LTOK; ++j)
        if (toks[w][f * LTOK + j] != 0) { sum += vals[j]; cnt += 1.f; }
      val = sum / (cnt + 1e-9f);
    }
    v[r] = val;
  }

  float p  = v[0] + v[1] + v[2];
  float p2 = v[0] * v[0] + v[1] * v[1] + v[2] * v[2];
  #pragma unroll
  for (int off = 32; off; off >>= 1) { p += __shfl_xor(p, off); p2 += __shfl_xor(p2, off); }
  float mu   = p * (1.f / DIN);
  float var  = fmaxf(p2 * (1.f / DIN) - mu * mu, 0.f);
  float rstd = rsqrtf(var + 1e-5f);

  float pr[8] = {0.f, 0.f, 0.f, 0.f, 0.f, 0.f, 0.f, 0.f};
  #pragma unroll
  for (int r = 0; r < 3; ++r) {
    int c = l + r * 64;
    float y = 0.f;
    if (c < DIN) {
      y = (v[r] - mu) * rstd * g[c] + b[c];
      float4 s4 = vs[c], d4 = vd[c];
      pr[0] += y * s4.x; pr[1] += y * s4.y; pr[2] += y * s4.z; pr[3] += y * s4.w;
      pr[4] += y * d4.x; pr[5] += y * d4.y; pr[6] += y * d4.z; pr[7] += y * d4.w;
    }
    if (c < KP1) out[(size_t)n * KP1 + c] = f2h(y);
  }
  #pragma unroll
  for (int j = 0; j < 8; ++j)
    #pragma unroll
    for (int off = 32; off; off >>= 1) pr[j] += __shfl_xor(pr[j], off);
  if (l == 0) {
    als[n * 4 + 0] = pr[0]; als[n * 4 + 1] = pr[1];
    als[n * 4 + 2] = pr[2]; als[n * 4 + 3] = pr[3];
    ald[n * 4 + 0] = pr[4]; ald[n * 4 + 1] = pr[5];
    ald[n * 4 + 2] = pr[6]; ald[n * 4 + 3] = pr[7];
  }
}

// ---------- 2. CSR build ----------
__global__ void count_kernel(const int* __restrict__ ei, int E, int N, int* __restrict__ deg)
{
  int e = blockIdx.x * blockDim.x + threadIdx.x;
  if (e < E + N) {
    int dst = (e < E) ? ei[E + e] : (e - E);
    atomicAdd(&deg[dst], 1);
  }
}

__global__ __launch_bounds__(1024)
void scan_kernel(const int* __restrict__ deg, int* __restrict__ rowptr,
                 int* __restrict__ fill, int N)
{
  __shared__ int sums[1024];
  int t = threadIdx.x;
  int CH = (N + 1023) >> 10;
  int base = t * CH;
  int s = 0;
  for (int i = 0; i < CH; ++i) if (base + i < N) s += deg[base + i];
  sums[t] = s;
  __syncthreads();
  for (int off = 1; off < 1024; off <<= 1) {
    int v = (t >= off) ? sums[t - off] : 0;
    __syncthreads();
    sums[t] += v;
    __syncthreads();
  }
  int run = sums[t] - s;  // exclusive prefix
  for (int i = 0; i < CH; ++i) {
    if (base + i < N) {
      rowptr[base + i] = run;
      fill[base + i]   = run;
      run += deg[base + i];
    }
  }
  if (t == 1023) rowptr[N] = run;
}

__global__ void scatter_kernel(const int* __restrict__ ei, int E, int N,
                               int* __restrict__ fill, int* __restrict__ csr_src)
{
  int e = blockIdx.x * blockDim.x + threadIdx.x;
  if (e < E + N) {
    int src, dst;
    if (e < E) { src = ei[e]; dst = ei[E + e]; }
    else       { src = dst = e - E; }
    int pos = atomicAdd(&fill[dst], 1);
    csr_src[pos] = src;
  }
}

// ---------- 3. layer-1 aggregation over FEATURES ----------
// 4 waves/block (one node per wave). Weights packed to f16 edge-pairs in
// pass A; pass B: lane owns 4 channels, per edge-pair 2x 8B loads + 4 perm
// + 16 v_dot2_f32_f16 (no cvt, 2 MACs/inst).
__global__ __launch_bounds__(256)
void agg_feat_kernel(const unsigned short* __restrict__ F,   // [N][KP1] f16
                     const float4* __restrict__ als, const float4* __restrict__ ald,
                     const int* __restrict__ rowptr, const int* __restrict__ csr_src,
                     unsigned short* __restrict__ G, int N)  // [4][N][KP1] f16
{
  int wv = threadIdx.x >> 6, lane = threadIdx.x & 63;
  int n = blockIdx.x * 4 + wv;
  if (n >= N) return;
  int rs = __builtin_amdgcn_readfirstlane(rowptr[n]);
  int re = __builtin_amdgcn_readfirstlane(rowptr[n + 1]);
  int cnt = re - rs;
  float4 ad4 = ald[n];
  float aldv[4] = { ad4.x, ad4.y, ad4.z, ad4.w };

  float acc[4][4] = {};
  bool act = lane < 48;                      // 48 lanes x 4 ch = 192
  const unsigned short* Fb = F + lane * 4;

#ifdef HAVE_FDOT2
  // pass B over a chunk of <=64 edges whose packed pair-weights are in pkw
  auto passB = [&](int srcA, unsigned pkw[4], int ccnt) {
    for (int j = 0; j < ccnt; j += 2) {
      int s0 = __builtin_amdgcn_readlane(srcA, j);
      int s1 = __builtin_amdgcn_readlane(srcA, j + 1 < 64 ? j + 1 : j);
      unsigned w0 = readlane_u(pkw[0], j);
      unsigned w1 = readlane_u(pkw[1], j);
      unsigned w2 = readlane_u(pkw[2], j);
      unsigned w3 = readlane_u(pkw[3], j);
      if (act) {
        int2 a0 = *(const int2*)(Fb + (size_t)s0 * KP1);
        int2 a1 = *(const int2*)(Fb + (size_t)s1 * KP1);
        unsigned pA = __builtin_amdgcn_perm((unsigned)a0.x, (unsigned)a1.x, 0x01000504u);
        unsigned pB = __builtin_amdgcn_perm((unsigned)a0.x, (unsigned)a1.x, 0x03020706u);
        unsigned pC = __builtin_amdgcn_perm((unsigned)a0.y, (unsigned)a1.y, 0x01000504u);
        unsigned pD = __builtin_amdgcn_perm((unsigned)a0.y, (unsigned)a1.y, 0x03020706u);
        acc[0][0] = dot2(w0, pA, acc[0][0]); acc[0][1] = dot2(w0, pB, acc[0][1]);
        acc[0][2] = dot2(w0, pC, acc[0][2]); acc[0][3] = dot2(w0, pD, acc[0][3]);
        acc[1][0] = dot2(w1, pA, acc[1][0]); acc[1][1] = dot2(w1, pB, acc[1][1]);
        acc[1][2] = dot2(w1, pC, acc[1][2]); acc[1][3] = dot2(w1, pD, acc[1][3]);
        acc[2][0] = dot2(w2, pA, acc[2][0]); acc[2][1] = dot2(w2, pB, acc[2][1]);
        acc[2][2] = dot2(w2, pC, acc[2][2]); acc[2][3] = dot2(w2, pD, acc[2][3]);
        acc[3][0] = dot2(w3, pA, acc[3][0]); acc[3][1] = dot2(w3, pB, acc[3][1]);
        acc[3][2] = dot2(w3, pC, acc[3][2]); acc[3][3] = dot2(w3, pD, acc[3][3]);
      }
    }
  };
#else
  auto passB = [&](int srcA, float wf[4], int ccnt) {
    for (int j = 0; j < ccnt; ++j) {
      int src = __builtin_amdgcn_readlane(srcA, j);
      float q0 = readlane_f(wf[0], j), q1 = readlane_f(wf[1], j);
      float q2 = readlane_f(wf[2], j), q3 = readlane_f(wf[3], j);
      if (act) {
        int2 a0 = *(const int2*)(Fb + (size_t)src * KP1);
        float f0 = h2f((unsigned short)(a0.x & 0xffff));
        float f1 = h2f((unsigned short)((unsigned)a0.x >> 16));
        float f2v = h2f((unsigned short)(a0.y & 0xffff));
        float f3 = h2f((unsigned short)((unsigned)a0.y >> 16));
        acc[0][0] += q0 * f0; acc[0][1] += q0 * f1; acc[0][2] += q0 * f2v; acc[0][3] += q0 * f3;
        acc[1][0] += q1 * f0; acc[1][1] += q1 * f1; acc[1][2] += q1 * f2v; acc[1][3] += q1 * f3;
        acc[2][0] += q2 * f0; acc[2][1] += q2 * f1; acc[2][2] += q2 * f2v; acc[2][3] += q2 * f3;
        acc[3][0] += q3 * f0; acc[3][1] += q3 * f1; acc[3][2] += q3 * f2v; acc[3][3] += q3 * f3;
      }
    }
  };
#endif

  if (cnt <= 64) {
    // fast path: lane j owns edge j
    int srcA = 0;
    float e[4] = { -1e30f, -1e30f, -1e30f, -1e30f };
    if (lane < cnt) {
      srcA = csr_src[rs + lane];
      float4 a4 = als[srcA];
      e[0] = leaky02(a4.x + aldv[0]); e[1] = leaky02(a4.y + aldv[1]);
      e[2] = leaky02(a4.z + aldv[2]); e[3] = leaky02(a4.w + aldv[3]);
    }
    float m[4] = { e[0], e[1], e[2], e[3] };
    #pragma unroll
    for (int off = 32; off; off >>= 1)
      #pragma unroll
      for (int h = 0; h < 4; ++h) m[h] = fmaxf(m[h], __shfl_xor(m[h], off));
    float w[4];
    #pragma unroll
    for (int h = 0; h < 4; ++h) w[h] = (lane < cnt) ? __expf(e[h] - m[h]) : 0.f;
    float den[4] = { w[0], w[1], w[2], w[3] };
    #pragma unroll
    for (int off = 32; off; off >>= 1)
      #pragma unroll
      for (int h = 0; h < 4; ++h) den[h] += __shfl_xor(den[h], off);
    #pragma unroll
    for (int h = 0; h < 4; ++h) w[h] /= (den[h] + 1e-16f);
#ifdef HAVE_FDOT2
    unsigned pkw[4];
    #pragma unroll
    for (int h = 0; h < 4; ++h) {
      float wn = __shfl_xor(w[h], 1);
      float we = (lane & 1) ? wn : w[h];
      float wo = (lane & 1) ? w[h] : wn;
      pkw[h] = (unsigned)f2h(we) | ((unsigned)f2h(wo) << 16);
    }
    passB(srcA, pkw, cnt);
#else
    passB(srcA, w, cnt);
#endif
  } else {
    // slow path: streaming online softmax for m/den, then 64-edge blocks
    float m[4], s[4];
    #pragma unroll
    for (int h = 0; h < 4; ++h) { m[h] = -1e30f; s[h] = 0.f; }
    for (int i = rs + lane; i < re; i += 64) {
      int src = csr_src[i];
      float4 a4 = als[src];
      float av[4] = { a4.x, a4.y, a4.z, a4.w };
      #pragma unroll
      for (int h = 0; h < 4; ++h) {
        float e = leaky02(av[h] + aldv[h]);
        float Mx = fmaxf(m[h], e);
        s[h] = s[h] * __expf(m[h] - Mx) + __expf(e - Mx);
        m[h] = Mx;
      }
    }
    #pragma unroll
    for (int off = 32; off; off >>= 1) {
      #pragma unroll
      for (int h = 0; h < 4; ++h) {
        float m2 = __shfl_xor(m[h], off);
        float s2 = __shfl_xor(s[h], off);
        float Mx = fmaxf(m[h], m2);
        s[h] = s[h] * __expf(m[h] - Mx) + s2 * __expf(m2 - Mx);
        m[h] = Mx;
      }
    }
    float inv[4];
    #pragma unroll
    for (int h = 0; h < 4; ++h) inv[h] = 1.f / (s[h] + 1e-16f);
    for (int b0 = rs; b0 < re; b0 += 64) {
      int bcnt = min(64, re - b0);
      int srcA = 0;
      float w[4] = {0.f, 0.f, 0.f, 0.f};
      if (lane < bcnt) {
        srcA = csr_src[b0 + lane];
        float4 a4 = als[srcA];
        w[0] = __expf(leaky02(a4.x + aldv[0]) - m[0]) * inv[0];
        w[1] = __expf(leaky02(a4.y + aldv[1]) - m[1]) * inv[1];
        w[2] = __expf(leaky02(a4.z + aldv[2]) - m[2]) * inv[2];
        w[3] = __expf(leaky02(a4.w + aldv[3]) - m[3]) * inv[3];
      }
#ifdef HAVE_FDOT2
      unsigned pkw[4];
      #pragma unroll
      for (int h = 0; h < 4; ++h) {
        float wn = __shfl_xor(w[h], 1);
        float we = (lane & 1) ? wn : w[h];
        float wo = (lane & 1) ? w[h] : wn;
        pkw[h] = (unsigned)f2h(we) | ((unsigned)f2h(wo) << 16);
      }
      passB(srcA, pkw, bcnt);
#else
      passB(srcA, w, bcnt);
#endif
    }
  }

  if (act) {
    #pragma unroll
    for (int h = 0; h < 4; ++h) {
      int2 o;
      o.x = (int)f2h(acc[h][0]) | ((int)f2h(acc[h][1]) << 16);
      o.y = (int)f2h(acc[h][2]) | ((int)f2h(acc[h][3]) << 16);
      *(int2*)&G[((size_t)h * N + n) * KP1 + lane * 4] = o;
    }
  }
}

// ---------- 4. MFMA f16 GEMM (+bias/ELU, optional fused row-logits) ----------
template<int KPad>
__global__ __launch_bounds__(256)
void gemm_f16_kernel(const unsigned short* __restrict__ A, const unsigned short* __restrict__ Bt,
                     unsigned short* __restrict__ C, int M, int Nc,
                     size_t aStrideZ, size_t bStrideZ, int cColStrideZ,
                     const float* __restrict__ bias, int act,
                     const float* __restrict__ la_s, const float* __restrict__ la_d,
                     float* __restrict__ lout_s, float* __restrict__ lout_d)
{
  A  += blockIdx.z * aStrideZ;
  Bt += blockIdx.z * bStrideZ;
  int colZ = blockIdx.z * cColStrideZ;

  __shared__ __align__(16) unsigned short As[4][128][8];
  __shared__ __align__(16) unsigned short Bs[4][128][8];
  __shared__ float ls[128][2];
  int tid  = threadIdx.x;
  int lane = tid & 63, wave = tid >> 6;
  int wm = (wave >> 1) << 6, wn = (wave & 1) << 6;
  int bm = blockIdx.y << 7, bn = blockIdx.x << 7;

  int srow = tid >> 1;
  int skc  = (tid & 1) << 1;
  const unsigned short* Arow = A  + (size_t)(bm + srow) * KPad + skc * 8;
  const unsigned short* Brow = Bt + (size_t)(bn + srow) * KPad + skc * 8;
  bool aok = (bm + srow) < M;

  f32x4 acc[4][4];
  #pragma unroll
  for (int m = 0; m < 4; ++m)
    #pragma unroll
    for (int n2 = 0; n2 < 4; ++n2) acc[m][n2] = (f32x4){0.f, 0.f, 0.f, 0.f};

  int kc  = lane >> 4;
  int r16 = lane & 15;

  for (int k0 = 0; k0 < KPad; k0 += 32) {
    int4 av0 = make_int4(0, 0, 0, 0), av1 = make_int4(0, 0, 0, 0);
    if (aok) {
      av0 = *(const int4*)(Arow + k0);
      av1 = *(const int4*)(Arow + k0 + 8);
    }
    int4 bv0 = *(const int4*)(Brow + k0);
    int4 bv1 = *(const int4*)(Brow + k0 + 8);
    __syncthreads();
    *(int4*)&As[skc][srow][0]     = av0;
    *(int4*)&As[skc + 1][srow][0] = av1;
    *(int4*)&Bs[skc][srow][0]     = bv0;
    *(int4*)&Bs[skc + 1][srow][0] = bv1;
    __syncthreads();

    f16x8 af[4], bfr[4];
    #pragma unroll
    for (int m = 0; m < 4; ++m)  af[m]  = *(const f16x8*)&As[kc][wm + m * 16 + r16][0];
    #pragma unroll
    for (int n2 = 0; n2 < 4; ++n2) bfr[n2] = *(const f16x8*)&Bs[kc][wn + n2 * 16 + r16][0];
    #pragma unroll
    for (int m = 0; m < 4; ++m)
      #pragma unroll
      for (int n2 = 0; n2 < 4; ++n2)
        acc[m][n2] = __builtin_amdgcn_mfma_f32_16x16x32_f16(af[m], bfr[n2], acc[m][n2], 0, 0, 0);
  }

  int rq = lane >> 4;
  #pragma unroll
  for (int m = 0; m < 4; ++m) {
    #pragma unroll
    for (int r = 0; r < 4; ++r) {
      int row = bm + wm + m * 16 + rq * 4 + r;
      if (row < M) {
        #pragma unroll
        for (int n2 = 0; n2 < 4; ++n2) {
          int col = colZ + bn + wn + n2 * 16 + r16;
          float val = acc[m][n2][r];
          if (bias) val += bias[col];
          if (act)  val = eluf(val);
          C[(size_t)row * Nc + col] = f2h(val);
        }
      }
    }
  }

  // fused per-row logits (gemm2 only; raw pre-bias values, Nc==128, 1 x-block)
  if (lout_s) {
    float ps[4][4] = {}, pd[4][4] = {};
    #pragma unroll
    for (int m = 0; m < 4; ++m)
      #pragma unroll
      for (int r = 0; r < 4; ++r)
        #pragma unroll
        for (int n2 = 0; n2 < 4; ++n2) {
          int col = wn + n2 * 16 + r16;
          float val = acc[m][n2][r];
          ps[m][r] += val * la_s[col];
          pd[m][r] += val * la_d[col];
        }
    #pragma unroll
    for (int off = 1; off < 16; off <<= 1)
      #pragma unroll
      for (int m = 0; m < 4; ++m)
        #pragma unroll
        for (int r = 0; r < 4; ++r) {
          ps[m][r] += __shfl_xor(ps[m][r], off);
          pd[m][r] += __shfl_xor(pd[m][r], off);
        }
    if (r16 == 0 && wn == 0) {
      #pragma unroll
      for (int m = 0; m < 4; ++m)
        #pragma unroll
        for (int r = 0; r < 4; ++r) {
          int rl = wm + m * 16 + rq * 4 + r;
          ls[rl][0] = ps[m][r];
          ls[rl][1] = pd[m][r];
        }
    }
    __syncthreads();
    if (r16 == 0 && wn != 0) {
      #pragma unroll
      for (int m = 0; m < 4; ++m)
        #pragma unroll
        for (int r = 0; r < 4; ++r) {
          int rl = wm + m * 16 + rq * 4 + r;
          int row = bm + rl;
          if (row < M) {
            lout_s[row] = ls[rl][0] + ps[m][r];
            lout_d[row] = ls[rl][1] + pd[m][r];
          }
        }
    }
  }
}

// ---------- 6. layer-2 aggregation; edge-pair dot2, lane owns 2 channels ----------
__global__ __launch_bounds__(256)
void agg_h2_kernel(const unsigned short* __restrict__ H,
                   const float* __restrict__ al_s, const float* __restrict__ al_d,
                   const int* __restrict__ rowptr, const int* __restrict__ csr_src,
                   const float* __restrict__ bias, unsigned short* __restrict__ out, int N)
{
  int wv = threadIdx.x >> 6, lane = threadIdx.x & 63;
  int n = blockIdx.x * 4 + wv;
  if (n >= N) return;
  int rs = __builtin_amdgcn_readfirstlane(rowptr[n]);
  int re = __builtin_amdgcn_readfirstlane(rowptr[n + 1]);
  int cnt = re - rs;
  float ald = al_d[n];
  float acc0 = 0.f, acc1 = 0.f;
  const unsigned short* Hb = H + lane * 2;   // lane owns channels {2l, 2l+1}

#ifdef HAVE_FDOT2
  auto passB = [&](int srcA, unsigned pkw, int ccnt) {
    for (int j = 0; j < ccnt; j += 2) {
      int s0 = __builtin_amdgcn_readlane(srcA, j);
      int s1 = __builtin_amdgcn_readlane(srcA, j + 1 < 64 ? j + 1 : j);
      unsigned pw = readlane_u(pkw, j);
      unsigned a0 = *(const unsigned*)(Hb + (size_t)s0 * HC);
      unsigned a1 = *(const unsigned*)(Hb + (size_t)s1 * HC);
      unsigned p0 = __builtin_amdgcn_perm(a0, a1, 0x01000504u);
      unsigned p1 = __builtin_amdgcn_perm(a0, a1, 0x03020706u);
      acc0 = dot2(pw, p0, acc0);
      acc1 = dot2(pw, p1, acc1);
    }
  };
#else
  auto passB = [&](int srcA, float wf, int ccnt) {
    for (int j = 0; j < ccnt; ++j) {
      int src = __builtin_amdgcn_readlane(srcA, j);
      float wgt = readlane_f(wf, j);
      unsigned a0 = *(const unsigned*)(Hb + (size_t)src * HC);
      acc0 += wgt * h2f((unsigned short)(a0 & 0xffff));
      acc1 += wgt * h2f((unsigned short)(a0 >> 16));
    }
  };
#endif

  if (cnt <= 64) {
    int srcA = 0;
    float e = -1e30f;
    if (lane < cnt) {
      srcA = csr_src[rs + lane];
      e = leaky02(al_s[srcA] + ald);
    }
    float m = e;
    #pragma unroll
    for (int off = 32; off; off >>= 1) m = fmaxf(m, __shfl_xor(m, off));
    float w = (lane < cnt) ? __expf(e - m) : 0.f;
    float den = w;
    #pragma unroll
    for (int off = 32; off; off >>= 1) den += __shfl_xor(den, off);
    w /= (den + 1e-16f);
#ifdef HAVE_FDOT2
    float wn2 = __shfl_xor(w, 1);
    float we = (lane & 1) ? wn2 : w;
    float wo = (lane & 1) ? w : wn2;
    unsigned pkw = (unsigned)f2h(we) | ((unsigned)f2h(wo) << 16);
    passB(srcA, pkw, cnt);
#else
    passB(srcA, w, cnt);
#endif
  } else {
    float m = -1e30f, s = 0.f;
    for (int i = rs + lane; i < re; i += 64) {
      int src = csr_src[i];
      float e = leaky02(al_s[src] + ald);
      float Mx = fmaxf(m, e);
      s = s * __expf(m - Mx) + __expf(e - Mx);
      m = Mx;
    }
    #pragma unroll
    for (int off = 32; off; off >>= 1) {
      float m2 = __shfl_xor(m, off);
      float s2 = __shfl_xor(s, off);
      float Mx = fmaxf(m, m2);
      s = s * __expf(m - Mx) + s2 * __expf(m2 - Mx);
      m = Mx;
    }
    float inv_den = 1.f / (s + 1e-16f);
    for (int c0 = rs; c0 < re; c0 += 64) {
      int ccnt = min(64, re - c0);
      int srcA = 0;
      float w = 0.f;
      if (lane < ccnt) {
        srcA = csr_src[c0 + lane];
        w = __expf(leaky02(al_s[srcA] + ald) - m) * inv_den;
      }
#ifdef HAVE_FDOT2
      float wn2 = __shfl_xor(w, 1);
      float we = (lane & 1) ? wn2 : w;
      float wo = (lane & 1) ? w : wn2;
      unsigned pkw = (unsigned)f2h(we) | ((unsigned)f2h(wo) << 16);
      passB(srcA, pkw, ccnt);
#else
      passB(srcA, w, ccnt);
#endif
    }
  }

  float o0 = eluf(acc0 + bias[lane * 2 + 0]);
  float o1 = eluf(acc1 + bias[lane * 2 + 1]);
  unsigned o = (unsigned)f2h(o0) | ((unsigned)f2h(o1) << 16);
  *(unsigned*)&out[(size_t)n * HC + lane * 2] = o;
}

// ---------- 7. global max pool (segmented over sorted batch) ----------
static __device__ __forceinline__ unsigned enc_f(float f)
{
  unsigned u = __float_as_uint(f);
  return (u & 0x80000000u) ? ~u : (u | 0x80000000u);
}
static __device__ __forceinline__ float dec_f(unsigned u)
{
  return (u & 0x80000000u) ? __uint_as_float(u & 0x7fffffffu) : __uint_as_float(~u);
}

#define PNPB 128   // nodes per pool block
__global__ __launch_bounds__(256)
void pool_seg_kernel(const unsigned short* __restrict__ x, const int* __restrict__ batch,
                     unsigned* __restrict__ pool, int N)
{
  int cp = (threadIdx.x & 63) * 2;     // channel pair
  int g  = threadIdx.x >> 6;           // node group 0..3
  int n0 = blockIdx.x * PNPB;
  int n1 = min(n0 + PNPB, N);
  int curb = -1;
  float m0 = 0.f, m1 = 0.f;
  for (int n = n0 + g; n < n1; n += 4) {
    int bg = batch[n];
    ushort2 v = *(const ushort2*)&x[(size_t)n * HC + cp];
    float v0 = h2f(v.x), v1 = h2f(v.y);
    if (bg != curb) {
      if (curb >= 0) {
        atomicMax(&pool[curb * HC + cp],     enc_f(m0));
        atomicMax(&pool[curb * HC + cp + 1], enc_f(m1));
      }
      curb = bg; m0 = v0; m1 = v1;
    } else {
      m0 = fmaxf(m0, v0);
      m1 = fmaxf(m1, v1);
    }
  }
  if (curb >= 0) {
    atomicMax(&pool[curb * HC + cp],     enc_f(m0));
    atomicMax(&pool[curb * HC + cp + 1], enc_f(m1));
  }
}

__global__ void pool_final_kernel(const unsigned* __restrict__ pool, float* __restrict__ out, int n)
{
  int i = blockIdx.x * blockDim.x + threadIdx.x;
  if (i < n) out[i] = dec_f(pool[i]);
}

// ---------- launch ----------
extern "C" void kernel_launch(void* const* d_in, const int* in_sizes, int n_in,
                              void* d_out, int out_size, void* d_ws, size_t ws_size,
                              hipStream_t stream)
{
  const float* x_scalar = (const float*)d_in[0];
  const int* i0 = (const int*)d_in[1];
  const int* i1 = (const int*)d_in[2];
  const int* i2 = (const int*)d_in[3];
  const int* i3 = (const int*)d_in[4];
  const int* i4 = (const int*)d_in[5];
  const int* ei = (const int*)d_in[6];
  const int* batch = (const int*)d_in[7];
  const float* e0 = (const float*)d_in[8];
  const float* e1 = (const float*)d_in[9];
  const float* e2 = (const float*)d_in[10];
  const float* e3 = (const float*)d_in[11];
  const float* e4 = (const float*)d_in[12];
  const float* ln_g = (const float*)d_in[13];
  const float* ln_b = (const float*)d_in[14];
  const float* W1 = (const float*)d_in[15];
  const float* as1 = (const float*)d_in[16];
  const float* ad1 = (const float*)d_in[17];
  const float* b1 = (const float*)d_in[18];
  const float* W2 = (const float*)d_in[19];
  const float* as2 = (const float*)d_in[20];
  const float* ad2 = (const float*)d_in[21];
  const float* b2 = (const float*)d_in[22];

  const int N  = in_sizes[0] / SF;
  const int E  = in_sizes[6] / 2;
  const int Et = E + N;
  const int Bg = out_size / HC;
  const int MT = (N + 127) / 128;

  char* w = (char*)d_ws;
  auto alloc = [&](size_t bytes) -> char* {
    char* p = w;
    w += (bytes + 255) & ~(size_t)255;
    return p;
  };
  unsigned short* featsb = (unsigned short*)alloc((size_t)N * KP1 * 2);
  unsigned short* G      = (unsigned short*)alloc((size_t)4 * N * KP1 * 2);
  unsigned short* X2b    = (unsigned short*)alloc((size_t)N * 512 * 2);
  unsigned short* H2b    = (unsigned short*)alloc((size_t)N * HC * 2);
  unsigned short* X3b    = (unsigned short*)alloc((size_t)N * HC * 2);
  unsigned short* W1t    = (unsigned short*)alloc((size_t)512 * KP1 * 2);
  unsigned short* W2t    = (unsigned short*)alloc((size_t)HC * 512 * 2);
  float* vs      = (float*)alloc((size_t)KP1 * 4 * 4);
  float* vd      = (float*)alloc((size_t)KP1 * 4 * 4);
  float* als1    = (float*)alloc((size_t)N * 4 * 4);
  float* ald1    = (float*)alloc((size_t)N * 4 * 4);
  float* als2    = (float*)alloc((size_t)N * 4);
  float* ald2    = (float*)alloc((size_t)N * 4);
  int*   deg     = (int*)alloc((size_t)N * 4);
  int*   rowptr  = (int*)alloc((size_t)(N + 1) * 4);
  int*   fill    = (int*)alloc((size_t)N * 4);
  int*   csr_src = (int*)alloc((size_t)Et * 4);
  unsigned* pool = (unsigned*)alloc((size_t)Bg * HC * 4);

  // combined prep: W packs, vs/vd, deg zero, pool init (one launch)
  {
    int nb1 = (512 * KP1 + 255) / 256;
    int nb2 = (HC * 512 + 255) / 256;
    int nb3 = (N + 255) / 256;
    int nb4 = (Bg * HC + 255) / 256;
    prep_combined_kernel<<<nb1 + nb2 + nb3 + nb4 + DIN, 256, 0, stream>>>(
        W1, W2, W1t, W2t, as1, ad1, vs, vd, deg, pool, N, Bg * HC);
  }

  // features + LN + fused layer-1 logits (one wave per node, 4 nodes/block)
  feat_ln_kernel<<<(N + 3) / 4, 256, 0, stream>>>(x_scalar, i0, i1, i2, i3, i4,
                                                  e0, e1, e2, e3, e4, ln_g, ln_b,
                                                  (const float4*)vs, (const float4*)vd,
                                                  featsb, als1, ald1, N);

  // CSR
  count_kernel<<<(Et + 255) / 256, 256, 0, stream>>>(ei, E, N, deg);
  scan_kernel<<<1, 1024, 0, stream>>>(deg, rowptr, fill, N);
  scatter_kernel<<<(Et + 255) / 256, 256, 0, stream>>>(ei, E, N, fill, csr_src);

  // layer 1: aggregate feats (4 heads share gather), then per-head GEMM (+b1, ELU)
  agg_feat_kernel<<<(N + 3) / 4, 256, 0, stream>>>(featsb, (const float4*)als1,
                                                   (const float4*)ald1,
                                                   rowptr, csr_src, G, N);
  gemm_f16_kernel<KP1><<<dim3(1, MT, 4), 256, 0, stream>>>(
      G, W1t, X2b, N, 512, (size_t)N * KP1, (size_t)HC * KP1, HC, b1, 1,
      nullptr, nullptr, nullptr, nullptr);

  // layer 2: GEMM with fused logits, then aggregate (+b2, ELU)
  gemm_f16_kernel<512><<<dim3(1, MT, 1), 256, 0, stream>>>(
      X2b, W2t, H2b, N, HC, 0, 0, 0, nullptr, 0,
      as2, ad2, als2, ald2);
  agg_h2_kernel<<<(N + 3) / 4, 256, 0, stream>>>(H2b, als2, ald2, rowptr, csr_src, b2, X3b, N);

  // pool
  pool_seg_kernel<<<(N + PNPB - 1) / PNPB, 256, 0, stream>>>(X3b, batch, pool, N);
  pool_final_kernel<<<(Bg * HC + 255) / 256, 256, 0, stream>>>(pool, (float*)d_out, Bg * HC);
}

// Round 11
// 228.386 us; speedup vs baseline: 1.3334x; 1.0722x over previous
//
#include <hip/hip_runtime.h>
#include <math.h>

#define SF 16
#define ED 32
#define LTOK 20
#define DIN 176
#define KP1 192   // DIN padded to multiple of 32
#define HC 128

typedef _Float16 f16x8 __attribute__((ext_vector_type(8)));
typedef _Float16 f16x2 __attribute__((ext_vector_type(2)));
typedef float f32x4 __attribute__((ext_vector_type(4)));

#if defined(__has_builtin)
#if __has_builtin(__builtin_amdgcn_fdot2)
#define HAVE_FDOT2 1
#endif
#endif

static __device__ __forceinline__ float leaky02(float x) { return x >= 0.f ? x : 0.2f * x; }
static __device__ __forceinline__ float eluf(float x)    { return x > 0.f ? x : expm1f(x); }
static __device__ __forceinline__ unsigned short f2h(float f)
{
  _Float16 h = (_Float16)f;
  return __builtin_bit_cast(unsigned short, h);
}
static __device__ __forceinline__ float h2f(unsigned short u)
{
  return (float)__builtin_bit_cast(_Float16, u);
}
static __device__ __forceinline__ float readlane_f(float v, int j)
{
  return __int_as_float(__builtin_amdgcn_readlane(__float_as_int(v), j));
}
static __device__ __forceinline__ unsigned readlane_u(unsigned v, int j)
{
  return (unsigned)__builtin_amdgcn_readlane((int)v, j);
}
#ifdef HAVE_FDOT2
static __device__ __forceinline__ float dot2(unsigned w, unsigned f, float c)
{
  return __builtin_amdgcn_fdot2(__builtin_bit_cast(f16x2, w),
                                __builtin_bit_cast(f16x2, f), c, false);
}
#endif

// ---------- 0. combined prep: pack W1t/W2t, vs/vd, zero deg+als2+ald2, init pool ----------
__global__ __launch_bounds__(256)
void prep_combined_kernel(const float* __restrict__ W1, const float* __restrict__ W2,
                          unsigned short* __restrict__ W1t, unsigned short* __restrict__ W2t,
                          const float* __restrict__ as1, const float* __restrict__ ad1,
                          float* __restrict__ vs, float* __restrict__ vd,
                          int* __restrict__ deg, unsigned* __restrict__ pool,
                          float* __restrict__ als2, float* __restrict__ ald2,
                          int N, int poolN)
{
  const int nb1 = (512 * KP1 + 255) / 256;
  const int nb2 = (HC * 512 + 255) / 256;
  const int nb3 = (N + 255) / 256;
  const int nb4 = (poolN + 255) / 256;
  int bid = blockIdx.x;
  if (bid < nb1) {                       // W1t [512][KP1] <- W1 [DIN][512]
    int i = bid * 256 + threadIdx.x;
    if (i < 512 * KP1) {
      int n = i / KP1, k = i - n * KP1;
      W1t[i] = f2h((k < DIN) ? W1[(size_t)k * 512 + n] : 0.f);
    }
    return;
  }
  bid -= nb1;
  if (bid < nb2) {                       // W2t [HC][512] <- W2 [512][HC]
    int i = bid * 256 + threadIdx.x;
    if (i < HC * 512) {
      int n = i / 512, k = i - n * 512;
      W2t[i] = f2h(W2[(size_t)k * HC + n]);
    }
    return;
  }
  bid -= nb2;
  if (bid < nb3) {                       // deg = 0, als2/ald2 = 0 (atomic targets)
    int i = bid * 256 + threadIdx.x;
    if (i < N) { deg[i] = 0; als2[i] = 0.f; ald2[i] = 0.f; }
    return;
  }
  bid -= nb3;
  if (bid < nb4) {                       // pool = enc(-FLT_MAX)
    int i = bid * 256 + threadIdx.x;
    if (i < poolN) pool[i] = 0x00800000u;
    return;
  }
  bid -= nb4;
  {                                      // vs/vd row bid (0..DIN-1)
    int k = bid;
    int h = threadIdx.x >> 6, lane = threadIdx.x & 63;
    const float* row = W1 + (size_t)k * 512 + h * HC;
    float s = row[lane] * as1[h * HC + lane] + row[lane + 64] * as1[h * HC + lane + 64];
    float d = row[lane] * ad1[h * HC + lane] + row[lane + 64] * ad1[h * HC + lane + 64];
    #pragma unroll
    for (int off = 32; off; off >>= 1) { s += __shfl_down(s, off); d += __shfl_down(d, off); }
    if (lane == 0) { vs[k * 4 + h] = s; vd[k * 4 + h] = d; }
  }
}

// ---------- 1. features + LayerNorm + fused logits; ONE WAVE PER NODE ----------
__global__ __launch_bounds__(256)
void feat_ln_kernel(const float* __restrict__ xs,
                    const int* __restrict__ i0, const int* __restrict__ i1,
                    const int* __restrict__ i2, const int* __restrict__ i3,
                    const int* __restrict__ i4,
                    const float* __restrict__ e0, const float* __restrict__ e1,
                    const float* __restrict__ e2, const float* __restrict__ e3,
                    const float* __restrict__ e4,
                    const float* __restrict__ g, const float* __restrict__ b,
                    const float4* __restrict__ vs, const float4* __restrict__ vd,
                    unsigned short* __restrict__ out,
                    float* __restrict__ als, float* __restrict__ ald, int N)
{
  __shared__ int toks[4][5 * LTOK];
  int w = threadIdx.x >> 6, l = threadIdx.x & 63;
  int n = blockIdx.x * 4 + w;
  if (n >= N) return;

  for (int q = l; q < 5 * LTOK; q += 64) {
    int f = q / LTOK, j = q - f * LTOK;
    const int* ip = (f == 0) ? i0 : (f == 1) ? i1 : (f == 2) ? i2 : (f == 3) ? i3 : i4;
    toks[w][q] = ip[n * LTOK + j];
  }

  float v[3];
  #pragma unroll
  for (int r = 0; r < 3; ++r) {
    int c = l + r * 64;
    float val = 0.f;
    if (c < SF) {
      val = xs[n * SF + c];
    } else if (c < DIN) {
      int f  = (c - SF) >> 5;
      int ch = (c - SF) & 31;
      const float* ep = (f == 0) ? e0 : (f == 1) ? e1 : (f == 2) ? e2 : (f == 3) ? e3 : e4;
      float vals[LTOK];
      #pragma unroll
      for (int j = 0; j < LTOK; ++j)
        vals[j] = ep[toks[w][f * LTOK + j] * ED + ch];
      float sum = 0.f, cnt = 0.f;
      #pragma unroll
      for (int j = 0; j < LTOK; ++j)
        if (toks[w][f * LTOK + j] != 0) { sum += vals[j]; cnt += 1.f; }
      val = sum / (cnt + 1e-9f);
    }
    v[r] = val;
  }

  float p  = v[0] + v[1] + v[2];
  float p2 = v[0] * v[0] + v[1] * v[1] + v[2] * v[2];
  #pragma unroll
  for (int off = 32; off; off >>= 1) { p += __shfl_xor(p, off); p2 += __shfl_xor(p2, off); }
  float mu   = p * (1.f / DIN);
  float var  = fmaxf(p2 * (1.f / DIN) - mu * mu, 0.f);
  float rstd = rsqrtf(var + 1e-5f);

  float pr[8] = {0.f, 0.f, 0.f, 0.f, 0.f, 0.f, 0.f, 0.f};
  #pragma unroll
  for (int r = 0; r < 3; ++r) {
    int c = l + r * 64;
    float y = 0.f;
    if (c < DIN) {
      y = (v[r] - mu) * rstd * g[c] + b[c];
      float4 s4 = vs[c], d4 = vd[c];
      pr[0] += y * s4.x; pr[1] += y * s4.y; pr[2] += y * s4.z; pr[3] += y * s4.w;
      pr[4] += y * d4.x; pr[5] += y * d4.y; pr[6] += y * d4.z; pr[7] += y * d4.w;
    }
    if (c < KP1) out[(size_t)n * KP1 + c] = f2h(y);
  }
  #pragma unroll
  for (int j = 0; j < 8; ++j)
    #pragma unroll
    for (int off = 32; off; off >>= 1) pr[j] += __shfl_xor(pr[j], off);
  if (l == 0) {
    als[n * 4 + 0] = pr[0]; als[n * 4 + 1] = pr[1];
    als[n * 4 + 2] = pr[2]; als[n * 4 + 3] = pr[3];
    ald[n * 4 + 0] = pr[4]; ald[n * 4 + 1] = pr[5];
    ald[n * 4 + 2] = pr[6]; ald[n * 4 + 3] = pr[7];
  }
}

// ---------- 2. CSR build ----------
__global__ void count_kernel(const int* __restrict__ ei, int E, int N, int* __restrict__ deg)
{
  int e = blockIdx.x * blockDim.x + threadIdx.x;
  if (e < E + N) {
    int dst = (e < E) ? ei[E + e] : (e - E);
    atomicAdd(&deg[dst], 1);
  }
}

__global__ __launch_bounds__(1024)
void scan_kernel(const int* __restrict__ deg, int* __restrict__ rowptr,
                 int* __restrict__ fill, int N)
{
  __shared__ int sums[1024];
  int t = threadIdx.x;
  int CH = (N + 1023) >> 10;
  int base = t * CH;
  int s = 0;
  for (int i = 0; i < CH; ++i) if (base + i < N) s += deg[base + i];
  sums[t] = s;
  __syncthreads();
  for (int off = 1; off < 1024; off <<= 1) {
    int v = (t >= off) ? sums[t - off] : 0;
    __syncthreads();
    sums[t] += v;
    __syncthreads();
  }
  int run = sums[t] - s;  // exclusive prefix
  for (int i = 0; i < CH; ++i) {
    if (base + i < N) {
      rowptr[base + i] = run;
      fill[base + i]   = run;
      run += deg[base + i];
    }
  }
  if (t == 1023) rowptr[N] = run;
}

__global__ void scatter_kernel(const int* __restrict__ ei, int E, int N,
                               int* __restrict__ fill, int* __restrict__ csr_src)
{
  int e = blockIdx.x * blockDim.x + threadIdx.x;
  if (e < E + N) {
    int src, dst;
    if (e < E) { src = ei[e]; dst = ei[E + e]; }
    else       { src = dst = e - E; }
    int pos = atomicAdd(&fill[dst], 1);
    csr_src[pos] = src;
  }
}

// ---------- 3. layer-1 aggregation over FEATURES (fdot2 edge-pair) ----------
__global__ __launch_bounds__(256)
void agg_feat_kernel(const unsigned short* __restrict__ F,   // [N][KP1] f16
                     const float4* __restrict__ als, const float4* __restrict__ ald,
                     const int* __restrict__ rowptr, const int* __restrict__ csr_src,
                     unsigned short* __restrict__ G, int N)  // [4][N][KP1] f16
{
  int wv = threadIdx.x >> 6, lane = threadIdx.x & 63;
  int n = blockIdx.x * 4 + wv;
  if (n >= N) return;
  int rs = __builtin_amdgcn_readfirstlane(rowptr[n]);
  int re = __builtin_amdgcn_readfirstlane(rowptr[n + 1]);
  int cnt = re - rs;
  float4 ad4 = ald[n];
  float aldv[4] = { ad4.x, ad4.y, ad4.z, ad4.w };

  float acc[4][4] = {};
  bool act = lane < 48;                      // 48 lanes x 4 ch = 192
  const unsigned short* Fb = F + lane * 4;

#ifdef HAVE_FDOT2
  auto passB = [&](int srcA, unsigned pkw[4], int ccnt) {
    for (int j = 0; j < ccnt; j += 2) {
      int s0 = __builtin_amdgcn_readlane(srcA, j);
      int s1 = __builtin_amdgcn_readlane(srcA, j + 1 < 64 ? j + 1 : j);
      unsigned w0 = readlane_u(pkw[0], j);
      unsigned w1 = readlane_u(pkw[1], j);
      unsigned w2 = readlane_u(pkw[2], j);
      unsigned w3 = readlane_u(pkw[3], j);
      if (act) {
        int2 a0 = *(const int2*)(Fb + (size_t)s0 * KP1);
        int2 a1 = *(const int2*)(Fb + (size_t)s1 * KP1);
        unsigned pA = __builtin_amdgcn_perm((unsigned)a0.x, (unsigned)a1.x, 0x01000504u);
        unsigned pB = __builtin_amdgcn_perm((unsigned)a0.x, (unsigned)a1.x, 0x03020706u);
        unsigned pC = __builtin_amdgcn_perm((unsigned)a0.y, (unsigned)a1.y, 0x01000504u);
        unsigned pD = __builtin_amdgcn_perm((unsigned)a0.y, (unsigned)a1.y, 0x03020706u);
        acc[0][0] = dot2(w0, pA, acc[0][0]); acc[0][1] = dot2(w0, pB, acc[0][1]);
        acc[0][2] = dot2(w0, pC, acc[0][2]); acc[0][3] = dot2(w0, pD, acc[0][3]);
        acc[1][0] = dot2(w1, pA, acc[1][0]); acc[1][1] = dot2(w1, pB, acc[1][1]);
        acc[1][2] = dot2(w1, pC, acc[1][2]); acc[1][3] = dot2(w1, pD, acc[1][3]);
        acc[2][0] = dot2(w2, pA, acc[2][0]); acc[2][1] = dot2(w2, pB, acc[2][1]);
        acc[2][2] = dot2(w2, pC, acc[2][2]); acc[2][3] = dot2(w2, pD, acc[2][3]);
        acc[3][0] = dot2(w3, pA, acc[3][0]); acc[3][1] = dot2(w3, pB, acc[3][1]);
        acc[3][2] = dot2(w3, pC, acc[3][2]); acc[3][3] = dot2(w3, pD, acc[3][3]);
      }
    }
  };
#else
  auto passB = [&](int srcA, float wf[4], int ccnt) {
    for (int j = 0; j < ccnt; ++j) {
      int src = __builtin_amdgcn_readlane(srcA, j);
      float q0 = readlane_f(wf[0], j), q1 = readlane_f(wf[1], j);
      float q2 = readlane_f(wf[2], j), q3 = readlane_f(wf[3], j);
      if (act) {
        int2 a0 = *(const int2*)(Fb + (size_t)src * KP1);
        float f0 = h2f((unsigned short)(a0.x & 0xffff));
        float f1 = h2f((unsigned short)((unsigned)a0.x >> 16));
        float f2v = h2f((unsigned short)(a0.y & 0xffff));
        float f3 = h2f((unsigned short)((unsigned)a0.y >> 16));
        acc[0][0] += q0 * f0; acc[0][1] += q0 * f1; acc[0][2] += q0 * f2v; acc[0][3] += q0 * f3;
        acc[1][0] += q1 * f0; acc[1][1] += q1 * f1; acc[1][2] += q1 * f2v; acc[1][3] += q1 * f3;
        acc[2][0] += q2 * f0; acc[2][1] += q2 * f1; acc[2][2] += q2 * f2v; acc[2][3] += q2 * f3;
        acc[3][0] += q3 * f0; acc[3][1] += q3 * f1; acc[3][2] += q3 * f2v; acc[3][3] += q3 * f3;
      }
    }
  };
#endif

  if (cnt <= 64) {
    int srcA = 0;
    float e[4] = { -1e30f, -1e30f, -1e30f, -1e30f };
    if (lane < cnt) {
      srcA = csr_src[rs + lane];
      float4 a4 = als[srcA];
      e[0] = leaky02(a4.x + aldv[0]); e[1] = leaky02(a4.y + aldv[1]);
      e[2] = leaky02(a4.z + aldv[2]); e[3] = leaky02(a4.w + aldv[3]);
    }
    float m[4] = { e[0], e[1], e[2], e[3] };
    #pragma unroll
    for (int off = 32; off; off >>= 1)
      #pragma unroll
      for (int h = 0; h < 4; ++h) m[h] = fmaxf(m[h], __shfl_xor(m[h], off));
    float w[4];
    #pragma unroll
    for (int h = 0; h < 4; ++h) w[h] = (lane < cnt) ? __expf(e[h] - m[h]) : 0.f;
    float den[4] = { w[0], w[1], w[2], w[3] };
    #pragma unroll
    for (int off = 32; off; off >>= 1)
      #pragma unroll
      for (int h = 0; h < 4; ++h) den[h] += __shfl_xor(den[h], off);
    #pragma unroll
    for (int h = 0; h < 4; ++h) w[h] /= (den[h] + 1e-16f);
#ifdef HAVE_FDOT2
    unsigned pkw[4];
    #pragma unroll
    for (int h = 0; h < 4; ++h) {
      float wn = __shfl_xor(w[h], 1);
      float we = (lane & 1) ? wn : w[h];
      float wo = (lane & 1) ? w[h] : wn;
      pkw[h] = (unsigned)f2h(we) | ((unsigned)f2h(wo) << 16);
    }
    passB(srcA, pkw, cnt);
#else
    passB(srcA, w, cnt);
#endif
  } else {
    float m[4], s[4];
    #pragma unroll
    for (int h = 0; h < 4; ++h) { m[h] = -1e30f; s[h] = 0.f; }
    for (int i = rs + lane; i < re; i += 64) {
      int src = csr_src[i];
      float4 a4 = als[src];
      float av[4] = { a4.x, a4.y, a4.z, a4.w };
      #pragma unroll
      for (int h = 0; h < 4; ++h) {
        float e = leaky02(av[h] + aldv[h]);
        float Mx = fmaxf(m[h], e);
        s[h] = s[h] * __expf(m[h] - Mx) + __expf(e - Mx);
        m[h] = Mx;
      }
    }
    #pragma unroll
    for (int off = 32; off; off >>= 1) {
      #pragma unroll
      for (int h = 0; h < 4; ++h) {
        float m2 = __shfl_xor(m[h], off);
        float s2 = __shfl_xor(s[h], off);
        float Mx = fmaxf(m[h], m2);
        s[h] = s[h] * __expf(m[h] - Mx) + s2 * __expf(m2 - Mx);
        m[h] = Mx;
      }
    }
    float inv[4];
    #pragma unroll
    for (int h = 0; h < 4; ++h) inv[h] = 1.f / (s[h] + 1e-16f);
    for (int b0 = rs; b0 < re; b0 += 64) {
      int bcnt = min(64, re - b0);
      int srcA = 0;
      float w[4] = {0.f, 0.f, 0.f, 0.f};
      if (lane < bcnt) {
        srcA = csr_src[b0 + lane];
        float4 a4 = als[srcA];
        w[0] = __expf(leaky02(a4.x + aldv[0]) - m[0]) * inv[0];
        w[1] = __expf(leaky02(a4.y + aldv[1]) - m[1]) * inv[1];
        w[2] = __expf(leaky02(a4.z + aldv[2]) - m[2]) * inv[2];
        w[3] = __expf(leaky02(a4.w + aldv[3]) - m[3]) * inv[3];
      }
#ifdef HAVE_FDOT2
      unsigned pkw[4];
      #pragma unroll
      for (int h = 0; h < 4; ++h) {
        float wn = __shfl_xor(w[h], 1);
        float we = (lane & 1) ? wn : w[h];
        float wo = (lane & 1) ? w[h] : wn;
        pkw[h] = (unsigned)f2h(we) | ((unsigned)f2h(wo) << 16);
      }
      passB(srcA, pkw, bcnt);
#else
      passB(srcA, w, bcnt);
#endif
    }
  }

  if (act) {
    #pragma unroll
    for (int h = 0; h < 4; ++h) {
      int2 o;
      o.x = (int)f2h(acc[h][0]) | ((int)f2h(acc[h][1]) << 16);
      o.y = (int)f2h(acc[h][2]) | ((int)f2h(acc[h][3]) << 16);
      *(int2*)&G[((size_t)h * N + n) * KP1 + lane * 4] = o;
    }
  }
}

// ---------- 4. MFMA f16 GEMM, 64x64 tile, 4 waves, reg-prefetch dbuf ----------
// LDS slabs padded to 520 ushorts so kc-groups start at banks {0,4,8,12}.
// Optional fused per-row logits via f32 atomicAdd (gemm2; raw pre-bias acc).
template<int KPad, int BIAS_ELU, int LOGITS>
__global__ __launch_bounds__(256)
void gemm64_kernel(const unsigned short* __restrict__ A,
                   const unsigned short* __restrict__ Bt,
                   unsigned short* __restrict__ C,
                   int M, int Nc,
                   size_t aStrideZ, size_t bStrideZ, int cColStrideZ,
                   const float* __restrict__ bias,
                   const float* __restrict__ la_s, const float* __restrict__ la_d,
                   float* __restrict__ lout_s, float* __restrict__ lout_d)
{
  A  += blockIdx.z * aStrideZ;
  Bt += blockIdx.z * bStrideZ;
  const int colZ = blockIdx.z * cColStrideZ;

  __shared__ __align__(16) unsigned short As[4][520];
  __shared__ __align__(16) unsigned short Bs[4][520];

  const int tid  = threadIdx.x;
  const int lane = tid & 63, wv = tid >> 6;
  const int bm = blockIdx.y << 6, bn = blockIdx.x << 6;
  const int wm = (wv >> 1) << 5, wn = (wv & 1) << 5;
  const int kc = lane >> 4, r16 = lane & 15;

  // staging map: thread t -> k-octet (t>>6), row (t&63)
  const int srow = lane, skc = wv;
  const unsigned short* Ap = A + (size_t)(bm + srow) * KPad + skc * 8;
  const unsigned short* Bp = Bt + (size_t)(bn + srow) * KPad + skc * 8;
  const bool aok = (bm + srow) < M;

  f32x4 acc[2][2];
  #pragma unroll
  for (int m = 0; m < 2; ++m)
    #pragma unroll
    for (int n2 = 0; n2 < 2; ++n2) acc[m][n2] = (f32x4){0.f, 0.f, 0.f, 0.f};

  constexpr int NT = KPad / 32;
  int4 av = aok ? *(const int4*)Ap : make_int4(0, 0, 0, 0);
  int4 bv = *(const int4*)Bp;

  for (int t = 0; t < NT; ++t) {
    *(int4*)&As[skc][srow * 8] = av;
    *(int4*)&Bs[skc][srow * 8] = bv;
    if (t + 1 < NT) {          // issue next-step loads early (hide under barrier+MFMA)
      av = aok ? *(const int4*)(Ap + (t + 1) * 32) : make_int4(0, 0, 0, 0);
      bv = *(const int4*)(Bp + (t + 1) * 32);
    }
    __syncthreads();
    f16x8 af0 = *(const f16x8*)&As[kc][(wm + r16) * 8];
    f16x8 af1 = *(const f16x8*)&As[kc][(wm + 16 + r16) * 8];
    f16x8 bf0 = *(const f16x8*)&Bs[kc][(wn + r16) * 8];
    f16x8 bf1 = *(const f16x8*)&Bs[kc][(wn + 16 + r16) * 8];
    acc[0][0] = __builtin_amdgcn_mfma_f32_16x16x32_f16(af0, bf0, acc[0][0], 0, 0, 0);
    acc[0][1] = __builtin_amdgcn_mfma_f32_16x16x32_f16(af0, bf1, acc[0][1], 0, 0, 0);
    acc[1][0] = __builtin_amdgcn_mfma_f32_16x16x32_f16(af1, bf0, acc[1][0], 0, 0, 0);
    acc[1][1] = __builtin_amdgcn_mfma_f32_16x16x32_f16(af1, bf1, acc[1][1], 0, 0, 0);
    __syncthreads();
  }

  const int rq = lane >> 4;
  #pragma unroll
  for (int m = 0; m < 2; ++m) {
    #pragma unroll
    for (int r = 0; r < 4; ++r) {
      int row = bm + wm + m * 16 + rq * 4 + r;
      if (row < M) {
        #pragma unroll
        for (int n2 = 0; n2 < 2; ++n2) {
          int col = colZ + bn + wn + n2 * 16 + r16;
          float val = acc[m][n2][r];
          if (BIAS_ELU) { val += bias[col]; val = eluf(val); }
          C[(size_t)row * Nc + col] = f2h(val);
        }
      }
    }
  }

  if (LOGITS) {
    #pragma unroll
    for (int m = 0; m < 2; ++m) {
      #pragma unroll
      for (int r = 0; r < 4; ++r) {
        float ps = 0.f, pd = 0.f;
        #pragma unroll
        for (int n2 = 0; n2 < 2; ++n2) {
          int col = bn + wn + n2 * 16 + r16;
          float val = acc[m][n2][r];
          ps += val * la_s[col];
          pd += val * la_d[col];
        }
        #pragma unroll
        for (int off = 1; off < 16; off <<= 1) {
          ps += __shfl_xor(ps, off);
          pd += __shfl_xor(pd, off);
        }
        int row = bm + wm + m * 16 + rq * 4 + r;
        if (r16 == 0 && row < M) {
          atomicAdd(&lout_s[row], ps);
          atomicAdd(&lout_d[row], pd);
        }
      }
    }
  }
}

// ---------- 6. layer-2 aggregation; edge-pair dot2, lane owns 2 channels ----------
__global__ __launch_bounds__(256)
void agg_h2_kernel(const unsigned short* __restrict__ H,
                   const float* __restrict__ al_s, const float* __restrict__ al_d,
                   const int* __restrict__ rowptr, const int* __restrict__ csr_src,
                   const float* __restrict__ bias, unsigned short* __restrict__ out, int N)
{
  int wv = threadIdx.x >> 6, lane = threadIdx.x & 63;
  int n = blockIdx.x * 4 + wv;
  if (n >= N) return;
  int rs = __builtin_amdgcn_readfirstlane(rowptr[n]);
  int re = __builtin_amdgcn_readfirstlane(rowptr[n + 1]);
  int cnt = re - rs;
  float ald = al_d[n];
  float acc0 = 0.f, acc1 = 0.f;
  const unsigned short* Hb = H + lane * 2;   // lane owns channels {2l, 2l+1}

#ifdef HAVE_FDOT2
  auto passB = [&](int srcA, unsigned pkw, int ccnt) {
    for (int j = 0; j < ccnt; j += 2) {
      int s0 = __builtin_amdgcn_readlane(srcA, j);
      int s1 = __builtin_amdgcn_readlane(srcA, j + 1 < 64 ? j + 1 : j);
      unsigned pw = readlane_u(pkw, j);
      unsigned a0 = *(const unsigned*)(Hb + (size_t)s0 * HC);
      unsigned a1 = *(const unsigned*)(Hb + (size_t)s1 * HC);
      unsigned p0 = __builtin_amdgcn_perm(a0, a1, 0x01000504u);
      unsigned p1 = __builtin_amdgcn_perm(a0, a1, 0x03020706u);
      acc0 = dot2(pw, p0, acc0);
      acc1 = dot2(pw, p1, acc1);
    }
  };
#else
  auto passB = [&](int srcA, float wf, int ccnt) {
    for (int j = 0; j < ccnt; ++j) {
      int src = __builtin_amdgcn_readlane(srcA, j);
      float wgt = readlane_f(wf, j);
      unsigned a0 = *(const unsigned*)(Hb + (size_t)src * HC);
      acc0 += wgt * h2f((unsigned short)(a0 & 0xffff));
      acc1 += wgt * h2f((unsigned short)(a0 >> 16));
    }
  };
#endif

  if (cnt <= 64) {
    int srcA = 0;
    float e = -1e30f;
    if (lane < cnt) {
      srcA = csr_src[rs + lane];
      e = leaky02(al_s[srcA] + ald);
    }
    float m = e;
    #pragma unroll
    for (int off = 32; off; off >>= 1) m = fmaxf(m, __shfl_xor(m, off));
    float w = (lane < cnt) ? __expf(e - m) : 0.f;
    float den = w;
    #pragma unroll
    for (int off = 32; off; off >>= 1) den += __shfl_xor(den, off);
    w /= (den + 1e-16f);
#ifdef HAVE_FDOT2
    float wn2 = __shfl_xor(w, 1);
    float we = (lane & 1) ? wn2 : w;
    float wo = (lane & 1) ? w : wn2;
    unsigned pkw = (unsigned)f2h(we) | ((unsigned)f2h(wo) << 16);
    passB(srcA, pkw, cnt);
#else
    passB(srcA, w, cnt);
#endif
  } else {
    float m = -1e30f, s = 0.f;
    for (int i = rs + lane; i < re; i += 64) {
      int src = csr_src[i];
      float e = leaky02(al_s[src] + ald);
      float Mx = fmaxf(m, e);
      s = s * __expf(m - Mx) + __expf(e - Mx);
      m = Mx;
    }
    #pragma unroll
    for (int off = 32; off; off >>= 1) {
      float m2 = __shfl_xor(m, off);
      float s2 = __shfl_xor(s, off);
      float Mx = fmaxf(m, m2);
      s = s * __expf(m - Mx) + s2 * __expf(m2 - Mx);
      m = Mx;
    }
    float inv_den = 1.f / (s + 1e-16f);
    for (int c0 = rs; c0 < re; c0 += 64) {
      int ccnt = min(64, re - c0);
      int srcA = 0;
      float w = 0.f;
      if (lane < ccnt) {
        srcA = csr_src[c0 + lane];
        w = __expf(leaky02(al_s[srcA] + ald) - m) * inv_den;
      }
#ifdef HAVE_FDOT2
      float wn2 = __shfl_xor(w, 1);
      float we = (lane & 1) ? wn2 : w;
      float wo = (lane & 1) ? w : wn2;
      unsigned pkw = (unsigned)f2h(we) | ((unsigned)f2h(wo) << 16);
      passB(srcA, pkw, ccnt);
#else
      passB(srcA, w, ccnt);
#endif
    }
  }

  float o0 = eluf(acc0 + bias[lane * 2 + 0]);
  float o1 = eluf(acc1 + bias[lane * 2 + 1]);
  unsigned o = (unsigned)f2h(o0) | ((unsigned)f2h(o1) << 16);
  *(unsigned*)&out[(size_t)n * HC + lane * 2] = o;
}

// ---------- 7. global max pool (segmented over sorted batch) ----------
static __device__ __forceinline__ unsigned enc_f(float f)
{
  unsigned u = __float_as_uint(f);
  return (u & 0x80000000u) ? ~u : (u | 0x80000000u);
}
static __device__ __forceinline__ float dec_f(unsigned u)
{
  return (u & 0x80000000u) ? __uint_as_float(u & 0x7fffffffu) : __uint_as_float(~u);
}

#define PNPB 128   // nodes per pool block
__global__ __launch_bounds__(256)
void pool_seg_kernel(const unsigned short* __restrict__ x, const int* __restrict__ batch,
                     unsigned* __restrict__ pool, int N)
{
  int cp = (threadIdx.x & 63) * 2;     // channel pair
  int g  = threadIdx.x >> 6;           // node group 0..3
  int n0 = blockIdx.x * PNPB;
  int n1 = min(n0 + PNPB, N);
  int curb = -1;
  float m0 = 0.f, m1 = 0.f;
  for (int n = n0 + g; n < n1; n += 4) {
    int bg = batch[n];
    ushort2 v = *(const ushort2*)&x[(size_t)n * HC + cp];
    float v0 = h2f(v.x), v1 = h2f(v.y);
    if (bg != curb) {
      if (curb >= 0) {
        atomicMax(&pool[curb * HC + cp],     enc_f(m0));
        atomicMax(&pool[curb * HC + cp + 1], enc_f(m1));
      }
      curb = bg; m0 = v0; m1 = v1;
    } else {
      m0 = fmaxf(m0, v0);
      m1 = fmaxf(m1, v1);
    }
  }
  if (curb >= 0) {
    atomicMax(&pool[curb * HC + cp],     enc_f(m0));
    atomicMax(&pool[curb * HC + cp + 1], enc_f(m1));
  }
}

__global__ void pool_final_kernel(const unsigned* __restrict__ pool, float* __restrict__ out, int n)
{
  int i = blockIdx.x * blockDim.x + threadIdx.x;
  if (i < n) out[i] = dec_f(pool[i]);
}

// ---------- launch ----------
extern "C" void kernel_launch(void* const* d_in, const int* in_sizes, int n_in,
                              void* d_out, int out_size, void* d_ws, size_t ws_size,
                              hipStream_t stream)
{
  const float* x_scalar = (const float*)d_in[0];
  const int* i0 = (const int*)d_in[1];
  const int* i1 = (const int*)d_in[2];
  const int* i2 = (const int*)d_in[3];
  const int* i3 = (const int*)d_in[4];
  const int* i4 = (const int*)d_in[5];
  const int* ei = (const int*)d_in[6];
  const int* batch = (const int*)d_in[7];
  const float* e0 = (const float*)d_in[8];
  const float* e1 = (const float*)d_in[9];
  const float* e2 = (const float*)d_in[10];
  const float* e3 = (const float*)d_in[11];
  const float* e4 = (const float*)d_in[12];
  const float* ln_g = (const float*)d_in[13];
  const float* ln_b = (const float*)d_in[14];
  const float* W1 = (const float*)d_in[15];
  const float* as1 = (const float*)d_in[16];
  const float* ad1 = (const float*)d_in[17];
  const float* b1 = (const float*)d_in[18];
  const float* W2 = (const float*)d_in[19];
  const float* as2 = (const float*)d_in[20];
  const float* ad2 = (const float*)d_in[21];
  const float* b2 = (const float*)d_in[22];

  const int N  = in_sizes[0] / SF;
  const int E  = in_sizes[6] / 2;
  const int Et = E + N;
  const int Bg = out_size / HC;
  const int MT64 = (N + 63) / 64;

  char* w = (char*)d_ws;
  auto alloc = [&](size_t bytes) -> char* {
    char* p = w;
    w += (bytes + 255) & ~(size_t)255;
    return p;
  };
  unsigned short* featsb = (unsigned short*)alloc((size_t)N * KP1 * 2);
  unsigned short* G      = (unsigned short*)alloc((size_t)4 * N * KP1 * 2);
  unsigned short* X2b    = (unsigned short*)alloc((size_t)N * 512 * 2);
  unsigned short* H2b    = (unsigned short*)alloc((size_t)N * HC * 2);
  unsigned short* X3b    = (unsigned short*)alloc((size_t)N * HC * 2);
  unsigned short* W1t    = (unsigned short*)alloc((size_t)512 * KP1 * 2);
  unsigned short* W2t    = (unsigned short*)alloc((size_t)HC * 512 * 2);
  float* vs      = (float*)alloc((size_t)KP1 * 4 * 4);
  float* vd      = (float*)alloc((size_t)KP1 * 4 * 4);
  float* als1    = (float*)alloc((size_t)N * 4 * 4);
  float* ald1    = (float*)alloc((size_t)N * 4 * 4);
  float* als2    = (float*)alloc((size_t)N * 4);
  float* ald2    = (float*)alloc((size_t)N * 4);
  int*   deg     = (int*)alloc((size_t)N * 4);
  int*   rowptr  = (int*)alloc((size_t)(N + 1) * 4);
  int*   fill    = (int*)alloc((size_t)N * 4);
  int*   csr_src = (int*)alloc((size_t)Et * 4);
  unsigned* pool = (unsigned*)alloc((size_t)Bg * HC * 4);

  // combined prep: W packs, vs/vd, deg+als2/ald2 zero, pool init (one launch)
  {
    int nb1 = (512 * KP1 + 255) / 256;
    int nb2 = (HC * 512 + 255) / 256;
    int nb3 = (N + 255) / 256;
    int nb4 = (Bg * HC + 255) / 256;
    prep_combined_kernel<<<nb1 + nb2 + nb3 + nb4 + DIN, 256, 0, stream>>>(
        W1, W2, W1t, W2t, as1, ad1, vs, vd, deg, pool, als2, ald2, N, Bg * HC);
  }

  // features + LN + fused layer-1 logits (one wave per node, 4 nodes/block)
  feat_ln_kernel<<<(N + 3) / 4, 256, 0, stream>>>(x_scalar, i0, i1, i2, i3, i4,
                                                  e0, e1, e2, e3, e4, ln_g, ln_b,
                                                  (const float4*)vs, (const float4*)vd,
                                                  featsb, als1, ald1, N);

  // CSR
  count_kernel<<<(Et + 255) / 256, 256, 0, stream>>>(ei, E, N, deg);
  scan_kernel<<<1, 1024, 0, stream>>>(deg, rowptr, fill, N);
  scatter_kernel<<<(Et + 255) / 256, 256, 0, stream>>>(ei, E, N, fill, csr_src);

  // layer 1: aggregate feats, then per-head GEMM (+b1, ELU); 64x64 tiles
  agg_feat_kernel<<<(N + 3) / 4, 256, 0, stream>>>(featsb, (const float4*)als1,
                                                   (const float4*)ald1,
                                                   rowptr, csr_src, G, N);
  gemm64_kernel<KP1, 1, 0><<<dim3(2, MT64, 4), 256, 0, stream>>>(
      G, W1t, X2b, N, 512, (size_t)N * KP1, (size_t)HC * KP1, HC, b1,
      nullptr, nullptr, nullptr, nullptr);

  // layer 2: GEMM with fused logits (atomicAdd), then aggregate (+b2, ELU)
  gemm64_kernel<512, 0, 1><<<dim3(2, MT64, 1), 256, 0, stream>>>(
      X2b, W2t, H2b, N, HC, 0, 0, 0, nullptr,
      as2, ad2, als2, ald2);
  agg_h2_kernel<<<(N + 3) / 4, 256, 0, stream>>>(H2b, als2, ald2, rowptr, csr_src, b2, X3b, N);

  // pool
  pool_seg_kernel<<<(N + PNPB - 1) / PNPB, 256, 0, stream>>>(X3b, batch, pool, N);
  pool_final_kernel<<<(Bg * HC + 255) / 256, 256, 0, stream>>>(pool, (float*)d_out, Bg * HC);
}

// Round 12
// 221.743 us; speedup vs baseline: 1.3734x; 1.0300x over previous
//
#include <hip/hip_runtime.h>
#include <math.h>

#define SF 16
#define ED 32
#define LTOK 20
#define DIN 176
#define KP1 192   // DIN padded to multiple of 32
#define HC 128

typedef _Float16 f16x8 __attribute__((ext_vector_type(8)));
typedef _Float16 f16x2 __attribute__((ext_vector_type(2)));
typedef float f32x4 __attribute__((ext_vector_type(4)));

#if defined(__has_builtin)
#if __has_builtin(__builtin_amdgcn_fdot2)
#define HAVE_FDOT2 1
#endif
#endif

static __device__ __forceinline__ float leaky02(float x) { return x >= 0.f ? x : 0.2f * x; }
static __device__ __forceinline__ float eluf(float x)    { return x > 0.f ? x : expm1f(x); }
static __device__ __forceinline__ unsigned short f2h(float f)
{
  _Float16 h = (_Float16)f;
  return __builtin_bit_cast(unsigned short, h);
}
static __device__ __forceinline__ float h2f(unsigned short u)
{
  return (float)__builtin_bit_cast(_Float16, u);
}
static __device__ __forceinline__ float readlane_f(float v, int j)
{
  return __int_as_float(__builtin_amdgcn_readlane(__float_as_int(v), j));
}
static __device__ __forceinline__ unsigned readlane_u(unsigned v, int j)
{
  return (unsigned)__builtin_amdgcn_readlane((int)v, j);
}
#ifdef HAVE_FDOT2
static __device__ __forceinline__ float dot2(unsigned w, unsigned f, float c)
{
  return __builtin_amdgcn_fdot2(__builtin_bit_cast(f16x2, w),
                                __builtin_bit_cast(f16x2, f), c, false);
}
#endif

// ---------- 0. combined prep: pack W1t/W2t, vs/vd, zero deg+als2+ald2, init pool ----------
__global__ __launch_bounds__(256)
void prep_combined_kernel(const float* __restrict__ W1, const float* __restrict__ W2,
                          unsigned short* __restrict__ W1t, unsigned short* __restrict__ W2t,
                          const float* __restrict__ as1, const float* __restrict__ ad1,
                          float* __restrict__ vs, float* __restrict__ vd,
                          int* __restrict__ deg, unsigned* __restrict__ pool,
                          float* __restrict__ als2, float* __restrict__ ald2,
                          int N, int poolN)
{
  const int nb1 = (512 * KP1 + 255) / 256;
  const int nb2 = (HC * 512 + 255) / 256;
  const int nb3 = (N + 255) / 256;
  const int nb4 = (poolN + 255) / 256;
  int bid = blockIdx.x;
  if (bid < nb1) {                       // W1t [512][KP1] <- W1 [DIN][512]
    int i = bid * 256 + threadIdx.x;
    if (i < 512 * KP1) {
      int n = i / KP1, k = i - n * KP1;
      W1t[i] = f2h((k < DIN) ? W1[(size_t)k * 512 + n] : 0.f);
    }
    return;
  }
  bid -= nb1;
  if (bid < nb2) {                       // W2t [HC][512] <- W2 [512][HC]
    int i = bid * 256 + threadIdx.x;
    if (i < HC * 512) {
      int n = i / 512, k = i - n * 512;
      W2t[i] = f2h(W2[(size_t)k * HC + n]);
    }
    return;
  }
  bid -= nb2;
  if (bid < nb3) {                       // deg = 0, als2/ald2 = 0 (atomic targets)
    int i = bid * 256 + threadIdx.x;
    if (i < N) { deg[i] = 0; als2[i] = 0.f; ald2[i] = 0.f; }
    return;
  }
  bid -= nb3;
  if (bid < nb4) {                       // pool = enc(-FLT_MAX)
    int i = bid * 256 + threadIdx.x;
    if (i < poolN) pool[i] = 0x00800000u;
    return;
  }
  bid -= nb4;
  {                                      // vs/vd row bid (0..DIN-1)
    int k = bid;
    int h = threadIdx.x >> 6, lane = threadIdx.x & 63;
    const float* row = W1 + (size_t)k * 512 + h * HC;
    float s = row[lane] * as1[h * HC + lane] + row[lane + 64] * as1[h * HC + lane + 64];
    float d = row[lane] * ad1[h * HC + lane] + row[lane + 64] * ad1[h * HC + lane + 64];
    #pragma unroll
    for (int off = 32; off; off >>= 1) { s += __shfl_down(s, off); d += __shfl_down(d, off); }
    if (lane == 0) { vs[k * 4 + h] = s; vd[k * 4 + h] = d; }
  }
}

// ---------- 1. features + LayerNorm + fused logits; ONE WAVE PER NODE ----------
__global__ __launch_bounds__(256)
void feat_ln_kernel(const float* __restrict__ xs,
                    const int* __restrict__ i0, const int* __restrict__ i1,
                    const int* __restrict__ i2, const int* __restrict__ i3,
                    const int* __restrict__ i4,
                    const float* __restrict__ e0, const float* __restrict__ e1,
                    const float* __restrict__ e2, const float* __restrict__ e3,
                    const float* __restrict__ e4,
                    const float* __restrict__ g, const float* __restrict__ b,
                    const float4* __restrict__ vs, const float4* __restrict__ vd,
                    unsigned short* __restrict__ out,
                    float* __restrict__ als, float* __restrict__ ald, int N)
{
  __shared__ int toks[4][5 * LTOK];
  int w = threadIdx.x >> 6, l = threadIdx.x & 63;
  int n = blockIdx.x * 4 + w;
  if (n >= N) return;

  for (int q = l; q < 5 * LTOK; q += 64) {
    int f = q / LTOK, j = q - f * LTOK;
    const int* ip = (f == 0) ? i0 : (f == 1) ? i1 : (f == 2) ? i2 : (f == 3) ? i3 : i4;
    toks[w][q] = ip[n * LTOK + j];
  }

  float v[3];
  #pragma unroll
  for (int r = 0; r < 3; ++r) {
    int c = l + r * 64;
    float val = 0.f;
    if (c < SF) {
      val = xs[n * SF + c];
    } else if (c < DIN) {
      int f  = (c - SF) >> 5;
      int ch = (c - SF) & 31;
      const float* ep = (f == 0) ? e0 : (f == 1) ? e1 : (f == 2) ? e2 : (f == 3) ? e3 : e4;
      float vals[LTOK];
      #pragma unroll
      for (int j = 0; j < LTOK; ++j)
        vals[j] = ep[toks[w][f * LTOK + j] * ED + ch];
      float sum = 0.f, cnt = 0.f;
      #pragma unroll
      for (int j = 0; j < LTOK; ++j)
        if (toks[w][f * LTOK + j] != 0) { sum += vals[j]; cnt += 1.f; }
      val = sum / (cnt + 1e-9f);
    }
    v[r] = val;
  }

  float p  = v[0] + v[1] + v[2];
  float p2 = v[0] * v[0] + v[1] * v[1] + v[2] * v[2];
  #pragma unroll
  for (int off = 32; off; off >>= 1) { p += __shfl_xor(p, off); p2 += __shfl_xor(p2, off); }
  float mu   = p * (1.f / DIN);
  float var  = fmaxf(p2 * (1.f / DIN) - mu * mu, 0.f);
  float rstd = rsqrtf(var + 1e-5f);

  float pr[8] = {0.f, 0.f, 0.f, 0.f, 0.f, 0.f, 0.f, 0.f};
  #pragma unroll
  for (int r = 0; r < 3; ++r) {
    int c = l + r * 64;
    float y = 0.f;
    if (c < DIN) {
      y = (v[r] - mu) * rstd * g[c] + b[c];
      float4 s4 = vs[c], d4 = vd[c];
      pr[0] += y * s4.x; pr[1] += y * s4.y; pr[2] += y * s4.z; pr[3] += y * s4.w;
      pr[4] += y * d4.x; pr[5] += y * d4.y; pr[6] += y * d4.z; pr[7] += y * d4.w;
    }
    if (c < KP1) out[(size_t)n * KP1 + c] = f2h(y);
  }
  #pragma unroll
  for (int j = 0; j < 8; ++j)
    #pragma unroll
    for (int off = 32; off; off >>= 1) pr[j] += __shfl_xor(pr[j], off);
  if (l == 0) {
    als[n * 4 + 0] = pr[0]; als[n * 4 + 1] = pr[1];
    als[n * 4 + 2] = pr[2]; als[n * 4 + 3] = pr[3];
    ald[n * 4 + 0] = pr[4]; ald[n * 4 + 1] = pr[5];
    ald[n * 4 + 2] = pr[6]; ald[n * 4 + 3] = pr[7];
  }
}

// ---------- 2. CSR build ----------
__global__ void count_kernel(const int* __restrict__ ei, int E, int N, int* __restrict__ deg)
{
  int e = blockIdx.x * blockDim.x + threadIdx.x;
  if (e < E + N) {
    int dst = (e < E) ? ei[E + e] : (e - E);
    atomicAdd(&deg[dst], 1);
  }
}

__global__ __launch_bounds__(1024)
void scan_kernel(const int* __restrict__ deg, int* __restrict__ rowptr,
                 int* __restrict__ fill, int N)
{
  __shared__ int sums[1024];
  int t = threadIdx.x;
  int CH = (N + 1023) >> 10;
  int base = t * CH;
  int s = 0;
  for (int i = 0; i < CH; ++i) if (base + i < N) s += deg[base + i];
  sums[t] = s;
  __syncthreads();
  for (int off = 1; off < 1024; off <<= 1) {
    int v = (t >= off) ? sums[t - off] : 0;
    __syncthreads();
    sums[t] += v;
    __syncthreads();
  }
  int run = sums[t] - s;  // exclusive prefix
  for (int i = 0; i < CH; ++i) {
    if (base + i < N) {
      rowptr[base + i] = run;
      fill[base + i]   = run;
      run += deg[base + i];
    }
  }
  if (t == 1023) rowptr[N] = run;
}

__global__ void scatter_kernel(const int* __restrict__ ei, int E, int N,
                               int* __restrict__ fill, int* __restrict__ csr_src)
{
  int e = blockIdx.x * blockDim.x + threadIdx.x;
  if (e < E + N) {
    int src, dst;
    if (e < E) { src = ei[e]; dst = ei[E + e]; }
    else       { src = dst = e - E; }
    int pos = atomicAdd(&fill[dst], 1);
    csr_src[pos] = src;
  }
}

// ---------- 3. layer-1 aggregation over FEATURES (fdot2, 4-edge unrolled) ----------
// Tail handling via weight-zero padding: lanes >= cnt carry w=0 and srcA=0,
// so readlanes past cnt contribute nothing (gather row 0 with w=0).
__global__ __launch_bounds__(256)
void agg_feat_kernel(const unsigned short* __restrict__ F,   // [N][KP1] f16
                     const float4* __restrict__ als, const float4* __restrict__ ald,
                     const int* __restrict__ rowptr, const int* __restrict__ csr_src,
                     unsigned short* __restrict__ G, int N)  // [4][N][KP1] f16
{
  int wv = threadIdx.x >> 6, lane = threadIdx.x & 63;
  int n = blockIdx.x * 4 + wv;
  if (n >= N) return;
  int rs = __builtin_amdgcn_readfirstlane(rowptr[n]);
  int re = __builtin_amdgcn_readfirstlane(rowptr[n + 1]);
  int cnt = re - rs;
  float4 ad4 = ald[n];
  float aldv[4] = { ad4.x, ad4.y, ad4.z, ad4.w };

  float acc[4][4] = {};
  bool act = lane < 48;                      // 48 lanes x 4 ch = 192
  const unsigned short* Fb = F + lane * 4;

#ifdef HAVE_FDOT2
  auto passB = [&](int srcA, unsigned pkw[4], int ccnt) {
    for (int j = 0; j < ccnt; j += 4) {      // 4 edges per iteration
      int s0 = __builtin_amdgcn_readlane(srcA, j);
      int s1 = __builtin_amdgcn_readlane(srcA, j + 1);
      int s2 = __builtin_amdgcn_readlane(srcA, j + 2);
      int s3 = __builtin_amdgcn_readlane(srcA, j + 3);
      unsigned wa0 = readlane_u(pkw[0], j), wb0 = readlane_u(pkw[0], j + 2);
      unsigned wa1 = readlane_u(pkw[1], j), wb1 = readlane_u(pkw[1], j + 2);
      unsigned wa2 = readlane_u(pkw[2], j), wb2 = readlane_u(pkw[2], j + 2);
      unsigned wa3 = readlane_u(pkw[3], j), wb3 = readlane_u(pkw[3], j + 2);
      if (act) {
        int2 a0 = *(const int2*)(Fb + (size_t)s0 * KP1);
        int2 a1 = *(const int2*)(Fb + (size_t)s1 * KP1);
        int2 a2 = *(const int2*)(Fb + (size_t)s2 * KP1);
        int2 a3 = *(const int2*)(Fb + (size_t)s3 * KP1);
        unsigned pA = __builtin_amdgcn_perm((unsigned)a0.x, (unsigned)a1.x, 0x01000504u);
        unsigned pB = __builtin_amdgcn_perm((unsigned)a0.x, (unsigned)a1.x, 0x03020706u);
        unsigned pC = __builtin_amdgcn_perm((unsigned)a0.y, (unsigned)a1.y, 0x01000504u);
        unsigned pD = __builtin_amdgcn_perm((unsigned)a0.y, (unsigned)a1.y, 0x03020706u);
        unsigned qA = __builtin_amdgcn_perm((unsigned)a2.x, (unsigned)a3.x, 0x01000504u);
        unsigned qB = __builtin_amdgcn_perm((unsigned)a2.x, (unsigned)a3.x, 0x03020706u);
        unsigned qC = __builtin_amdgcn_perm((unsigned)a2.y, (unsigned)a3.y, 0x01000504u);
        unsigned qD = __builtin_amdgcn_perm((unsigned)a2.y, (unsigned)a3.y, 0x03020706u);
        acc[0][0] = dot2(wa0, pA, acc[0][0]); acc[0][1] = dot2(wa0, pB, acc[0][1]);
        acc[0][2] = dot2(wa0, pC, acc[0][2]); acc[0][3] = dot2(wa0, pD, acc[0][3]);
        acc[1][0] = dot2(wa1, pA, acc[1][0]); acc[1][1] = dot2(wa1, pB, acc[1][1]);
        acc[1][2] = dot2(wa1, pC, acc[1][2]); acc[1][3] = dot2(wa1, pD, acc[1][3]);
        acc[2][0] = dot2(wa2, pA, acc[2][0]); acc[2][1] = dot2(wa2, pB, acc[2][1]);
        acc[2][2] = dot2(wa2, pC, acc[2][2]); acc[2][3] = dot2(wa2, pD, acc[2][3]);
        acc[3][0] = dot2(wa3, pA, acc[3][0]); acc[3][1] = dot2(wa3, pB, acc[3][1]);
        acc[3][2] = dot2(wa3, pC, acc[3][2]); acc[3][3] = dot2(wa3, pD, acc[3][3]);
        acc[0][0] = dot2(wb0, qA, acc[0][0]); acc[0][1] = dot2(wb0, qB, acc[0][1]);
        acc[0][2] = dot2(wb0, qC, acc[0][2]); acc[0][3] = dot2(wb0, qD, acc[0][3]);
        acc[1][0] = dot2(wb1, qA, acc[1][0]); acc[1][1] = dot2(wb1, qB, acc[1][1]);
        acc[1][2] = dot2(wb1, qC, acc[1][2]); acc[1][3] = dot2(wb1, qD, acc[1][3]);
        acc[2][0] = dot2(wb2, qA, acc[2][0]); acc[2][1] = dot2(wb2, qB, acc[2][1]);
        acc[2][2] = dot2(wb2, qC, acc[2][2]); acc[2][3] = dot2(wb2, qD, acc[2][3]);
        acc[3][0] = dot2(wb3, qA, acc[3][0]); acc[3][1] = dot2(wb3, qB, acc[3][1]);
        acc[3][2] = dot2(wb3, qC, acc[3][2]); acc[3][3] = dot2(wb3, qD, acc[3][3]);
      }
    }
  };
#else
  auto passB = [&](int srcA, float wf[4], int ccnt) {
    for (int j = 0; j < ccnt; ++j) {
      int src = __builtin_amdgcn_readlane(srcA, j);
      float q0 = readlane_f(wf[0], j), q1 = readlane_f(wf[1], j);
      float q2 = readlane_f(wf[2], j), q3 = readlane_f(wf[3], j);
      if (act) {
        int2 a0 = *(const int2*)(Fb + (size_t)src * KP1);
        float f0 = h2f((unsigned short)(a0.x & 0xffff));
        float f1 = h2f((unsigned short)((unsigned)a0.x >> 16));
        float f2v = h2f((unsigned short)(a0.y & 0xffff));
        float f3 = h2f((unsigned short)((unsigned)a0.y >> 16));
        acc[0][0] += q0 * f0; acc[0][1] += q0 * f1; acc[0][2] += q0 * f2v; acc[0][3] += q0 * f3;
        acc[1][0] += q1 * f0; acc[1][1] += q1 * f1; acc[1][2] += q1 * f2v; acc[1][3] += q1 * f3;
        acc[2][0] += q2 * f0; acc[2][1] += q2 * f1; acc[2][2] += q2 * f2v; acc[2][3] += q2 * f3;
        acc[3][0] += q3 * f0; acc[3][1] += q3 * f1; acc[3][2] += q3 * f2v; acc[3][3] += q3 * f3;
      }
    }
  };
#endif

  if (cnt <= 64) {
    int srcA = 0;
    float e[4] = { -1e30f, -1e30f, -1e30f, -1e30f };
    if (lane < cnt) {
      srcA = csr_src[rs + lane];
      float4 a4 = als[srcA];
      e[0] = leaky02(a4.x + aldv[0]); e[1] = leaky02(a4.y + aldv[1]);
      e[2] = leaky02(a4.z + aldv[2]); e[3] = leaky02(a4.w + aldv[3]);
    }
    float m[4] = { e[0], e[1], e[2], e[3] };
    #pragma unroll
    for (int off = 32; off; off >>= 1)
      #pragma unroll
      for (int h = 0; h < 4; ++h) m[h] = fmaxf(m[h], __shfl_xor(m[h], off));
    float w[4];
    #pragma unroll
    for (int h = 0; h < 4; ++h) w[h] = (lane < cnt) ? __expf(e[h] - m[h]) : 0.f;
    float den[4] = { w[0], w[1], w[2], w[3] };
    #pragma unroll
    for (int off = 32; off; off >>= 1)
      #pragma unroll
      for (int h = 0; h < 4; ++h) den[h] += __shfl_xor(den[h], off);
    #pragma unroll
    for (int h = 0; h < 4; ++h) w[h] /= (den[h] + 1e-16f);
#ifdef HAVE_FDOT2
    unsigned pkw[4];
    #pragma unroll
    for (int h = 0; h < 4; ++h) {
      float wn = __shfl_xor(w[h], 1);
      float we = (lane & 1) ? wn : w[h];
      float wo = (lane & 1) ? w[h] : wn;
      pkw[h] = (unsigned)f2h(we) | ((unsigned)f2h(wo) << 16);
    }
    passB(srcA, pkw, cnt);
#else
    passB(srcA, w, cnt);
#endif
  } else {
    float m[4], s[4];
    #pragma unroll
    for (int h = 0; h < 4; ++h) { m[h] = -1e30f; s[h] = 0.f; }
    for (int i = rs + lane; i < re; i += 64) {
      int src = csr_src[i];
      float4 a4 = als[src];
      float av[4] = { a4.x, a4.y, a4.z, a4.w };
      #pragma unroll
      for (int h = 0; h < 4; ++h) {
        float e = leaky02(av[h] + aldv[h]);
        float Mx = fmaxf(m[h], e);
        s[h] = s[h] * __expf(m[h] - Mx) + __expf(e - Mx);
        m[h] = Mx;
      }
    }
    #pragma unroll
    for (int off = 32; off; off >>= 1) {
      #pragma unroll
      for (int h = 0; h < 4; ++h) {
        float m2 = __shfl_xor(m[h], off);
        float s2 = __shfl_xor(s[h], off);
        float Mx = fmaxf(m[h], m2);
        s[h] = s[h] * __expf(m[h] - Mx) + s2 * __expf(m2 - Mx);
        m[h] = Mx;
      }
    }
    float inv[4];
    #pragma unroll
    for (int h = 0; h < 4; ++h) inv[h] = 1.f / (s[h] + 1e-16f);
    for (int b0 = rs; b0 < re; b0 += 64) {
      int bcnt = min(64, re - b0);
      int srcA = 0;
      float w[4] = {0.f, 0.f, 0.f, 0.f};
      if (lane < bcnt) {
        srcA = csr_src[b0 + lane];
        float4 a4 = als[srcA];
        w[0] = __expf(leaky02(a4.x + aldv[0]) - m[0]) * inv[0];
        w[1] = __expf(leaky02(a4.y + aldv[1]) - m[1]) * inv[1];
        w[2] = __expf(leaky02(a4.z + aldv[2]) - m[2]) * inv[2];
        w[3] = __expf(leaky02(a4.w + aldv[3]) - m[3]) * inv[3];
      }
#ifdef HAVE_FDOT2
      unsigned pkw[4];
      #pragma unroll
      for (int h = 0; h < 4; ++h) {
        float wn = __shfl_xor(w[h], 1);
        float we = (lane & 1) ? wn : w[h];
        float wo = (lane & 1) ? w[h] : wn;
        pkw[h] = (unsigned)f2h(we) | ((unsigned)f2h(wo) << 16);
      }
      passB(srcA, pkw, bcnt);
#else
      passB(srcA, w, bcnt);
#endif
    }
  }

  if (act) {
    #pragma unroll
    for (int h = 0; h < 4; ++h) {
      int2 o;
      o.x = (int)f2h(acc[h][0]) | ((int)f2h(acc[h][1]) << 16);
      o.y = (int)f2h(acc[h][2]) | ((int)f2h(acc[h][3]) << 16);
      *(int2*)&G[((size_t)h * N + n) * KP1 + lane * 4] = o;
    }
  }
}

// ---------- 4. MFMA f16 GEMM, 64x64 tile, DOUBLE-BUFFERED LDS (1 barrier/K-step) ----------
// Write of step t+1 targets the buffer not being read -> no WAR barrier needed.
template<int KPad, int BIAS_ELU, int LOGITS>
__global__ __launch_bounds__(256)
void gemm64_kernel(const unsigned short* __restrict__ A,
                   const unsigned short* __restrict__ Bt,
                   unsigned short* __restrict__ C,
                   int M, int Nc,
                   size_t aStrideZ, size_t bStrideZ, int cColStrideZ,
                   const float* __restrict__ bias,
                   const float* __restrict__ la_s, const float* __restrict__ la_d,
                   float* __restrict__ lout_s, float* __restrict__ lout_d)
{
  A  += blockIdx.z * aStrideZ;
  Bt += blockIdx.z * bStrideZ;
  const int colZ = blockIdx.z * cColStrideZ;

  __shared__ __align__(16) unsigned short As[2][4][520];
  __shared__ __align__(16) unsigned short Bs[2][4][520];

  const int tid  = threadIdx.x;
  const int lane = tid & 63, wv = tid >> 6;
  const int bm = blockIdx.y << 6, bn = blockIdx.x << 6;
  const int wm = (wv >> 1) << 5, wn = (wv & 1) << 5;
  const int kc = lane >> 4, r16 = lane & 15;

  const int srow = lane, skc = wv;
  const unsigned short* Ap = A + (size_t)(bm + srow) * KPad + skc * 8;
  const unsigned short* Bp = Bt + (size_t)(bn + srow) * KPad + skc * 8;
  const bool aok = (bm + srow) < M;

  f32x4 acc[2][2];
  #pragma unroll
  for (int m = 0; m < 2; ++m)
    #pragma unroll
    for (int n2 = 0; n2 < 2; ++n2) acc[m][n2] = (f32x4){0.f, 0.f, 0.f, 0.f};

  constexpr int NT = KPad / 32;
  int4 av = aok ? *(const int4*)Ap : make_int4(0, 0, 0, 0);
  int4 bv = *(const int4*)Bp;

  for (int t = 0; t < NT; ++t) {
    const int cur = t & 1;
    *(int4*)&As[cur][skc][srow * 8] = av;
    *(int4*)&Bs[cur][skc][srow * 8] = bv;
    if (t + 1 < NT) {          // prefetch next step while this one computes
      av = aok ? *(const int4*)(Ap + (t + 1) * 32) : make_int4(0, 0, 0, 0);
      bv = *(const int4*)(Bp + (t + 1) * 32);
    }
    __syncthreads();
    f16x8 af0 = *(const f16x8*)&As[cur][kc][(wm + r16) * 8];
    f16x8 af1 = *(const f16x8*)&As[cur][kc][(wm + 16 + r16) * 8];
    f16x8 bf0 = *(const f16x8*)&Bs[cur][kc][(wn + r16) * 8];
    f16x8 bf1 = *(const f16x8*)&Bs[cur][kc][(wn + 16 + r16) * 8];
    acc[0][0] = __builtin_amdgcn_mfma_f32_16x16x32_f16(af0, bf0, acc[0][0], 0, 0, 0);
    acc[0][1] = __builtin_amdgcn_mfma_f32_16x16x32_f16(af0, bf1, acc[0][1], 0, 0, 0);
    acc[1][0] = __builtin_amdgcn_mfma_f32_16x16x32_f16(af1, bf0, acc[1][0], 0, 0, 0);
    acc[1][1] = __builtin_amdgcn_mfma_f32_16x16x32_f16(af1, bf1, acc[1][1], 0, 0, 0);
  }

  const int rq = lane >> 4;
  #pragma unroll
  for (int m = 0; m < 2; ++m) {
    #pragma unroll
    for (int r = 0; r < 4; ++r) {
      int row = bm + wm + m * 16 + rq * 4 + r;
      if (row < M) {
        #pragma unroll
        for (int n2 = 0; n2 < 2; ++n2) {
          int col = colZ + bn + wn + n2 * 16 + r16;
          float val = acc[m][n2][r];
          if (BIAS_ELU) { val += bias[col]; val = eluf(val); }
          C[(size_t)row * Nc + col] = f2h(val);
        }
      }
    }
  }

  if (LOGITS) {
    #pragma unroll
    for (int m = 0; m < 2; ++m) {
      #pragma unroll
      for (int r = 0; r < 4; ++r) {
        float ps = 0.f, pd = 0.f;
        #pragma unroll
        for (int n2 = 0; n2 < 2; ++n2) {
          int col = bn + wn + n2 * 16 + r16;
          float val = acc[m][n2][r];
          ps += val * la_s[col];
          pd += val * la_d[col];
        }
        #pragma unroll
        for (int off = 1; off < 16; off <<= 1) {
          ps += __shfl_xor(ps, off);
          pd += __shfl_xor(pd, off);
        }
        int row = bm + wm + m * 16 + rq * 4 + r;
        if (r16 == 0 && row < M) {
          atomicAdd(&lout_s[row], ps);
          atomicAdd(&lout_d[row], pd);
        }
      }
    }
  }
}

// ---------- 6. layer-2 aggregation; fdot2 4-edge unrolled, lane owns 2 channels ----------
__global__ __launch_bounds__(256)
void agg_h2_kernel(const unsigned short* __restrict__ H,
                   const float* __restrict__ al_s, const float* __restrict__ al_d,
                   const int* __restrict__ rowptr, const int* __restrict__ csr_src,
                   const float* __restrict__ bias, unsigned short* __restrict__ out, int N)
{
  int wv = threadIdx.x >> 6, lane = threadIdx.x & 63;
  int n = blockIdx.x * 4 + wv;
  if (n >= N) return;
  int rs = __builtin_amdgcn_readfirstlane(rowptr[n]);
  int re = __builtin_amdgcn_readfirstlane(rowptr[n + 1]);
  int cnt = re - rs;
  float ald = al_d[n];
  float acc0 = 0.f, acc1 = 0.f;
  const unsigned short* Hb = H + lane * 2;   // lane owns channels {2l, 2l+1}

#ifdef HAVE_FDOT2
  auto passB = [&](int srcA, unsigned pkw, int ccnt) {
    for (int j = 0; j < ccnt; j += 4) {
      int s0 = __builtin_amdgcn_readlane(srcA, j);
      int s1 = __builtin_amdgcn_readlane(srcA, j + 1);
      int s2 = __builtin_amdgcn_readlane(srcA, j + 2);
      int s3 = __builtin_amdgcn_readlane(srcA, j + 3);
      unsigned pw0 = readlane_u(pkw, j);
      unsigned pw1 = readlane_u(pkw, j + 2);
      unsigned a0 = *(const unsigned*)(Hb + (size_t)s0 * HC);
      unsigned a1 = *(const unsigned*)(Hb + (size_t)s1 * HC);
      unsigned a2 = *(const unsigned*)(Hb + (size_t)s2 * HC);
      unsigned a3 = *(const unsigned*)(Hb + (size_t)s3 * HC);
      unsigned p0 = __builtin_amdgcn_perm(a0, a1, 0x01000504u);
      unsigned p1 = __builtin_amdgcn_perm(a0, a1, 0x03020706u);
      unsigned q0 = __builtin_amdgcn_perm(a2, a3, 0x01000504u);
      unsigned q1 = __builtin_amdgcn_perm(a2, a3, 0x03020706u);
      acc0 = dot2(pw0, p0, acc0);
      acc1 = dot2(pw0, p1, acc1);
      acc0 = dot2(pw1, q0, acc0);
      acc1 = dot2(pw1, q1, acc1);
    }
  };
#else
  auto passB = [&](int srcA, float wf, int ccnt) {
    for (int j = 0; j < ccnt; ++j) {
      int src = __builtin_amdgcn_readlane(srcA, j);
      float wgt = readlane_f(wf, j);
      unsigned a0 = *(const unsigned*)(Hb + (size_t)src * HC);
      acc0 += wgt * h2f((unsigned short)(a0 & 0xffff));
      acc1 += wgt * h2f((unsigned short)(a0 >> 16));
    }
  };
#endif

  if (cnt <= 64) {
    int srcA = 0;
    float e = -1e30f;
    if (lane < cnt) {
      srcA = csr_src[rs + lane];
      e = leaky02(al_s[srcA] + ald);
    }
    float m = e;
    #pragma unroll
    for (int off = 32; off; off >>= 1) m = fmaxf(m, __shfl_xor(m, off));
    float w = (lane < cnt) ? __expf(e - m) : 0.f;
    float den = w;
    #pragma unroll
    for (int off = 32; off; off >>= 1) den += __shfl_xor(den, off);
    w /= (den + 1e-16f);
#ifdef HAVE_FDOT2
    float wn2 = __shfl_xor(w, 1);
    float we = (lane & 1) ? wn2 : w;
    float wo = (lane & 1) ? w : wn2;
    unsigned pkw = (unsigned)f2h(we) | ((unsigned)f2h(wo) << 16);
    passB(srcA, pkw, cnt);
#else
    passB(srcA, w, cnt);
#endif
  } else {
    float m = -1e30f, s = 0.f;
    for (int i = rs + lane; i < re; i += 64) {
      int src = csr_src[i];
      float e = leaky02(al_s[src] + ald);
      float Mx = fmaxf(m, e);
      s = s * __expf(m - Mx) + __expf(e - Mx);
      m = Mx;
    }
    #pragma unroll
    for (int off = 32; off; off >>= 1) {
      float m2 = __shfl_xor(m, off);
      float s2 = __shfl_xor(s, off);
      float Mx = fmaxf(m, m2);
      s = s * __expf(m - Mx) + s2 * __expf(m2 - Mx);
      m = Mx;
    }
    float inv_den = 1.f / (s + 1e-16f);
    for (int c0 = rs; c0 < re; c0 += 64) {
      int ccnt = min(64, re - c0);
      int srcA = 0;
      float w = 0.f;
      if (lane < ccnt) {
        srcA = csr_src[c0 + lane];
        w = __expf(leaky02(al_s[srcA] + ald) - m) * inv_den;
      }
#ifdef HAVE_FDOT2
      float wn2 = __shfl_xor(w, 1);
      float we = (lane & 1) ? wn2 : w;
      float wo = (lane & 1) ? w : wn2;
      unsigned pkw = (unsigned)f2h(we) | ((unsigned)f2h(wo) << 16);
      passB(srcA, pkw, ccnt);
#else
      passB(srcA, w, ccnt);
#endif
    }
  }

  float o0 = eluf(acc0 + bias[lane * 2 + 0]);
  float o1 = eluf(acc1 + bias[lane * 2 + 1]);
  unsigned o = (unsigned)f2h(o0) | ((unsigned)f2h(o1) << 16);
  *(unsigned*)&out[(size_t)n * HC + lane * 2] = o;
}

// ---------- 7. global max pool (segmented over sorted batch) ----------
static __device__ __forceinline__ unsigned enc_f(float f)
{
  unsigned u = __float_as_uint(f);
  return (u & 0x80000000u) ? ~u : (u | 0x80000000u);
}
static __device__ __forceinline__ float dec_f(unsigned u)
{
  return (u & 0x80000000u) ? __uint_as_float(u & 0x7fffffffu) : __uint_as_float(~u);
}

#define PNPB 128   // nodes per pool block
__global__ __launch_bounds__(256)
void pool_seg_kernel(const unsigned short* __restrict__ x, const int* __restrict__ batch,
                     unsigned* __restrict__ pool, int N)
{
  int cp = (threadIdx.x & 63) * 2;     // channel pair
  int g  = threadIdx.x >> 6;           // node group 0..3
  int n0 = blockIdx.x * PNPB;
  int n1 = min(n0 + PNPB, N);
  int curb = -1;
  float m0 = 0.f, m1 = 0.f;
  for (int n = n0 + g; n < n1; n += 4) {
    int bg = batch[n];
    ushort2 v = *(const ushort2*)&x[(size_t)n * HC + cp];
    float v0 = h2f(v.x), v1 = h2f(v.y);
    if (bg != curb) {
      if (curb >= 0) {
        atomicMax(&pool[curb * HC + cp],     enc_f(m0));
        atomicMax(&pool[curb * HC + cp + 1], enc_f(m1));
      }
      curb = bg; m0 = v0; m1 = v1;
    } else {
      m0 = fmaxf(m0, v0);
      m1 = fmaxf(m1, v1);
    }
  }
  if (curb >= 0) {
    atomicMax(&pool[curb * HC + cp],     enc_f(m0));
    atomicMax(&pool[curb * HC + cp + 1], enc_f(m1));
  }
}

__global__ void pool_final_kernel(const unsigned* __restrict__ pool, float* __restrict__ out, int n)
{
  int i = blockIdx.x * blockDim.x + threadIdx.x;
  if (i < n) out[i] = dec_f(pool[i]);
}

// ---------- launch ----------
extern "C" void kernel_launch(void* const* d_in, const int* in_sizes, int n_in,
                              void* d_out, int out_size, void* d_ws, size_t ws_size,
                              hipStream_t stream)
{
  const float* x_scalar = (const float*)d_in[0];
  const int* i0 = (const int*)d_in[1];
  const int* i1 = (const int*)d_in[2];
  const int* i2 = (const int*)d_in[3];
  const int* i3 = (const int*)d_in[4];
  const int* i4 = (const int*)d_in[5];
  const int* ei = (const int*)d_in[6];
  const int* batch = (const int*)d_in[7];
  const float* e0 = (const float*)d_in[8];
  const float* e1 = (const float*)d_in[9];
  const float* e2 = (const float*)d_in[10];
  const float* e3 = (const float*)d_in[11];
  const float* e4 = (const float*)d_in[12];
  const float* ln_g = (const float*)d_in[13];
  const float* ln_b = (const float*)d_in[14];
  const float* W1 = (const float*)d_in[15];
  const float* as1 = (const float*)d_in[16];
  const float* ad1 = (const float*)d_in[17];
  const float* b1 = (const float*)d_in[18];
  const float* W2 = (const float*)d_in[19];
  const float* as2 = (const float*)d_in[20];
  const float* ad2 = (const float*)d_in[21];
  const float* b2 = (const float*)d_in[22];

  const int N  = in_sizes[0] / SF;
  const int E  = in_sizes[6] / 2;
  const int Et = E + N;
  const int Bg = out_size / HC;
  const int MT64 = (N + 63) / 64;

  char* w = (char*)d_ws;
  auto alloc = [&](size_t bytes) -> char* {
    char* p = w;
    w += (bytes + 255) & ~(size_t)255;
    return p;
  };
  unsigned short* featsb = (unsigned short*)alloc((size_t)N * KP1 * 2);
  unsigned short* G      = (unsigned short*)alloc((size_t)4 * N * KP1 * 2);
  unsigned short* X2b    = (unsigned short*)alloc((size_t)N * 512 * 2);
  unsigned short* H2b    = (unsigned short*)alloc((size_t)N * HC * 2);
  unsigned short* X3b    = (unsigned short*)alloc((size_t)N * HC * 2);
  unsigned short* W1t    = (unsigned short*)alloc((size_t)512 * KP1 * 2);
  unsigned short* W2t    = (unsigned short*)alloc((size_t)HC * 512 * 2);
  float* vs      = (float*)alloc((size_t)KP1 * 4 * 4);
  float* vd      = (float*)alloc((size_t)KP1 * 4 * 4);
  float* als1    = (float*)alloc((size_t)N * 4 * 4);
  float* ald1    = (float*)alloc((size_t)N * 4 * 4);
  float* als2    = (float*)alloc((size_t)N * 4);
  float* ald2    = (float*)alloc((size_t)N * 4);
  int*   deg     = (int*)alloc((size_t)N * 4);
  int*   rowptr  = (int*)alloc((size_t)(N + 1) * 4);
  int*   fill    = (int*)alloc((size_t)N * 4);
  int*   csr_src = (int*)alloc((size_t)Et * 4);
  unsigned* pool = (unsigned*)alloc((size_t)Bg * HC * 4);

  // combined prep: W packs, vs/vd, deg+als2/ald2 zero, pool init (one launch)
  {
    int nb1 = (512 * KP1 + 255) / 256;
    int nb2 = (HC * 512 + 255) / 256;
    int nb3 = (N + 255) / 256;
    int nb4 = (Bg * HC + 255) / 256;
    prep_combined_kernel<<<nb1 + nb2 + nb3 + nb4 + DIN, 256, 0, stream>>>(
        W1, W2, W1t, W2t, as1, ad1, vs, vd, deg, pool, als2, ald2, N, Bg * HC);
  }

  // features + LN + fused layer-1 logits (one wave per node, 4 nodes/block)
  feat_ln_kernel<<<(N + 3) / 4, 256, 0, stream>>>(x_scalar, i0, i1, i2, i3, i4,
                                                  e0, e1, e2, e3, e4, ln_g, ln_b,
                                                  (const float4*)vs, (const float4*)vd,
                                                  featsb, als1, ald1, N);

  // CSR
  count_kernel<<<(Et + 255) / 256, 256, 0, stream>>>(ei, E, N, deg);
  scan_kernel<<<1, 1024, 0, stream>>>(deg, rowptr, fill, N);
  scatter_kernel<<<(Et + 255) / 256, 256, 0, stream>>>(ei, E, N, fill, csr_src);

  // layer 1: aggregate feats, then per-head GEMM (+b1, ELU); 64x64 dbuf tiles
  agg_feat_kernel<<<(N + 3) / 4, 256, 0, stream>>>(featsb, (const float4*)als1,
                                                   (const float4*)ald1,
                                                   rowptr, csr_src, G, N);
  gemm64_kernel<KP1, 1, 0><<<dim3(2, MT64, 4), 256, 0, stream>>>(
      G, W1t, X2b, N, 512, (size_t)N * KP1, (size_t)HC * KP1, HC, b1,
      nullptr, nullptr, nullptr, nullptr);

  // layer 2: GEMM with fused logits (atomicAdd), then aggregate (+b2, ELU)
  gemm64_kernel<512, 0, 1><<<dim3(2, MT64, 1), 256, 0, stream>>>(
      X2b, W2t, H2b, N, HC, 0, 0, 0, nullptr,
      as2, ad2, als2, ald2);
  agg_h2_kernel<<<(N + 3) / 4, 256, 0, stream>>>(H2b, als2, ald2, rowptr, csr_src, b2, X3b, N);

  // pool
  pool_seg_kernel<<<(N + PNPB - 1) / PNPB, 256, 0, stream>>>(X3b, batch, pool, N);
  pool_final_kernel<<<(Bg * HC + 255) / 256, 256, 0, stream>>>(pool, (float*)d_out, Bg * HC);
}

// Round 13
// 220.035 us; speedup vs baseline: 1.3840x; 1.0078x over previous
//
#include <hip/hip_runtime.h>
#include <math.h>

#define SF 16
#define ED 32
#define LTOK 20
#define DIN 176
#define KP1 192   // DIN padded to multiple of 32
#define HC 128

typedef _Float16 f16x8 __attribute__((ext_vector_type(8)));
typedef _Float16 f16x2 __attribute__((ext_vector_type(2)));
typedef float f32x4 __attribute__((ext_vector_type(4)));

#if defined(__has_builtin)
#if __has_builtin(__builtin_amdgcn_fdot2)
#define HAVE_FDOT2 1
#endif
#endif

static __device__ __forceinline__ float leaky02(float x) { return x >= 0.f ? x : 0.2f * x; }
static __device__ __forceinline__ float eluf(float x)    { return x > 0.f ? x : expm1f(x); }
static __device__ __forceinline__ unsigned short f2h(float f)
{
  _Float16 h = (_Float16)f;
  return __builtin_bit_cast(unsigned short, h);
}
static __device__ __forceinline__ float h2f(unsigned short u)
{
  return (float)__builtin_bit_cast(_Float16, u);
}
static __device__ __forceinline__ float readlane_f(float v, int j)
{
  return __int_as_float(__builtin_amdgcn_readlane(__float_as_int(v), j));
}
static __device__ __forceinline__ unsigned readlane_u(unsigned v, int j)
{
  return (unsigned)__builtin_amdgcn_readlane((int)v, j);
}
#ifdef HAVE_FDOT2
static __device__ __forceinline__ float dot2(unsigned w, unsigned f, float c)
{
  return __builtin_amdgcn_fdot2(__builtin_bit_cast(f16x2, w),
                                __builtin_bit_cast(f16x2, f), c, false);
}
#endif

// ---------- 0. combined prep: pack W1t/W2t, vs/vd, zero deg+als2+ald2, init pool ----------
__global__ __launch_bounds__(256)
void prep_combined_kernel(const float* __restrict__ W1, const float* __restrict__ W2,
                          unsigned short* __restrict__ W1t, unsigned short* __restrict__ W2t,
                          const float* __restrict__ as1, const float* __restrict__ ad1,
                          float* __restrict__ vs, float* __restrict__ vd,
                          int* __restrict__ deg, unsigned* __restrict__ pool,
                          float* __restrict__ als2, float* __restrict__ ald2,
                          int N, int poolN)
{
  const int nb1 = (512 * KP1 + 255) / 256;
  const int nb2 = (HC * 512 + 255) / 256;
  const int nb3 = (N + 255) / 256;
  const int nb4 = (poolN + 255) / 256;
  int bid = blockIdx.x;
  if (bid < nb1) {                       // W1t [512][KP1] <- W1 [DIN][512]
    int i = bid * 256 + threadIdx.x;
    if (i < 512 * KP1) {
      int n = i / KP1, k = i - n * KP1;
      W1t[i] = f2h((k < DIN) ? W1[(size_t)k * 512 + n] : 0.f);
    }
    return;
  }
  bid -= nb1;
  if (bid < nb2) {                       // W2t [HC][512] <- W2 [512][HC]
    int i = bid * 256 + threadIdx.x;
    if (i < HC * 512) {
      int n = i / 512, k = i - n * 512;
      W2t[i] = f2h(W2[(size_t)k * HC + n]);
    }
    return;
  }
  bid -= nb2;
  if (bid < nb3) {                       // deg = 0, als2/ald2 = 0 (atomic targets)
    int i = bid * 256 + threadIdx.x;
    if (i < N) { deg[i] = 0; als2[i] = 0.f; ald2[i] = 0.f; }
    return;
  }
  bid -= nb3;
  if (bid < nb4) {                       // pool = enc(-FLT_MAX)
    int i = bid * 256 + threadIdx.x;
    if (i < poolN) pool[i] = 0x00800000u;
    return;
  }
  bid -= nb4;
  {                                      // vs/vd row bid (0..DIN-1)
    int k = bid;
    int h = threadIdx.x >> 6, lane = threadIdx.x & 63;
    const float* row = W1 + (size_t)k * 512 + h * HC;
    float s = row[lane] * as1[h * HC + lane] + row[lane + 64] * as1[h * HC + lane + 64];
    float d = row[lane] * ad1[h * HC + lane] + row[lane + 64] * ad1[h * HC + lane + 64];
    #pragma unroll
    for (int off = 32; off; off >>= 1) { s += __shfl_down(s, off); d += __shfl_down(d, off); }
    if (lane == 0) { vs[k * 4 + h] = s; vd[k * 4 + h] = d; }
  }
}

// ---------- 1. features + LayerNorm + fused logits + fused edge-count ----------
// One wave per node; lane owns a CHANNEL PAIR (float2 gathers, 2 rounds).
// Blocks >= nodeBlocks do the CSR degree count (independent work, deg
// pre-zeroed by prep which precedes on the stream).
__global__ __launch_bounds__(256)
void feat_ln_kernel(const float* __restrict__ xs,
                    const int* __restrict__ i0, const int* __restrict__ i1,
                    const int* __restrict__ i2, const int* __restrict__ i3,
                    const int* __restrict__ i4,
                    const float* __restrict__ e0, const float* __restrict__ e1,
                    const float* __restrict__ e2, const float* __restrict__ e3,
                    const float* __restrict__ e4,
                    const float* __restrict__ g, const float* __restrict__ b,
                    const float4* __restrict__ vs, const float4* __restrict__ vd,
                    unsigned short* __restrict__ out,
                    float* __restrict__ als, float* __restrict__ ald,
                    const int* __restrict__ ei, int E, int* __restrict__ deg,
                    int nodeBlocks, int N)
{
  if (blockIdx.x >= nodeBlocks) {        // fused CSR degree count
    int e = (blockIdx.x - nodeBlocks) * 256 + threadIdx.x;
    if (e < E + N) {
      int dst = (e < E) ? ei[E + e] : (e - E);
      atomicAdd(&deg[dst], 1);
    }
    return;
  }

  __shared__ int toks[4][5 * LTOK];
  int w = threadIdx.x >> 6, l = threadIdx.x & 63;
  int n = blockIdx.x * 4 + w;
  if (n >= N) return;

  for (int q = l; q < 5 * LTOK; q += 64) {
    int f = q / LTOK, j = q - f * LTOK;
    const int* ip = (f == 0) ? i0 : (f == 1) ? i1 : (f == 2) ? i2 : (f == 3) ? i3 : i4;
    toks[w][q] = ip[n * LTOK + j];
  }

  // 2 rounds; pair index p = l + r*64; global channels {2p, 2p+1}
  float2 v[2];
  #pragma unroll
  for (int r = 0; r < 2; ++r) {
    int p = l + r * 64;
    float2 val = make_float2(0.f, 0.f);
    if (p < 8) {                          // scalar features
      val = *(const float2*)&xs[n * SF + 2 * p];
    } else if (p < 88) {                  // embedding channels
      int c0 = 2 * p - 16;
      int f  = c0 >> 5;
      int ch = c0 & 31;
      const float* ep = (f == 0) ? e0 : (f == 1) ? e1 : (f == 2) ? e2 : (f == 3) ? e3 : e4;
      float2 vals[LTOK];
      #pragma unroll
      for (int j = 0; j < LTOK; ++j)
        vals[j] = *(const float2*)&ep[(size_t)toks[w][f * LTOK + j] * ED + ch];
      float sx = 0.f, sy = 0.f, cntv = 0.f;
      #pragma unroll
      for (int j = 0; j < LTOK; ++j)
        if (toks[w][f * LTOK + j] != 0) { sx += vals[j].x; sy += vals[j].y; cntv += 1.f; }
      float inv = 1.f / (cntv + 1e-9f);
      val.x = sx * inv; val.y = sy * inv;
    }
    v[r] = val;
  }

  float p1 = v[0].x + v[0].y + v[1].x + v[1].y;
  float p2 = v[0].x * v[0].x + v[0].y * v[0].y + v[1].x * v[1].x + v[1].y * v[1].y;
  #pragma unroll
  for (int off = 32; off; off >>= 1) { p1 += __shfl_xor(p1, off); p2 += __shfl_xor(p2, off); }
  float mu   = p1 * (1.f / DIN);
  float var  = fmaxf(p2 * (1.f / DIN) - mu * mu, 0.f);
  float rstd = rsqrtf(var + 1e-5f);

  float pr[8] = {0.f, 0.f, 0.f, 0.f, 0.f, 0.f, 0.f, 0.f};
  #pragma unroll
  for (int r = 0; r < 2; ++r) {
    int p = l + r * 64;
    float y0 = 0.f, y1 = 0.f;
    if (p < 88) {
      int c = 2 * p;
      y0 = (v[r].x - mu) * rstd * g[c] + b[c];
      y1 = (v[r].y - mu) * rstd * g[c + 1] + b[c + 1];
      float4 s0 = vs[c], s1 = vs[c + 1], d0 = vd[c], d1 = vd[c + 1];
      pr[0] += y0 * s0.x + y1 * s1.x; pr[1] += y0 * s0.y + y1 * s1.y;
      pr[2] += y0 * s0.z + y1 * s1.z; pr[3] += y0 * s0.w + y1 * s1.w;
      pr[4] += y0 * d0.x + y1 * d1.x; pr[5] += y0 * d0.y + y1 * d1.y;
      pr[6] += y0 * d0.z + y1 * d1.z; pr[7] += y0 * d0.w + y1 * d1.w;
    }
    if (p < 96) {
      unsigned o = (unsigned)f2h(y0) | ((unsigned)f2h(y1) << 16);
      *(unsigned*)&out[(size_t)n * KP1 + 2 * p] = o;
    }
  }
  #pragma unroll
  for (int j = 0; j < 8; ++j)
    #pragma unroll
    for (int off = 32; off; off >>= 1) pr[j] += __shfl_xor(pr[j], off);
  if (l == 0) {
    als[n * 4 + 0] = pr[0]; als[n * 4 + 1] = pr[1];
    als[n * 4 + 2] = pr[2]; als[n * 4 + 3] = pr[3];
    ald[n * 4 + 0] = pr[4]; ald[n * 4 + 1] = pr[5];
    ald[n * 4 + 2] = pr[6]; ald[n * 4 + 3] = pr[7];
  }
}

// ---------- 2. CSR build (scan + scatter) ----------
__global__ __launch_bounds__(1024)
void scan_kernel(const int* __restrict__ deg, int* __restrict__ rowptr,
                 int* __restrict__ fill, int N)
{
  __shared__ int sums[1024];
  int t = threadIdx.x;
  int CH = (N + 1023) >> 10;
  int base = t * CH;
  int s = 0;
  for (int i = 0; i < CH; ++i) if (base + i < N) s += deg[base + i];
  sums[t] = s;
  __syncthreads();
  for (int off = 1; off < 1024; off <<= 1) {
    int v = (t >= off) ? sums[t - off] : 0;
    __syncthreads();
    sums[t] += v;
    __syncthreads();
  }
  int run = sums[t] - s;  // exclusive prefix
  for (int i = 0; i < CH; ++i) {
    if (base + i < N) {
      rowptr[base + i] = run;
      fill[base + i]   = run;
      run += deg[base + i];
    }
  }
  if (t == 1023) rowptr[N] = run;
}

__global__ void scatter_kernel(const int* __restrict__ ei, int E, int N,
                               int* __restrict__ fill, int* __restrict__ csr_src)
{
  int e = blockIdx.x * blockDim.x + threadIdx.x;
  if (e < E + N) {
    int src, dst;
    if (e < E) { src = ei[e]; dst = ei[E + e]; }
    else       { src = dst = e - E; }
    int pos = atomicAdd(&fill[dst], 1);
    csr_src[pos] = src;
  }
}

// ---------- 3. layer-1 aggregation over FEATURES (fdot2, 4-edge unrolled) ----------
__global__ __launch_bounds__(256)
void agg_feat_kernel(const unsigned short* __restrict__ F,   // [N][KP1] f16
                     const float4* __restrict__ als, const float4* __restrict__ ald,
                     const int* __restrict__ rowptr, const int* __restrict__ csr_src,
                     unsigned short* __restrict__ G, int N)  // [4][N][KP1] f16
{
  int wv = threadIdx.x >> 6, lane = threadIdx.x & 63;
  int n = blockIdx.x * 4 + wv;
  if (n >= N) return;
  int rs = __builtin_amdgcn_readfirstlane(rowptr[n]);
  int re = __builtin_amdgcn_readfirstlane(rowptr[n + 1]);
  int cnt = re - rs;
  float4 ad4 = ald[n];
  float aldv[4] = { ad4.x, ad4.y, ad4.z, ad4.w };

  float acc[4][4] = {};
  bool act = lane < 48;                      // 48 lanes x 4 ch = 192
  const unsigned short* Fb = F + lane * 4;

#ifdef HAVE_FDOT2
  auto passB = [&](int srcA, unsigned pkw[4], int ccnt) {
    for (int j = 0; j < ccnt; j += 4) {      // 4 edges per iteration
      int s0 = __builtin_amdgcn_readlane(srcA, j);
      int s1 = __builtin_amdgcn_readlane(srcA, j + 1);
      int s2 = __builtin_amdgcn_readlane(srcA, j + 2);
      int s3 = __builtin_amdgcn_readlane(srcA, j + 3);
      unsigned wa0 = readlane_u(pkw[0], j), wb0 = readlane_u(pkw[0], j + 2);
      unsigned wa1 = readlane_u(pkw[1], j), wb1 = readlane_u(pkw[1], j + 2);
      unsigned wa2 = readlane_u(pkw[2], j), wb2 = readlane_u(pkw[2], j + 2);
      unsigned wa3 = readlane_u(pkw[3], j), wb3 = readlane_u(pkw[3], j + 2);
      if (act) {
        int2 a0 = *(const int2*)(Fb + (size_t)s0 * KP1);
        int2 a1 = *(const int2*)(Fb + (size_t)s1 * KP1);
        int2 a2 = *(const int2*)(Fb + (size_t)s2 * KP1);
        int2 a3 = *(const int2*)(Fb + (size_t)s3 * KP1);
        unsigned pA = __builtin_amdgcn_perm((unsigned)a0.x, (unsigned)a1.x, 0x01000504u);
        unsigned pB = __builtin_amdgcn_perm((unsigned)a0.x, (unsigned)a1.x, 0x03020706u);
        unsigned pC = __builtin_amdgcn_perm((unsigned)a0.y, (unsigned)a1.y, 0x01000504u);
        unsigned pD = __builtin_amdgcn_perm((unsigned)a0.y, (unsigned)a1.y, 0x03020706u);
        unsigned qA = __builtin_amdgcn_perm((unsigned)a2.x, (unsigned)a3.x, 0x01000504u);
        unsigned qB = __builtin_amdgcn_perm((unsigned)a2.x, (unsigned)a3.x, 0x03020706u);
        unsigned qC = __builtin_amdgcn_perm((unsigned)a2.y, (unsigned)a3.y, 0x01000504u);
        unsigned qD = __builtin_amdgcn_perm((unsigned)a2.y, (unsigned)a3.y, 0x03020706u);
        acc[0][0] = dot2(wa0, pA, acc[0][0]); acc[0][1] = dot2(wa0, pB, acc[0][1]);
        acc[0][2] = dot2(wa0, pC, acc[0][2]); acc[0][3] = dot2(wa0, pD, acc[0][3]);
        acc[1][0] = dot2(wa1, pA, acc[1][0]); acc[1][1] = dot2(wa1, pB, acc[1][1]);
        acc[1][2] = dot2(wa1, pC, acc[1][2]); acc[1][3] = dot2(wa1, pD, acc[1][3]);
        acc[2][0] = dot2(wa2, pA, acc[2][0]); acc[2][1] = dot2(wa2, pB, acc[2][1]);
        acc[2][2] = dot2(wa2, pC, acc[2][2]); acc[2][3] = dot2(wa2, pD, acc[2][3]);
        acc[3][0] = dot2(wa3, pA, acc[3][0]); acc[3][1] = dot2(wa3, pB, acc[3][1]);
        acc[3][2] = dot2(wa3, pC, acc[3][2]); acc[3][3] = dot2(wa3, pD, acc[3][3]);
        acc[0][0] = dot2(wb0, qA, acc[0][0]); acc[0][1] = dot2(wb0, qB, acc[0][1]);
        acc[0][2] = dot2(wb0, qC, acc[0][2]); acc[0][3] = dot2(wb0, qD, acc[0][3]);
        acc[1][0] = dot2(wb1, qA, acc[1][0]); acc[1][1] = dot2(wb1, qB, acc[1][1]);
        acc[1][2] = dot2(wb1, qC, acc[1][2]); acc[1][3] = dot2(wb1, qD, acc[1][3]);
        acc[2][0] = dot2(wb2, qA, acc[2][0]); acc[2][1] = dot2(wb2, qB, acc[2][1]);
        acc[2][2] = dot2(wb2, qC, acc[2][2]); acc[2][3] = dot2(wb2, qD, acc[2][3]);
        acc[3][0] = dot2(wb3, qA, acc[3][0]); acc[3][1] = dot2(wb3, qB, acc[3][1]);
        acc[3][2] = dot2(wb3, qC, acc[3][2]); acc[3][3] = dot2(wb3, qD, acc[3][3]);
      }
    }
  };
#else
  auto passB = [&](int srcA, float wf[4], int ccnt) {
    for (int j = 0; j < ccnt; ++j) {
      int src = __builtin_amdgcn_readlane(srcA, j);
      float q0 = readlane_f(wf[0], j), q1 = readlane_f(wf[1], j);
      float q2 = readlane_f(wf[2], j), q3 = readlane_f(wf[3], j);
      if (act) {
        int2 a0 = *(const int2*)(Fb + (size_t)src * KP1);
        float f0 = h2f((unsigned short)(a0.x & 0xffff));
        float f1 = h2f((unsigned short)((unsigned)a0.x >> 16));
        float f2v = h2f((unsigned short)(a0.y & 0xffff));
        float f3 = h2f((unsigned short)((unsigned)a0.y >> 16));
        acc[0][0] += q0 * f0; acc[0][1] += q0 * f1; acc[0][2] += q0 * f2v; acc[0][3] += q0 * f3;
        acc[1][0] += q1 * f0; acc[1][1] += q1 * f1; acc[1][2] += q1 * f2v; acc[1][3] += q1 * f3;
        acc[2][0] += q2 * f0; acc[2][1] += q2 * f1; acc[2][2] += q2 * f2v; acc[2][3] += q2 * f3;
        acc[3][0] += q3 * f0; acc[3][1] += q3 * f1; acc[3][2] += q3 * f2v; acc[3][3] += q3 * f3;
      }
    }
  };
#endif

  if (cnt <= 64) {
    int srcA = 0;
    float e[4] = { -1e30f, -1e30f, -1e30f, -1e30f };
    if (lane < cnt) {
      srcA = csr_src[rs + lane];
      float4 a4 = als[srcA];
      e[0] = leaky02(a4.x + aldv[0]); e[1] = leaky02(a4.y + aldv[1]);
      e[2] = leaky02(a4.z + aldv[2]); e[3] = leaky02(a4.w + aldv[3]);
    }
    float m[4] = { e[0], e[1], e[2], e[3] };
    #pragma unroll
    for (int off = 32; off; off >>= 1)
      #pragma unroll
      for (int h = 0; h < 4; ++h) m[h] = fmaxf(m[h], __shfl_xor(m[h], off));
    float w[4];
    #pragma unroll
    for (int h = 0; h < 4; ++h) w[h] = (lane < cnt) ? __expf(e[h] - m[h]) : 0.f;
    float den[4] = { w[0], w[1], w[2], w[3] };
    #pragma unroll
    for (int off = 32; off; off >>= 1)
      #pragma unroll
      for (int h = 0; h < 4; ++h) den[h] += __shfl_xor(den[h], off);
    #pragma unroll
    for (int h = 0; h < 4; ++h) w[h] /= (den[h] + 1e-16f);
#ifdef HAVE_FDOT2
    unsigned pkw[4];
    #pragma unroll
    for (int h = 0; h < 4; ++h) {
      float wn = __shfl_xor(w[h], 1);
      float we = (lane & 1) ? wn : w[h];
      float wo = (lane & 1) ? w[h] : wn;
      pkw[h] = (unsigned)f2h(we) | ((unsigned)f2h(wo) << 16);
    }
    passB(srcA, pkw, cnt);
#else
    passB(srcA, w, cnt);
#endif
  } else {
    float m[4], s[4];
    #pragma unroll
    for (int h = 0; h < 4; ++h) { m[h] = -1e30f; s[h] = 0.f; }
    for (int i = rs + lane; i < re; i += 64) {
      int src = csr_src[i];
      float4 a4 = als[src];
      float av[4] = { a4.x, a4.y, a4.z, a4.w };
      #pragma unroll
      for (int h = 0; h < 4; ++h) {
        float e = leaky02(av[h] + aldv[h]);
        float Mx = fmaxf(m[h], e);
        s[h] = s[h] * __expf(m[h] - Mx) + __expf(e - Mx);
        m[h] = Mx;
      }
    }
    #pragma unroll
    for (int off = 32; off; off >>= 1) {
      #pragma unroll
      for (int h = 0; h < 4; ++h) {
        float m2 = __shfl_xor(m[h], off);
        float s2 = __shfl_xor(s[h], off);
        float Mx = fmaxf(m[h], m2);
        s[h] = s[h] * __expf(m[h] - Mx) + s2 * __expf(m2 - Mx);
        m[h] = Mx;
      }
    }
    float inv[4];
    #pragma unroll
    for (int h = 0; h < 4; ++h) inv[h] = 1.f / (s[h] + 1e-16f);
    for (int b0 = rs; b0 < re; b0 += 64) {
      int bcnt = min(64, re - b0);
      int srcA = 0;
      float w[4] = {0.f, 0.f, 0.f, 0.f};
      if (lane < bcnt) {
        srcA = csr_src[b0 + lane];
        float4 a4 = als[srcA];
        w[0] = __expf(leaky02(a4.x + aldv[0]) - m[0]) * inv[0];
        w[1] = __expf(leaky02(a4.y + aldv[1]) - m[1]) * inv[1];
        w[2] = __expf(leaky02(a4.z + aldv[2]) - m[2]) * inv[2];
        w[3] = __expf(leaky02(a4.w + aldv[3]) - m[3]) * inv[3];
      }
#ifdef HAVE_FDOT2
      unsigned pkw[4];
      #pragma unroll
      for (int h = 0; h < 4; ++h) {
        float wn = __shfl_xor(w[h], 1);
        float we = (lane & 1) ? wn : w[h];
        float wo = (lane & 1) ? w[h] : wn;
        pkw[h] = (unsigned)f2h(we) | ((unsigned)f2h(wo) << 16);
      }
      passB(srcA, pkw, bcnt);
#else
      passB(srcA, w, bcnt);
#endif
    }
  }

  if (act) {
    #pragma unroll
    for (int h = 0; h < 4; ++h) {
      int2 o;
      o.x = (int)f2h(acc[h][0]) | ((int)f2h(acc[h][1]) << 16);
      o.y = (int)f2h(acc[h][2]) | ((int)f2h(acc[h][3]) << 16);
      *(int2*)&G[((size_t)h * N + n) * KP1 + lane * 4] = o;
    }
  }
}

// ---------- 4. MFMA f16 GEMM, 64x64 tile, DOUBLE-BUFFERED LDS (1 barrier/K-step) ----------
template<int KPad, int BIAS_ELU, int LOGITS>
__global__ __launch_bounds__(256)
void gemm64_kernel(const unsigned short* __restrict__ A,
                   const unsigned short* __restrict__ Bt,
                   unsigned short* __restrict__ C,
                   int M, int Nc,
                   size_t aStrideZ, size_t bStrideZ, int cColStrideZ,
                   const float* __restrict__ bias,
                   const float* __restrict__ la_s, const float* __restrict__ la_d,
                   float* __restrict__ lout_s, float* __restrict__ lout_d)
{
  A  += blockIdx.z * aStrideZ;
  Bt += blockIdx.z * bStrideZ;
  const int colZ = blockIdx.z * cColStrideZ;

  __shared__ __align__(16) unsigned short As[2][4][520];
  __shared__ __align__(16) unsigned short Bs[2][4][520];

  const int tid  = threadIdx.x;
  const int lane = tid & 63, wv = tid >> 6;
  const int bm = blockIdx.y << 6, bn = blockIdx.x << 6;
  const int wm = (wv >> 1) << 5, wn = (wv & 1) << 5;
  const int kc = lane >> 4, r16 = lane & 15;

  const int srow = lane, skc = wv;
  const unsigned short* Ap = A + (size_t)(bm + srow) * KPad + skc * 8;
  const unsigned short* Bp = Bt + (size_t)(bn + srow) * KPad + skc * 8;
  const bool aok = (bm + srow) < M;

  f32x4 acc[2][2];
  #pragma unroll
  for (int m = 0; m < 2; ++m)
    #pragma unroll
    for (int n2 = 0; n2 < 2; ++n2) acc[m][n2] = (f32x4){0.f, 0.f, 0.f, 0.f};

  constexpr int NT = KPad / 32;
  int4 av = aok ? *(const int4*)Ap : make_int4(0, 0, 0, 0);
  int4 bv = *(const int4*)Bp;

  for (int t = 0; t < NT; ++t) {
    const int cur = t & 1;
    *(int4*)&As[cur][skc][srow * 8] = av;
    *(int4*)&Bs[cur][skc][srow * 8] = bv;
    if (t + 1 < NT) {
      av = aok ? *(const int4*)(Ap + (t + 1) * 32) : make_int4(0, 0, 0, 0);
      bv = *(const int4*)(Bp + (t + 1) * 32);
    }
    __syncthreads();
    f16x8 af0 = *(const f16x8*)&As[cur][kc][(wm + r16) * 8];
    f16x8 af1 = *(const f16x8*)&As[cur][kc][(wm + 16 + r16) * 8];
    f16x8 bf0 = *(const f16x8*)&Bs[cur][kc][(wn + r16) * 8];
    f16x8 bf1 = *(const f16x8*)&Bs[cur][kc][(wn + 16 + r16) * 8];
    acc[0][0] = __builtin_amdgcn_mfma_f32_16x16x32_f16(af0, bf0, acc[0][0], 0, 0, 0);
    acc[0][1] = __builtin_amdgcn_mfma_f32_16x16x32_f16(af0, bf1, acc[0][1], 0, 0, 0);
    acc[1][0] = __builtin_amdgcn_mfma_f32_16x16x32_f16(af1, bf0, acc[1][0], 0, 0, 0);
    acc[1][1] = __builtin_amdgcn_mfma_f32_16x16x32_f16(af1, bf1, acc[1][1], 0, 0, 0);
  }

  const int rq = lane >> 4;
  #pragma unroll
  for (int m = 0; m < 2; ++m) {
    #pragma unroll
    for (int r = 0; r < 4; ++r) {
      int row = bm + wm + m * 16 + rq * 4 + r;
      if (row < M) {
        #pragma unroll
        for (int n2 = 0; n2 < 2; ++n2) {
          int col = colZ + bn + wn + n2 * 16 + r16;
          float val = acc[m][n2][r];
          if (BIAS_ELU) { val += bias[col]; val = eluf(val); }
          C[(size_t)row * Nc + col] = f2h(val);
        }
      }
    }
  }

  if (LOGITS) {
    #pragma unroll
    for (int m = 0; m < 2; ++m) {
      #pragma unroll
      for (int r = 0; r < 4; ++r) {
        float ps = 0.f, pd = 0.f;
        #pragma unroll
        for (int n2 = 0; n2 < 2; ++n2) {
          int col = bn + wn + n2 * 16 + r16;
          float val = acc[m][n2][r];
          ps += val * la_s[col];
          pd += val * la_d[col];
        }
        #pragma unroll
        for (int off = 1; off < 16; off <<= 1) {
          ps += __shfl_xor(ps, off);
          pd += __shfl_xor(pd, off);
        }
        int row = bm + wm + m * 16 + rq * 4 + r;
        if (r16 == 0 && row < M) {
          atomicAdd(&lout_s[row], ps);
          atomicAdd(&lout_d[row], pd);
        }
      }
    }
  }
}

// ---------- 6. layer-2 aggregation; fdot2 4-edge unrolled, lane owns 2 channels ----------
__global__ __launch_bounds__(256)
void agg_h2_kernel(const unsigned short* __restrict__ H,
                   const float* __restrict__ al_s, const float* __restrict__ al_d,
                   const int* __restrict__ rowptr, const int* __restrict__ csr_src,
                   const float* __restrict__ bias, unsigned short* __restrict__ out, int N)
{
  int wv = threadIdx.x >> 6, lane = threadIdx.x & 63;
  int n = blockIdx.x * 4 + wv;
  if (n >= N) return;
  int rs = __builtin_amdgcn_readfirstlane(rowptr[n]);
  int re = __builtin_amdgcn_readfirstlane(rowptr[n + 1]);
  int cnt = re - rs;
  float ald = al_d[n];
  float acc0 = 0.f, acc1 = 0.f;
  const unsigned short* Hb = H + lane * 2;   // lane owns channels {2l, 2l+1}

#ifdef HAVE_FDOT2
  auto passB = [&](int srcA, unsigned pkw, int ccnt) {
    for (int j = 0; j < ccnt; j += 4) {
      int s0 = __builtin_amdgcn_readlane(srcA, j);
      int s1 = __builtin_amdgcn_readlane(srcA, j + 1);
      int s2 = __builtin_amdgcn_readlane(srcA, j + 2);
      int s3 = __builtin_amdgcn_readlane(srcA, j + 3);
      unsigned pw0 = readlane_u(pkw, j);
      unsigned pw1 = readlane_u(pkw, j + 2);
      unsigned a0 = *(const unsigned*)(Hb + (size_t)s0 * HC);
      unsigned a1 = *(const unsigned*)(Hb + (size_t)s1 * HC);
      unsigned a2 = *(const unsigned*)(Hb + (size_t)s2 * HC);
      unsigned a3 = *(const unsigned*)(Hb + (size_t)s3 * HC);
      unsigned p0 = __builtin_amdgcn_perm(a0, a1, 0x01000504u);
      unsigned p1 = __builtin_amdgcn_perm(a0, a1, 0x03020706u);
      unsigned q0 = __builtin_amdgcn_perm(a2, a3, 0x01000504u);
      unsigned q1 = __builtin_amdgcn_perm(a2, a3, 0x03020706u);
      acc0 = dot2(pw0, p0, acc0);
      acc1 = dot2(pw0, p1, acc1);
      acc0 = dot2(pw1, q0, acc0);
      acc1 = dot2(pw1, q1, acc1);
    }
  };
#else
  auto passB = [&](int srcA, float wf, int ccnt) {
    for (int j = 0; j < ccnt; ++j) {
      int src = __builtin_amdgcn_readlane(srcA, j);
      float wgt = readlane_f(wf, j);
      unsigned a0 = *(const unsigned*)(Hb + (size_t)src * HC);
      acc0 += wgt * h2f((unsigned short)(a0 & 0xffff));
      acc1 += wgt * h2f((unsigned short)(a0 >> 16));
    }
  };
#endif

  if (cnt <= 64) {
    int srcA = 0;
    float e = -1e30f;
    if (lane < cnt) {
      srcA = csr_src[rs + lane];
      e = leaky02(al_s[srcA] + ald);
    }
    float m = e;
    #pragma unroll
    for (int off = 32; off; off >>= 1) m = fmaxf(m, __shfl_xor(m, off));
    float w = (lane < cnt) ? __expf(e - m) : 0.f;
    float den = w;
    #pragma unroll
    for (int off = 32; off; off >>= 1) den += __shfl_xor(den, off);
    w /= (den + 1e-16f);
#ifdef HAVE_FDOT2
    float wn2 = __shfl_xor(w, 1);
    float we = (lane & 1) ? wn2 : w;
    float wo = (lane & 1) ? w : wn2;
    unsigned pkw = (unsigned)f2h(we) | ((unsigned)f2h(wo) << 16);
    passB(srcA, pkw, cnt);
#else
    passB(srcA, w, cnt);
#endif
  } else {
    float m = -1e30f, s = 0.f;
    for (int i = rs + lane; i < re; i += 64) {
      int src = csr_src[i];
      float e = leaky02(al_s[src] + ald);
      float Mx = fmaxf(m, e);
      s = s * __expf(m - Mx) + __expf(e - Mx);
      m = Mx;
    }
    #pragma unroll
    for (int off = 32; off; off >>= 1) {
      float m2 = __shfl_xor(m, off);
      float s2 = __shfl_xor(s, off);
      float Mx = fmaxf(m, m2);
      s = s * __expf(m - Mx) + s2 * __expf(m2 - Mx);
      m = Mx;
    }
    float inv_den = 1.f / (s + 1e-16f);
    for (int c0 = rs; c0 < re; c0 += 64) {
      int ccnt = min(64, re - c0);
      int srcA = 0;
      float w = 0.f;
      if (lane < ccnt) {
        srcA = csr_src[c0 + lane];
        w = __expf(leaky02(al_s[srcA] + ald) - m) * inv_den;
      }
#ifdef HAVE_FDOT2
      float wn2 = __shfl_xor(w, 1);
      float we = (lane & 1) ? wn2 : w;
      float wo = (lane & 1) ? w : wn2;
      unsigned pkw = (unsigned)f2h(we) | ((unsigned)f2h(wo) << 16);
      passB(srcA, pkw, ccnt);
#else
      passB(srcA, w, ccnt);
#endif
    }
  }

  float o0 = eluf(acc0 + bias[lane * 2 + 0]);
  float o1 = eluf(acc1 + bias[lane * 2 + 1]);
  unsigned o = (unsigned)f2h(o0) | ((unsigned)f2h(o1) << 16);
  *(unsigned*)&out[(size_t)n * HC + lane * 2] = o;
}

// ---------- 7. global max pool (segmented over sorted batch) ----------
static __device__ __forceinline__ unsigned enc_f(float f)
{
  unsigned u = __float_as_uint(f);
  return (u & 0x80000000u) ? ~u : (u | 0x80000000u);
}
static __device__ __forceinline__ float dec_f(unsigned u)
{
  return (u & 0x80000000u) ? __uint_as_float(u & 0x7fffffffu) : __uint_as_float(~u);
}

#define PNPB 128   // nodes per pool block
__global__ __launch_bounds__(256)
void pool_seg_kernel(const unsigned short* __restrict__ x, const int* __restrict__ batch,
                     unsigned* __restrict__ pool, int N)
{
  int cp = (threadIdx.x & 63) * 2;     // channel pair
  int g  = threadIdx.x >> 6;           // node group 0..3
  int n0 = blockIdx.x * PNPB;
  int n1 = min(n0 + PNPB, N);
  int curb = -1;
  float m0 = 0.f, m1 = 0.f;
  for (int n = n0 + g; n < n1; n += 4) {
    int bg = batch[n];
    ushort2 v = *(const ushort2*)&x[(size_t)n * HC + cp];
    float v0 = h2f(v.x), v1 = h2f(v.y);
    if (bg != curb) {
      if (curb >= 0) {
        atomicMax(&pool[curb * HC + cp],     enc_f(m0));
        atomicMax(&pool[curb * HC + cp + 1], enc_f(m1));
      }
      curb = bg; m0 = v0; m1 = v1;
    } else {
      m0 = fmaxf(m0, v0);
      m1 = fmaxf(m1, v1);
    }
  }
  if (curb >= 0) {
    atomicMax(&pool[curb * HC + cp],     enc_f(m0));
    atomicMax(&pool[curb * HC + cp + 1], enc_f(m1));
  }
}

__global__ void pool_final_kernel(const unsigned* __restrict__ pool, float* __restrict__ out, int n)
{
  int i = blockIdx.x * blockDim.x + threadIdx.x;
  if (i < n) out[i] = dec_f(pool[i]);
}

// ---------- launch ----------
extern "C" void kernel_launch(void* const* d_in, const int* in_sizes, int n_in,
                              void* d_out, int out_size, void* d_ws, size_t ws_size,
                              hipStream_t stream)
{
  const float* x_scalar = (const float*)d_in[0];
  const int* i0 = (const int*)d_in[1];
  const int* i1 = (const int*)d_in[2];
  const int* i2 = (const int*)d_in[3];
  const int* i3 = (const int*)d_in[4];
  const int* i4 = (const int*)d_in[5];
  const int* ei = (const int*)d_in[6];
  const int* batch = (const int*)d_in[7];
  const float* e0 = (const float*)d_in[8];
  const float* e1 = (const float*)d_in[9];
  const float* e2 = (const float*)d_in[10];
  const float* e3 = (const float*)d_in[11];
  const float* e4 = (const float*)d_in[12];
  const float* ln_g = (const float*)d_in[13];
  const float* ln_b = (const float*)d_in[14];
  const float* W1 = (const float*)d_in[15];
  const float* as1 = (const float*)d_in[16];
  const float* ad1 = (const float*)d_in[17];
  const float* b1 = (const float*)d_in[18];
  const float* W2 = (const float*)d_in[19];
  const float* as2 = (const float*)d_in[20];
  const float* ad2 = (const float*)d_in[21];
  const float* b2 = (const float*)d_in[22];

  const int N  = in_sizes[0] / SF;
  const int E  = in_sizes[6] / 2;
  const int Et = E + N;
  const int Bg = out_size / HC;
  const int MT64 = (N + 63) / 64;

  char* w = (char*)d_ws;
  auto alloc = [&](size_t bytes) -> char* {
    char* p = w;
    w += (bytes + 255) & ~(size_t)255;
    return p;
  };
  unsigned short* featsb = (unsigned short*)alloc((size_t)N * KP1 * 2);
  unsigned short* G      = (unsigned short*)alloc((size_t)4 * N * KP1 * 2);
  unsigned short* X2b    = (unsigned short*)alloc((size_t)N * 512 * 2);
  unsigned short* H2b    = (unsigned short*)alloc((size_t)N * HC * 2);
  unsigned short* X3b    = (unsigned short*)alloc((size_t)N * HC * 2);
  unsigned short* W1t    = (unsigned short*)alloc((size_t)512 * KP1 * 2);
  unsigned short* W2t    = (unsigned short*)alloc((size_t)HC * 512 * 2);
  float* vs      = (float*)alloc((size_t)KP1 * 4 * 4);
  float* vd      = (float*)alloc((size_t)KP1 * 4 * 4);
  float* als1    = (float*)alloc((size_t)N * 4 * 4);
  float* ald1    = (float*)alloc((size_t)N * 4 * 4);
  float* als2    = (float*)alloc((size_t)N * 4);
  float* ald2    = (float*)alloc((size_t)N * 4);
  int*   deg     = (int*)alloc((size_t)N * 4);
  int*   rowptr  = (int*)alloc((size_t)(N + 1) * 4);
  int*   fill    = (int*)alloc((size_t)N * 4);
  int*   csr_src = (int*)alloc((size_t)Et * 4);
  unsigned* pool = (unsigned*)alloc((size_t)Bg * HC * 4);

  // combined prep: W packs, vs/vd, deg+als2/ald2 zero, pool init (one launch)
  {
    int nb1 = (512 * KP1 + 255) / 256;
    int nb2 = (HC * 512 + 255) / 256;
    int nb3 = (N + 255) / 256;
    int nb4 = (Bg * HC + 255) / 256;
    prep_combined_kernel<<<nb1 + nb2 + nb3 + nb4 + DIN, 256, 0, stream>>>(
        W1, W2, W1t, W2t, as1, ad1, vs, vd, deg, pool, als2, ald2, N, Bg * HC);
  }

  // features + LN + fused layer-1 logits + fused degree count
  {
    int nodeBlocks  = (N + 3) / 4;
    int countBlocks = (Et + 255) / 256;
    feat_ln_kernel<<<nodeBlocks + countBlocks, 256, 0, stream>>>(
        x_scalar, i0, i1, i2, i3, i4, e0, e1, e2, e3, e4, ln_g, ln_b,
        (const float4*)vs, (const float4*)vd, featsb, als1, ald1,
        ei, E, deg, nodeBlocks, N);
  }

  // CSR scan + scatter
  scan_kernel<<<1, 1024, 0, stream>>>(deg, rowptr, fill, N);
  scatter_kernel<<<(Et + 255) / 256, 256, 0, stream>>>(ei, E, N, fill, csr_src);

  // layer 1: aggregate feats, then per-head GEMM (+b1, ELU); 64x64 dbuf tiles
  agg_feat_kernel<<<(N + 3) / 4, 256, 0, stream>>>(featsb, (const float4*)als1,
                                                   (const float4*)ald1,
                                                   rowptr, csr_src, G, N);
  gemm64_kernel<KP1, 1, 0><<<dim3(2, MT64, 4), 256, 0, stream>>>(
      G, W1t, X2b, N, 512, (size_t)N * KP1, (size_t)HC * KP1, HC, b1,
      nullptr, nullptr, nullptr, nullptr);

  // layer 2: GEMM with fused logits (atomicAdd), then aggregate (+b2, ELU)
  gemm64_kernel<512, 0, 1><<<dim3(2, MT64, 1), 256, 0, stream>>>(
      X2b, W2t, H2b, N, HC, 0, 0, 0, nullptr,
      as2, ad2, als2, ald2);
  agg_h2_kernel<<<(N + 3) / 4, 256, 0, stream>>>(H2b, als2, ald2, rowptr, csr_src, b2, X3b, N);

  // pool
  pool_seg_kernel<<<(N + PNPB - 1) / PNPB, 256, 0, stream>>>(X3b, batch, pool, N);
  pool_final_kernel<<<(Bg * HC + 255) / 256, 256, 0, stream>>>(pool, (float*)d_out, Bg * HC);
}

// Round 14
// 216.454 us; speedup vs baseline: 1.4069x; 1.0165x over previous
//
#include <hip/hip_runtime.h>
#include <math.h>

#define SF 16
#define ED 32
#define LTOK 20
#define DIN 176
#define KP1 192   // DIN padded to multiple of 32
#define HC 128

typedef _Float16 f16x8 __attribute__((ext_vector_type(8)));
typedef _Float16 f16x2 __attribute__((ext_vector_type(2)));
typedef float f32x4 __attribute__((ext_vector_type(4)));

#if defined(__has_builtin)
#if __has_builtin(__builtin_amdgcn_fdot2)
#define HAVE_FDOT2 1
#endif
#endif

static __device__ __forceinline__ float leaky02(float x) { return x >= 0.f ? x : 0.2f * x; }
static __device__ __forceinline__ float eluf(float x)    { return x > 0.f ? x : expm1f(x); }
static __device__ __forceinline__ unsigned short f2h(float f)
{
  _Float16 h = (_Float16)f;
  return __builtin_bit_cast(unsigned short, h);
}
static __device__ __forceinline__ float h2f(unsigned short u)
{
  return (float)__builtin_bit_cast(_Float16, u);
}
static __device__ __forceinline__ float readlane_f(float v, int j)
{
  return __int_as_float(__builtin_amdgcn_readlane(__float_as_int(v), j));
}
static __device__ __forceinline__ unsigned readlane_u(unsigned v, int j)
{
  return (unsigned)__builtin_amdgcn_readlane((int)v, j);
}
#ifdef HAVE_FDOT2
static __device__ __forceinline__ float dot2(unsigned w, unsigned f, float c)
{
  return __builtin_amdgcn_fdot2(__builtin_bit_cast(f16x2, w),
                                __builtin_bit_cast(f16x2, f), c, false);
}
#endif

// ---------- 0. combined prep: pack W1t/W2t, vs/vd, zero deg+als2+ald2, init pool ----------
__global__ __launch_bounds__(256)
void prep_combined_kernel(const float* __restrict__ W1, const float* __restrict__ W2,
                          unsigned short* __restrict__ W1t, unsigned short* __restrict__ W2t,
                          const float* __restrict__ as1, const float* __restrict__ ad1,
                          float* __restrict__ vs, float* __restrict__ vd,
                          int* __restrict__ deg, unsigned* __restrict__ pool,
                          float* __restrict__ als2, float* __restrict__ ald2,
                          int N, int poolN)
{
  const int nb1 = (512 * KP1 + 255) / 256;
  const int nb2 = (HC * 512 + 255) / 256;
  const int nb3 = (N + 255) / 256;
  const int nb4 = (poolN + 255) / 256;
  int bid = blockIdx.x;
  if (bid < nb1) {                       // W1t [512][KP1] <- W1 [DIN][512]
    int i = bid * 256 + threadIdx.x;
    if (i < 512 * KP1) {
      int n = i / KP1, k = i - n * KP1;
      W1t[i] = f2h((k < DIN) ? W1[(size_t)k * 512 + n] : 0.f);
    }
    return;
  }
  bid -= nb1;
  if (bid < nb2) {                       // W2t [HC][512] <- W2 [512][HC]
    int i = bid * 256 + threadIdx.x;
    if (i < HC * 512) {
      int n = i / 512, k = i - n * 512;
      W2t[i] = f2h(W2[(size_t)k * HC + n]);
    }
    return;
  }
  bid -= nb2;
  if (bid < nb3) {                       // deg = 0, als2/ald2 = 0 (atomic targets)
    int i = bid * 256 + threadIdx.x;
    if (i < N) { deg[i] = 0; als2[i] = 0.f; ald2[i] = 0.f; }
    return;
  }
  bid -= nb3;
  if (bid < nb4) {                       // pool = enc(-FLT_MAX)
    int i = bid * 256 + threadIdx.x;
    if (i < poolN) pool[i] = 0x00800000u;
    return;
  }
  bid -= nb4;
  {                                      // vs/vd row bid (0..DIN-1)
    int k = bid;
    int h = threadIdx.x >> 6, lane = threadIdx.x & 63;
    const float* row = W1 + (size_t)k * 512 + h * HC;
    float s = row[lane] * as1[h * HC + lane] + row[lane + 64] * as1[h * HC + lane + 64];
    float d = row[lane] * ad1[h * HC + lane] + row[lane + 64] * ad1[h * HC + lane + 64];
    #pragma unroll
    for (int off = 32; off; off >>= 1) { s += __shfl_down(s, off); d += __shfl_down(d, off); }
    if (lane == 0) { vs[k * 4 + h] = s; vd[k * 4 + h] = d; }
  }
}

// ---------- 1. features + LayerNorm + fused logits + fused edge-count ----------
// One wave per node, lane owns channels {l, l+64, l+128} (scalar gathers:
// float vals[20] = 20 VGPR keeps all 20 loads in flight; the float2 variant
// needed 40 VGPR and the compiler serialized it -- measured regression R13).
__global__ __launch_bounds__(256)
void feat_ln_kernel(const float* __restrict__ xs,
                    const int* __restrict__ i0, const int* __restrict__ i1,
                    const int* __restrict__ i2, const int* __restrict__ i3,
                    const int* __restrict__ i4,
                    const float* __restrict__ e0, const float* __restrict__ e1,
                    const float* __restrict__ e2, const float* __restrict__ e3,
                    const float* __restrict__ e4,
                    const float* __restrict__ g, const float* __restrict__ b,
                    const float4* __restrict__ vs, const float4* __restrict__ vd,
                    unsigned short* __restrict__ out,
                    float* __restrict__ als, float* __restrict__ ald,
                    const int* __restrict__ ei, int E, int* __restrict__ deg,
                    int nodeBlocks, int N)
{
  if (blockIdx.x >= nodeBlocks) {        // fused CSR degree count
    int e = (blockIdx.x - nodeBlocks) * 256 + threadIdx.x;
    if (e < E + N) {
      int dst = (e < E) ? ei[E + e] : (e - E);
      atomicAdd(&deg[dst], 1);
    }
    return;
  }

  __shared__ int toks[4][5 * LTOK];
  int w = threadIdx.x >> 6, l = threadIdx.x & 63;
  int n = blockIdx.x * 4 + w;
  if (n >= N) return;

  for (int q = l; q < 5 * LTOK; q += 64) {
    int f = q / LTOK, j = q - f * LTOK;
    const int* ip = (f == 0) ? i0 : (f == 1) ? i1 : (f == 2) ? i2 : (f == 3) ? i3 : i4;
    toks[w][q] = ip[n * LTOK + j];
  }

  float v[3];
  #pragma unroll
  for (int r = 0; r < 3; ++r) {
    int c = l + r * 64;
    float val = 0.f;
    if (c < SF) {
      val = xs[n * SF + c];
    } else if (c < DIN) {
      int f  = (c - SF) >> 5;
      int ch = (c - SF) & 31;
      const float* ep = (f == 0) ? e0 : (f == 1) ? e1 : (f == 2) ? e2 : (f == 3) ? e3 : e4;
      float vals[LTOK];
      #pragma unroll
      for (int j = 0; j < LTOK; ++j)
        vals[j] = ep[toks[w][f * LTOK + j] * ED + ch];
      float sum = 0.f, cnt = 0.f;
      #pragma unroll
      for (int j = 0; j < LTOK; ++j)
        if (toks[w][f * LTOK + j] != 0) { sum += vals[j]; cnt += 1.f; }
      val = sum / (cnt + 1e-9f);
    }
    v[r] = val;
  }

  float p  = v[0] + v[1] + v[2];
  float p2 = v[0] * v[0] + v[1] * v[1] + v[2] * v[2];
  #pragma unroll
  for (int off = 32; off; off >>= 1) { p += __shfl_xor(p, off); p2 += __shfl_xor(p2, off); }
  float mu   = p * (1.f / DIN);
  float var  = fmaxf(p2 * (1.f / DIN) - mu * mu, 0.f);
  float rstd = rsqrtf(var + 1e-5f);

  float pr[8] = {0.f, 0.f, 0.f, 0.f, 0.f, 0.f, 0.f, 0.f};
  #pragma unroll
  for (int r = 0; r < 3; ++r) {
    int c = l + r * 64;
    float y = 0.f;
    if (c < DIN) {
      y = (v[r] - mu) * rstd * g[c] + b[c];
      float4 s4 = vs[c], d4 = vd[c];
      pr[0] += y * s4.x; pr[1] += y * s4.y; pr[2] += y * s4.z; pr[3] += y * s4.w;
      pr[4] += y * d4.x; pr[5] += y * d4.y; pr[6] += y * d4.z; pr[7] += y * d4.w;
    }
    if (c < KP1) out[(size_t)n * KP1 + c] = f2h(y);
  }
  #pragma unroll
  for (int j = 0; j < 8; ++j)
    #pragma unroll
    for (int off = 32; off; off >>= 1) pr[j] += __shfl_xor(pr[j], off);
  if (l == 0) {
    als[n * 4 + 0] = pr[0]; als[n * 4 + 1] = pr[1];
    als[n * 4 + 2] = pr[2]; als[n * 4 + 3] = pr[3];
    ald[n * 4 + 0] = pr[4]; ald[n * 4 + 1] = pr[5];
    ald[n * 4 + 2] = pr[6]; ald[n * 4 + 3] = pr[7];
  }
}

// ---------- 2. CSR build (scan + scatter) ----------
__global__ __launch_bounds__(1024)
void scan_kernel(const int* __restrict__ deg, int* __restrict__ rowptr,
                 int* __restrict__ fill, int N)
{
  __shared__ int sums[1024];
  int t = threadIdx.x;
  int CH = (N + 1023) >> 10;
  int base = t * CH;
  int s = 0;
  for (int i = 0; i < CH; ++i) if (base + i < N) s += deg[base + i];
  sums[t] = s;
  __syncthreads();
  for (int off = 1; off < 1024; off <<= 1) {
    int v = (t >= off) ? sums[t - off] : 0;
    __syncthreads();
    sums[t] += v;
    __syncthreads();
  }
  int run = sums[t] - s;  // exclusive prefix
  for (int i = 0; i < CH; ++i) {
    if (base + i < N) {
      rowptr[base + i] = run;
      fill[base + i]   = run;
      run += deg[base + i];
    }
  }
  if (t == 1023) rowptr[N] = run;
}

__global__ void scatter_kernel(const int* __restrict__ ei, int E, int N,
                               int* __restrict__ fill, int* __restrict__ csr_src)
{
  int e = blockIdx.x * blockDim.x + threadIdx.x;
  if (e < E + N) {
    int src, dst;
    if (e < E) { src = ei[e]; dst = ei[E + e]; }
    else       { src = dst = e - E; }
    int pos = atomicAdd(&fill[dst], 1);
    csr_src[pos] = src;
  }
}

// ---------- 3. layer-1 aggregation over FEATURES (fdot2, 4-edge unrolled) ----------
__global__ __launch_bounds__(256)
void agg_feat_kernel(const unsigned short* __restrict__ F,   // [N][KP1] f16
                     const float4* __restrict__ als, const float4* __restrict__ ald,
                     const int* __restrict__ rowptr, const int* __restrict__ csr_src,
                     unsigned short* __restrict__ G, int N)  // [4][N][KP1] f16
{
  int wv = threadIdx.x >> 6, lane = threadIdx.x & 63;
  int n = blockIdx.x * 4 + wv;
  if (n >= N) return;
  int rs = __builtin_amdgcn_readfirstlane(rowptr[n]);
  int re = __builtin_amdgcn_readfirstlane(rowptr[n + 1]);
  int cnt = re - rs;
  float4 ad4 = ald[n];
  float aldv[4] = { ad4.x, ad4.y, ad4.z, ad4.w };

  float acc[4][4] = {};
  bool act = lane < 48;                      // 48 lanes x 4 ch = 192
  const unsigned short* Fb = F + lane * 4;

#ifdef HAVE_FDOT2
  auto passB = [&](int srcA, unsigned pkw[4], int ccnt) {
    for (int j = 0; j < ccnt; j += 4) {      // 4 edges per iteration
      int s0 = __builtin_amdgcn_readlane(srcA, j);
      int s1 = __builtin_amdgcn_readlane(srcA, j + 1);
      int s2 = __builtin_amdgcn_readlane(srcA, j + 2);
      int s3 = __builtin_amdgcn_readlane(srcA, j + 3);
      unsigned wa0 = readlane_u(pkw[0], j), wb0 = readlane_u(pkw[0], j + 2);
      unsigned wa1 = readlane_u(pkw[1], j), wb1 = readlane_u(pkw[1], j + 2);
      unsigned wa2 = readlane_u(pkw[2], j), wb2 = readlane_u(pkw[2], j + 2);
      unsigned wa3 = readlane_u(pkw[3], j), wb3 = readlane_u(pkw[3], j + 2);
      if (act) {
        int2 a0 = *(const int2*)(Fb + (size_t)s0 * KP1);
        int2 a1 = *(const int2*)(Fb + (size_t)s1 * KP1);
        int2 a2 = *(const int2*)(Fb + (size_t)s2 * KP1);
        int2 a3 = *(const int2*)(Fb + (size_t)s3 * KP1);
        unsigned pA = __builtin_amdgcn_perm((unsigned)a0.x, (unsigned)a1.x, 0x01000504u);
        unsigned pB = __builtin_amdgcn_perm((unsigned)a0.x, (unsigned)a1.x, 0x03020706u);
        unsigned pC = __builtin_amdgcn_perm((unsigned)a0.y, (unsigned)a1.y, 0x01000504u);
        unsigned pD = __builtin_amdgcn_perm((unsigned)a0.y, (unsigned)a1.y, 0x03020706u);
        unsigned qA = __builtin_amdgcn_perm((unsigned)a2.x, (unsigned)a3.x, 0x01000504u);
        unsigned qB = __builtin_amdgcn_perm((unsigned)a2.x, (unsigned)a3.x, 0x03020706u);
        unsigned qC = __builtin_amdgcn_perm((unsigned)a2.y, (unsigned)a3.y, 0x01000504u);
        unsigned qD = __builtin_amdgcn_perm((unsigned)a2.y, (unsigned)a3.y, 0x03020706u);
        acc[0][0] = dot2(wa0, pA, acc[0][0]); acc[0][1] = dot2(wa0, pB, acc[0][1]);
        acc[0][2] = dot2(wa0, pC, acc[0][2]); acc[0][3] = dot2(wa0, pD, acc[0][3]);
        acc[1][0] = dot2(wa1, pA, acc[1][0]); acc[1][1] = dot2(wa1, pB, acc[1][1]);
        acc[1][2] = dot2(wa1, pC, acc[1][2]); acc[1][3] = dot2(wa1, pD, acc[1][3]);
        acc[2][0] = dot2(wa2, pA, acc[2][0]); acc[2][1] = dot2(wa2, pB, acc[2][1]);
        acc[2][2] = dot2(wa2, pC, acc[2][2]); acc[2][3] = dot2(wa2, pD, acc[2][3]);
        acc[3][0] = dot2(wa3, pA, acc[3][0]); acc[3][1] = dot2(wa3, pB, acc[3][1]);
        acc[3][2] = dot2(wa3, pC, acc[3][2]); acc[3][3] = dot2(wa3, pD, acc[3][3]);
        acc[0][0] = dot2(wb0, qA, acc[0][0]); acc[0][1] = dot2(wb0, qB, acc[0][1]);
        acc[0][2] = dot2(wb0, qC, acc[0][2]); acc[0][3] = dot2(wb0, qD, acc[0][3]);
        acc[1][0] = dot2(wb1, qA, acc[1][0]); acc[1][1] = dot2(wb1, qB, acc[1][1]);
        acc[1][2] = dot2(wb1, qC, acc[1][2]); acc[1][3] = dot2(wb1, qD, acc[1][3]);
        acc[2][0] = dot2(wb2, qA, acc[2][0]); acc[2][1] = dot2(wb2, qB, acc[2][1]);
        acc[2][2] = dot2(wb2, qC, acc[2][2]); acc[2][3] = dot2(wb2, qD, acc[2][3]);
        acc[3][0] = dot2(wb3, qA, acc[3][0]); acc[3][1] = dot2(wb3, qB, acc[3][1]);
        acc[3][2] = dot2(wb3, qC, acc[3][2]); acc[3][3] = dot2(wb3, qD, acc[3][3]);
      }
    }
  };
#else
  auto passB = [&](int srcA, float wf[4], int ccnt) {
    for (int j = 0; j < ccnt; ++j) {
      int src = __builtin_amdgcn_readlane(srcA, j);
      float q0 = readlane_f(wf[0], j), q1 = readlane_f(wf[1], j);
      float q2 = readlane_f(wf[2], j), q3 = readlane_f(wf[3], j);
      if (act) {
        int2 a0 = *(const int2*)(Fb + (size_t)src * KP1);
        float f0 = h2f((unsigned short)(a0.x & 0xffff));
        float f1 = h2f((unsigned short)((unsigned)a0.x >> 16));
        float f2v = h2f((unsigned short)(a0.y & 0xffff));
        float f3 = h2f((unsigned short)((unsigned)a0.y >> 16));
        acc[0][0] += q0 * f0; acc[0][1] += q0 * f1; acc[0][2] += q0 * f2v; acc[0][3] += q0 * f3;
        acc[1][0] += q1 * f0; acc[1][1] += q1 * f1; acc[1][2] += q1 * f2v; acc[1][3] += q1 * f3;
        acc[2][0] += q2 * f0; acc[2][1] += q2 * f1; acc[2][2] += q2 * f2v; acc[2][3] += q2 * f3;
        acc[3][0] += q3 * f0; acc[3][1] += q3 * f1; acc[3][2] += q3 * f2v; acc[3][3] += q3 * f3;
      }
    }
  };
#endif

  if (cnt <= 64) {
    int srcA = 0;
    float e[4] = { -1e30f, -1e30f, -1e30f, -1e30f };
    if (lane < cnt) {
      srcA = csr_src[rs + lane];
      float4 a4 = als[srcA];
      e[0] = leaky02(a4.x + aldv[0]); e[1] = leaky02(a4.y + aldv[1]);
      e[2] = leaky02(a4.z + aldv[2]); e[3] = leaky02(a4.w + aldv[3]);
    }
    float m[4] = { e[0], e[1], e[2], e[3] };
    #pragma unroll
    for (int off = 32; off; off >>= 1)
      #pragma unroll
      for (int h = 0; h < 4; ++h) m[h] = fmaxf(m[h], __shfl_xor(m[h], off));
    float w[4];
    #pragma unroll
    for (int h = 0; h < 4; ++h) w[h] = (lane < cnt) ? __expf(e[h] - m[h]) : 0.f;
    float den[4] = { w[0], w[1], w[2], w[3] };
    #pragma unroll
    for (int off = 32; off; off >>= 1)
      #pragma unroll
      for (int h = 0; h < 4; ++h) den[h] += __shfl_xor(den[h], off);
    #pragma unroll
    for (int h = 0; h < 4; ++h) w[h] /= (den[h] + 1e-16f);
#ifdef HAVE_FDOT2
    unsigned pkw[4];
    #pragma unroll
    for (int h = 0; h < 4; ++h) {
      float wn = __shfl_xor(w[h], 1);
      float we = (lane & 1) ? wn : w[h];
      float wo = (lane & 1) ? w[h] : wn;
      pkw[h] = (unsigned)f2h(we) | ((unsigned)f2h(wo) << 16);
    }
    passB(srcA, pkw, cnt);
#else
    passB(srcA, w, cnt);
#endif
  } else {
    float m[4], s[4];
    #pragma unroll
    for (int h = 0; h < 4; ++h) { m[h] = -1e30f; s[h] = 0.f; }
    for (int i = rs + lane; i < re; i += 64) {
      int src = csr_src[i];
      float4 a4 = als[src];
      float av[4] = { a4.x, a4.y, a4.z, a4.w };
      #pragma unroll
      for (int h = 0; h < 4; ++h) {
        float e = leaky02(av[h] + aldv[h]);
        float Mx = fmaxf(m[h], e);
        s[h] = s[h] * __expf(m[h] - Mx) + __expf(e - Mx);
        m[h] = Mx;
      }
    }
    #pragma unroll
    for (int off = 32; off; off >>= 1) {
      #pragma unroll
      for (int h = 0; h < 4; ++h) {
        float m2 = __shfl_xor(m[h], off);
        float s2 = __shfl_xor(s[h], off);
        float Mx = fmaxf(m[h], m2);
        s[h] = s[h] * __expf(m[h] - Mx) + s2 * __expf(m2 - Mx);
        m[h] = Mx;
      }
    }
    float inv[4];
    #pragma unroll
    for (int h = 0; h < 4; ++h) inv[h] = 1.f / (s[h] + 1e-16f);
    for (int b0 = rs; b0 < re; b0 += 64) {
      int bcnt = min(64, re - b0);
      int srcA = 0;
      float w[4] = {0.f, 0.f, 0.f, 0.f};
      if (lane < bcnt) {
        srcA = csr_src[b0 + lane];
        float4 a4 = als[srcA];
        w[0] = __expf(leaky02(a4.x + aldv[0]) - m[0]) * inv[0];
        w[1] = __expf(leaky02(a4.y + aldv[1]) - m[1]) * inv[1];
        w[2] = __expf(leaky02(a4.z + aldv[2]) - m[2]) * inv[2];
        w[3] = __expf(leaky02(a4.w + aldv[3]) - m[3]) * inv[3];
      }
#ifdef HAVE_FDOT2
      unsigned pkw[4];
      #pragma unroll
      for (int h = 0; h < 4; ++h) {
        float wn = __shfl_xor(w[h], 1);
        float we = (lane & 1) ? wn : w[h];
        float wo = (lane & 1) ? w[h] : wn;
        pkw[h] = (unsigned)f2h(we) | ((unsigned)f2h(wo) << 16);
      }
      passB(srcA, pkw, bcnt);
#else
      passB(srcA, w, bcnt);
#endif
    }
  }

  if (act) {
    #pragma unroll
    for (int h = 0; h < 4; ++h) {
      int2 o;
      o.x = (int)f2h(acc[h][0]) | ((int)f2h(acc[h][1]) << 16);
      o.y = (int)f2h(acc[h][2]) | ((int)f2h(acc[h][3]) << 16);
      *(int2*)&G[((size_t)h * N + n) * KP1 + lane * 4] = o;
    }
  }
}

// ---------- 4. MFMA f16 GEMM, 64x64 tile, DOUBLE-BUFFERED LDS (1 barrier/K-step) ----------
template<int KPad, int BIAS_ELU, int LOGITS>
__global__ __launch_bounds__(256)
void gemm64_kernel(const unsigned short* __restrict__ A,
                   const unsigned short* __restrict__ Bt,
                   unsigned short* __restrict__ C,
                   int M, int Nc,
                   size_t aStrideZ, size_t bStrideZ, int cColStrideZ,
                   const float* __restrict__ bias,
                   const float* __restrict__ la_s, const float* __restrict__ la_d,
                   float* __restrict__ lout_s, float* __restrict__ lout_d)
{
  A  += blockIdx.z * aStrideZ;
  Bt += blockIdx.z * bStrideZ;
  const int colZ = blockIdx.z * cColStrideZ;

  __shared__ __align__(16) unsigned short As[2][4][520];
  __shared__ __align__(16) unsigned short Bs[2][4][520];

  const int tid  = threadIdx.x;
  const int lane = tid & 63, wv = tid >> 6;
  const int bm = blockIdx.y << 6, bn = blockIdx.x << 6;
  const int wm = (wv >> 1) << 5, wn = (wv & 1) << 5;
  const int kc = lane >> 4, r16 = lane & 15;

  const int srow = lane, skc = wv;
  const unsigned short* Ap = A + (size_t)(bm + srow) * KPad + skc * 8;
  const unsigned short* Bp = Bt + (size_t)(bn + srow) * KPad + skc * 8;
  const bool aok = (bm + srow) < M;

  f32x4 acc[2][2];
  #pragma unroll
  for (int m = 0; m < 2; ++m)
    #pragma unroll
    for (int n2 = 0; n2 < 2; ++n2) acc[m][n2] = (f32x4){0.f, 0.f, 0.f, 0.f};

  constexpr int NT = KPad / 32;
  int4 av = aok ? *(const int4*)Ap : make_int4(0, 0, 0, 0);
  int4 bv = *(const int4*)Bp;

  for (int t = 0; t < NT; ++t) {
    const int cur = t & 1;
    *(int4*)&As[cur][skc][srow * 8] = av;
    *(int4*)&Bs[cur][skc][srow * 8] = bv;
    if (t + 1 < NT) {
      av = aok ? *(const int4*)(Ap + (t + 1) * 32) : make_int4(0, 0, 0, 0);
      bv = *(const int4*)(Bp + (t + 1) * 32);
    }
    __syncthreads();
    f16x8 af0 = *(const f16x8*)&As[cur][kc][(wm + r16) * 8];
    f16x8 af1 = *(const f16x8*)&As[cur][kc][(wm + 16 + r16) * 8];
    f16x8 bf0 = *(const f16x8*)&Bs[cur][kc][(wn + r16) * 8];
    f16x8 bf1 = *(const f16x8*)&Bs[cur][kc][(wn + 16 + r16) * 8];
    acc[0][0] = __builtin_amdgcn_mfma_f32_16x16x32_f16(af0, bf0, acc[0][0], 0, 0, 0);
    acc[0][1] = __builtin_amdgcn_mfma_f32_16x16x32_f16(af0, bf1, acc[0][1], 0, 0, 0);
    acc[1][0] = __builtin_amdgcn_mfma_f32_16x16x32_f16(af1, bf0, acc[1][0], 0, 0, 0);
    acc[1][1] = __builtin_amdgcn_mfma_f32_16x16x32_f16(af1, bf1, acc[1][1], 0, 0, 0);
  }

  const int rq = lane >> 4;
  #pragma unroll
  for (int m = 0; m < 2; ++m) {
    #pragma unroll
    for (int r = 0; r < 4; ++r) {
      int row = bm + wm + m * 16 + rq * 4 + r;
      if (row < M) {
        #pragma unroll
        for (int n2 = 0; n2 < 2; ++n2) {
          int col = colZ + bn + wn + n2 * 16 + r16;
          float val = acc[m][n2][r];
          if (BIAS_ELU) { val += bias[col]; val = eluf(val); }
          C[(size_t)row * Nc + col] = f2h(val);
        }
      }
    }
  }

  if (LOGITS) {
    #pragma unroll
    for (int m = 0; m < 2; ++m) {
      #pragma unroll
      for (int r = 0; r < 4; ++r) {
        float ps = 0.f, pd = 0.f;
        #pragma unroll
        for (int n2 = 0; n2 < 2; ++n2) {
          int col = bn + wn + n2 * 16 + r16;
          float val = acc[m][n2][r];
          ps += val * la_s[col];
          pd += val * la_d[col];
        }
        #pragma unroll
        for (int off = 1; off < 16; off <<= 1) {
          ps += __shfl_xor(ps, off);
          pd += __shfl_xor(pd, off);
        }
        int row = bm + wm + m * 16 + rq * 4 + r;
        if (r16 == 0 && row < M) {
          atomicAdd(&lout_s[row], ps);
          atomicAdd(&lout_d[row], pd);
        }
      }
    }
  }
}

// ---------- 6. layer-2 aggregation; fdot2 4-edge unrolled, lane owns 2 channels ----------
__global__ __launch_bounds__(256)
void agg_h2_kernel(const unsigned short* __restrict__ H,
                   const float* __restrict__ al_s, const float* __restrict__ al_d,
                   const int* __restrict__ rowptr, const int* __restrict__ csr_src,
                   const float* __restrict__ bias, unsigned short* __restrict__ out, int N)
{
  int wv = threadIdx.x >> 6, lane = threadIdx.x & 63;
  int n = blockIdx.x * 4 + wv;
  if (n >= N) return;
  int rs = __builtin_amdgcn_readfirstlane(rowptr[n]);
  int re = __builtin_amdgcn_readfirstlane(rowptr[n + 1]);
  int cnt = re - rs;
  float ald = al_d[n];
  float acc0 = 0.f, acc1 = 0.f;
  const unsigned short* Hb = H + lane * 2;   // lane owns channels {2l, 2l+1}

#ifdef HAVE_FDOT2
  auto passB = [&](int srcA, unsigned pkw, int ccnt) {
    for (int j = 0; j < ccnt; j += 4) {
      int s0 = __builtin_amdgcn_readlane(srcA, j);
      int s1 = __builtin_amdgcn_readlane(srcA, j + 1);
      int s2 = __builtin_amdgcn_readlane(srcA, j + 2);
      int s3 = __builtin_amdgcn_readlane(srcA, j + 3);
      unsigned pw0 = readlane_u(pkw, j);
      unsigned pw1 = readlane_u(pkw, j + 2);
      unsigned a0 = *(const unsigned*)(Hb + (size_t)s0 * HC);
      unsigned a1 = *(const unsigned*)(Hb + (size_t)s1 * HC);
      unsigned a2 = *(const unsigned*)(Hb + (size_t)s2 * HC);
      unsigned a3 = *(const unsigned*)(Hb + (size_t)s3 * HC);
      unsigned p0 = __builtin_amdgcn_perm(a0, a1, 0x01000504u);
      unsigned p1 = __builtin_amdgcn_perm(a0, a1, 0x03020706u);
      unsigned q0 = __builtin_amdgcn_perm(a2, a3, 0x01000504u);
      unsigned q1 = __builtin_amdgcn_perm(a2, a3, 0x03020706u);
      acc0 = dot2(pw0, p0, acc0);
      acc1 = dot2(pw0, p1, acc1);
      acc0 = dot2(pw1, q0, acc0);
      acc1 = dot2(pw1, q1, acc1);
    }
  };
#else
  auto passB = [&](int srcA, float wf, int ccnt) {
    for (int j = 0; j < ccnt; ++j) {
      int src = __builtin_amdgcn_readlane(srcA, j);
      float wgt = readlane_f(wf, j);
      unsigned a0 = *(const unsigned*)(Hb + (size_t)src * HC);
      acc0 += wgt * h2f((unsigned short)(a0 & 0xffff));
      acc1 += wgt * h2f((unsigned short)(a0 >> 16));
    }
  };
#endif

  if (cnt <= 64) {
    int srcA = 0;
    float e = -1e30f;
    if (lane < cnt) {
      srcA = csr_src[rs + lane];
      e = leaky02(al_s[srcA] + ald);
    }
    float m = e;
    #pragma unroll
    for (int off = 32; off; off >>= 1) m = fmaxf(m, __shfl_xor(m, off));
    float w = (lane < cnt) ? __expf(e - m) : 0.f;
    float den = w;
    #pragma unroll
    for (int off = 32; off; off >>= 1) den += __shfl_xor(den, off);
    w /= (den + 1e-16f);
#ifdef HAVE_FDOT2
    float wn2 = __shfl_xor(w, 1);
    float we = (lane & 1) ? wn2 : w;
    float wo = (lane & 1) ? w : wn2;
    unsigned pkw = (unsigned)f2h(we) | ((unsigned)f2h(wo) << 16);
    passB(srcA, pkw, cnt);
#else
    passB(srcA, w, cnt);
#endif
  } else {
    float m = -1e30f, s = 0.f;
    for (int i = rs + lane; i < re; i += 64) {
      int src = csr_src[i];
      float e = leaky02(al_s[src] + ald);
      float Mx = fmaxf(m, e);
      s = s * __expf(m - Mx) + __expf(e - Mx);
      m = Mx;
    }
    #pragma unroll
    for (int off = 32; off; off >>= 1) {
      float m2 = __shfl_xor(m, off);
      float s2 = __shfl_xor(s, off);
      float Mx = fmaxf(m, m2);
      s = s * __expf(m - Mx) + s2 * __expf(m2 - Mx);
      m = Mx;
    }
    float inv_den = 1.f / (s + 1e-16f);
    for (int c0 = rs; c0 < re; c0 += 64) {
      int ccnt = min(64, re - c0);
      int srcA = 0;
      float w = 0.f;
      if (lane < ccnt) {
        srcA = csr_src[c0 + lane];
        w = __expf(leaky02(al_s[srcA] + ald) - m) * inv_den;
      }
#ifdef HAVE_FDOT2
      float wn2 = __shfl_xor(w, 1);
      float we = (lane & 1) ? wn2 : w;
      float wo = (lane & 1) ? w : wn2;
      unsigned pkw = (unsigned)f2h(we) | ((unsigned)f2h(wo) << 16);
      passB(srcA, pkw, ccnt);
#else
      passB(srcA, w, ccnt);
#endif
    }
  }

  float o0 = eluf(acc0 + bias[lane * 2 + 0]);
  float o1 = eluf(acc1 + bias[lane * 2 + 1]);
  unsigned o = (unsigned)f2h(o0) | ((unsigned)f2h(o1) << 16);
  *(unsigned*)&out[(size_t)n * HC + lane * 2] = o;
}

// ---------- 7. global max pool (segmented over sorted batch) ----------
static __device__ __forceinline__ unsigned enc_f(float f)
{
  unsigned u = __float_as_uint(f);
  return (u & 0x80000000u) ? ~u : (u | 0x80000000u);
}
static __device__ __forceinline__ float dec_f(unsigned u)
{
  return (u & 0x80000000u) ? __uint_as_float(u & 0x7fffffffu) : __uint_as_float(~u);
}

#define PNPB 128   // nodes per pool block
__global__ __launch_bounds__(256)
void pool_seg_kernel(const unsigned short* __restrict__ x, const int* __restrict__ batch,
                     unsigned* __restrict__ pool, int N)
{
  int cp = (threadIdx.x & 63) * 2;     // channel pair
  int g  = threadIdx.x >> 6;           // node group 0..3
  int n0 = blockIdx.x * PNPB;
  int n1 = min(n0 + PNPB, N);
  int curb = -1;
  float m0 = 0.f, m1 = 0.f;
  for (int n = n0 + g; n < n1; n += 4) {
    int bg = batch[n];
    ushort2 v = *(const ushort2*)&x[(size_t)n * HC + cp];
    float v0 = h2f(v.x), v1 = h2f(v.y);
    if (bg != curb) {
      if (curb >= 0) {
        atomicMax(&pool[curb * HC + cp],     enc_f(m0));
        atomicMax(&pool[curb * HC + cp + 1], enc_f(m1));
      }
      curb = bg; m0 = v0; m1 = v1;
    } else {
      m0 = fmaxf(m0, v0);
      m1 = fmaxf(m1, v1);
    }
  }
  if (curb >= 0) {
    atomicMax(&pool[curb * HC + cp],     enc_f(m0));
    atomicMax(&pool[curb * HC + cp + 1], enc_f(m1));
  }
}

__global__ void pool_final_kernel(const unsigned* __restrict__ pool, float* __restrict__ out, int n)
{
  int i = blockIdx.x * blockDim.x + threadIdx.x;
  if (i < n) out[i] = dec_f(pool[i]);
}

// ---------- launch ----------
extern "C" void kernel_launch(void* const* d_in, const int* in_sizes, int n_in,
                              void* d_out, int out_size, void* d_ws, size_t ws_size,
                              hipStream_t stream)
{
  const float* x_scalar = (const float*)d_in[0];
  const int* i0 = (const int*)d_in[1];
  const int* i1 = (const int*)d_in[2];
  const int* i2 = (const int*)d_in[3];
  const int* i3 = (const int*)d_in[4];
  const int* i4 = (const int*)d_in[5];
  const int* ei = (const int*)d_in[6];
  const int* batch = (const int*)d_in[7];
  const float* e0 = (const float*)d_in[8];
  const float* e1 = (const float*)d_in[9];
  const float* e2 = (const float*)d_in[10];
  const float* e3 = (const float*)d_in[11];
  const float* e4 = (const float*)d_in[12];
  const float* ln_g = (const float*)d_in[13];
  const float* ln_b = (const float*)d_in[14];
  const float* W1 = (const float*)d_in[15];
  const float* as1 = (const float*)d_in[16];
  const float* ad1 = (const float*)d_in[17];
  const float* b1 = (const float*)d_in[18];
  const float* W2 = (const float*)d_in[19];
  const float* as2 = (const float*)d_in[20];
  const float* ad2 = (const float*)d_in[21];
  const float* b2 = (const float*)d_in[22];

  const int N  = in_sizes[0] / SF;
  const int E  = in_sizes[6] / 2;
  const int Et = E + N;
  const int Bg = out_size / HC;
  const int MT64 = (N + 63) / 64;

  char* w = (char*)d_ws;
  auto alloc = [&](size_t bytes) -> char* {
    char* p = w;
    w += (bytes + 255) & ~(size_t)255;
    return p;
  };
  unsigned short* featsb = (unsigned short*)alloc((size_t)N * KP1 * 2);
  unsigned short* G      = (unsigned short*)alloc((size_t)4 * N * KP1 * 2);
  unsigned short* X2b    = (unsigned short*)alloc((size_t)N * 512 * 2);
  unsigned short* H2b    = (unsigned short*)alloc((size_t)N * HC * 2);
  unsigned short* X3b    = (unsigned short*)alloc((size_t)N * HC * 2);
  unsigned short* W1t    = (unsigned short*)alloc((size_t)512 * KP1 * 2);
  unsigned short* W2t    = (unsigned short*)alloc((size_t)HC * 512 * 2);
  float* vs      = (float*)alloc((size_t)KP1 * 4 * 4);
  float* vd      = (float*)alloc((size_t)KP1 * 4 * 4);
  float* als1    = (float*)alloc((size_t)N * 4 * 4);
  float* ald1    = (float*)alloc((size_t)N * 4 * 4);
  float* als2    = (float*)alloc((size_t)N * 4);
  float* ald2    = (float*)alloc((size_t)N * 4);
  int*   deg     = (int*)alloc((size_t)N * 4);
  int*   rowptr  = (int*)alloc((size_t)(N + 1) * 4);
  int*   fill    = (int*)alloc((size_t)N * 4);
  int*   csr_src = (int*)alloc((size_t)Et * 4);
  unsigned* pool = (unsigned*)alloc((size_t)Bg * HC * 4);

  // combined prep: W packs, vs/vd, deg+als2/ald2 zero, pool init (one launch)
  {
    int nb1 = (512 * KP1 + 255) / 256;
    int nb2 = (HC * 512 + 255) / 256;
    int nb3 = (N + 255) / 256;
    int nb4 = (Bg * HC + 255) / 256;
    prep_combined_kernel<<<nb1 + nb2 + nb3 + nb4 + DIN, 256, 0, stream>>>(
        W1, W2, W1t, W2t, as1, ad1, vs, vd, deg, pool, als2, ald2, N, Bg * HC);
  }

  // features + LN + fused layer-1 logits + fused degree count
  {
    int nodeBlocks  = (N + 3) / 4;
    int countBlocks = (Et + 255) / 256;
    feat_ln_kernel<<<nodeBlocks + countBlocks, 256, 0, stream>>>(
        x_scalar, i0, i1, i2, i3, i4, e0, e1, e2, e3, e4, ln_g, ln_b,
        (const float4*)vs, (const float4*)vd, featsb, als1, ald1,
        ei, E, deg, nodeBlocks, N);
  }

  // CSR scan + scatter
  scan_kernel<<<1, 1024, 0, stream>>>(deg, rowptr, fill, N);
  scatter_kernel<<<(Et + 255) / 256, 256, 0, stream>>>(ei, E, N, fill, csr_src);

  // layer 1: aggregate feats, then per-head GEMM (+b1, ELU); 64x64 dbuf tiles
  agg_feat_kernel<<<(N + 3) / 4, 256, 0, stream>>>(featsb, (const float4*)als1,
                                                   (const float4*)ald1,
                                                   rowptr, csr_src, G, N);
  gemm64_kernel<KP1, 1, 0><<<dim3(2, MT64, 4), 256, 0, stream>>>(
      G, W1t, X2b, N, 512, (size_t)N * KP1, (size_t)HC * KP1, HC, b1,
      nullptr, nullptr, nullptr, nullptr);

  // layer 2: GEMM with fused logits (atomicAdd), then aggregate (+b2, ELU)
  gemm64_kernel<512, 0, 1><<<dim3(2, MT64, 1), 256, 0, stream>>>(
      X2b, W2t, H2b, N, HC, 0, 0, 0, nullptr,
      as2, ad2, als2, ald2);
  agg_h2_kernel<<<(N + 3) / 4, 256, 0, stream>>>(H2b, als2, ald2, rowptr, csr_src, b2, X3b, N);

  // pool
  pool_seg_kernel<<<(N + PNPB - 1) / PNPB, 256, 0, stream>>>(X3b, batch, pool, N);
  pool_final_kernel<<<(Bg * HC + 255) / 256, 256, 0, stream>>>(pool, (float*)d_out, Bg * HC);
}

// Round 15
// 213.872 us; speedup vs baseline: 1.4239x; 1.0121x over previous
//
#include <hip/hip_runtime.h>
#include <math.h>

#define SF 16
#define ED 32
#define LTOK 20
#define DIN 176
#define KP1 192   // DIN padded to multiple of 32
#define HC 128

typedef _Float16 f16x8 __attribute__((ext_vector_type(8)));
typedef _Float16 f16x2 __attribute__((ext_vector_type(2)));
typedef float f32x4 __attribute__((ext_vector_type(4)));

#if defined(__has_builtin)
#if __has_builtin(__builtin_amdgcn_fdot2)
#define HAVE_FDOT2 1
#endif
#endif

static __device__ __forceinline__ float leaky02(float x) { return x >= 0.f ? x : 0.2f * x; }
static __device__ __forceinline__ float eluf(float x)    { return x > 0.f ? x : expm1f(x); }
static __device__ __forceinline__ unsigned short f2h(float f)
{
  _Float16 h = (_Float16)f;
  return __builtin_bit_cast(unsigned short, h);
}
static __device__ __forceinline__ float h2f(unsigned short u)
{
  return (float)__builtin_bit_cast(_Float16, u);
}
static __device__ __forceinline__ float readlane_f(float v, int j)
{
  return __int_as_float(__builtin_amdgcn_readlane(__float_as_int(v), j));
}
static __device__ __forceinline__ unsigned readlane_u(unsigned v, int j)
{
  return (unsigned)__builtin_amdgcn_readlane((int)v, j);
}
#ifdef HAVE_FDOT2
static __device__ __forceinline__ float dot2(unsigned w, unsigned f, float c)
{
  return __builtin_amdgcn_fdot2(__builtin_bit_cast(f16x2, w),
                                __builtin_bit_cast(f16x2, f), c, false);
}
#endif

// ---------- 0. combined prep: pack W1t/W2t, vs/vd, zero deg+als2+ald2, init pool ----------
__global__ __launch_bounds__(256)
void prep_combined_kernel(const float* __restrict__ W1, const float* __restrict__ W2,
                          unsigned short* __restrict__ W1t, unsigned short* __restrict__ W2t,
                          const float* __restrict__ as1, const float* __restrict__ ad1,
                          float* __restrict__ vs, float* __restrict__ vd,
                          int* __restrict__ deg, unsigned* __restrict__ pool,
                          float* __restrict__ als2, float* __restrict__ ald2,
                          int N, int poolN)
{
  const int nb1 = (512 * KP1 + 255) / 256;
  const int nb2 = (HC * 512 + 255) / 256;
  const int nb3 = (N + 255) / 256;
  const int nb4 = (poolN + 255) / 256;
  int bid = blockIdx.x;
  if (bid < nb1) {                       // W1t [512][KP1] <- W1 [DIN][512]
    int i = bid * 256 + threadIdx.x;
    if (i < 512 * KP1) {
      int n = i / KP1, k = i - n * KP1;
      W1t[i] = f2h((k < DIN) ? W1[(size_t)k * 512 + n] : 0.f);
    }
    return;
  }
  bid -= nb1;
  if (bid < nb2) {                       // W2t [HC][512] <- W2 [512][HC]
    int i = bid * 256 + threadIdx.x;
    if (i < HC * 512) {
      int n = i / 512, k = i - n * 512;
      W2t[i] = f2h(W2[(size_t)k * HC + n]);
    }
    return;
  }
  bid -= nb2;
  if (bid < nb3) {                       // deg = 0, als2/ald2 = 0 (atomic targets)
    int i = bid * 256 + threadIdx.x;
    if (i < N) { deg[i] = 0; als2[i] = 0.f; ald2[i] = 0.f; }
    return;
  }
  bid -= nb3;
  if (bid < nb4) {                       // pool = enc(-FLT_MAX)
    int i = bid * 256 + threadIdx.x;
    if (i < poolN) pool[i] = 0x00800000u;
    return;
  }
  bid -= nb4;
  {                                      // vs/vd row bid (0..DIN-1)
    int k = bid;
    int h = threadIdx.x >> 6, lane = threadIdx.x & 63;
    const float* row = W1 + (size_t)k * 512 + h * HC;
    float s = row[lane] * as1[h * HC + lane] + row[lane + 64] * as1[h * HC + lane + 64];
    float d = row[lane] * ad1[h * HC + lane] + row[lane + 64] * ad1[h * HC + lane + 64];
    #pragma unroll
    for (int off = 32; off; off >>= 1) { s += __shfl_down(s, off); d += __shfl_down(d, off); }
    if (lane == 0) { vs[k * 4 + h] = s; vd[k * 4 + h] = d; }
  }
}

// ---------- 1. features + LayerNorm + fused logits + fused edge-count ----------
// One wave per node, lane owns channels {l, l+64, l+128}. Tokens are
// register-cached per round (tk[20]) so both gather addresses and the mask
// come from VGPRs -- no second LDS read on the critical path.
__global__ __launch_bounds__(256)
void feat_ln_kernel(const float* __restrict__ xs,
                    const int* __restrict__ i0, const int* __restrict__ i1,
                    const int* __restrict__ i2, const int* __restrict__ i3,
                    const int* __restrict__ i4,
                    const float* __restrict__ e0, const float* __restrict__ e1,
                    const float* __restrict__ e2, const float* __restrict__ e3,
                    const float* __restrict__ e4,
                    const float* __restrict__ g, const float* __restrict__ b,
                    const float4* __restrict__ vs, const float4* __restrict__ vd,
                    unsigned short* __restrict__ out,
                    float* __restrict__ als, float* __restrict__ ald,
                    const int* __restrict__ ei, int E, int* __restrict__ deg,
                    int nodeBlocks, int N)
{
  if (blockIdx.x >= nodeBlocks) {        // fused CSR degree count
    int e = (blockIdx.x - nodeBlocks) * 256 + threadIdx.x;
    if (e < E + N) {
      int dst = (e < E) ? ei[E + e] : (e - E);
      atomicAdd(&deg[dst], 1);
    }
    return;
  }

  __shared__ int toks[4][5 * LTOK];
  int w = threadIdx.x >> 6, l = threadIdx.x & 63;
  int n = blockIdx.x * 4 + w;
  if (n >= N) return;

  for (int q = l; q < 5 * LTOK; q += 64) {
    int f = q / LTOK, j = q - f * LTOK;
    const int* ip = (f == 0) ? i0 : (f == 1) ? i1 : (f == 2) ? i2 : (f == 3) ? i3 : i4;
    toks[w][q] = ip[n * LTOK + j];
  }

  float v[3];
  #pragma unroll
  for (int r = 0; r < 3; ++r) {
    int c = l + r * 64;
    float val = 0.f;
    if (c < SF) {
      val = xs[n * SF + c];
    } else if (c < DIN) {
      int f  = (c - SF) >> 5;
      int ch = (c - SF) & 31;
      const float* ep = (f == 0) ? e0 : (f == 1) ? e1 : (f == 2) ? e2 : (f == 3) ? e3 : e4;
      // register-cache tokens: one LDS read each; addr+mask both from regs
      int tk[LTOK];
      #pragma unroll
      for (int j = 0; j < LTOK; ++j) tk[j] = toks[w][f * LTOK + j];
      float vals[LTOK];
      #pragma unroll
      for (int j = 0; j < LTOK; ++j) vals[j] = ep[tk[j] * ED + ch];
      float sum = 0.f, cnt = 0.f;
      #pragma unroll
      for (int j = 0; j < LTOK; ++j)
        if (tk[j] != 0) { sum += vals[j]; cnt += 1.f; }
      val = sum / (cnt + 1e-9f);
    }
    v[r] = val;
  }

  float p  = v[0] + v[1] + v[2];
  float p2 = v[0] * v[0] + v[1] * v[1] + v[2] * v[2];
  #pragma unroll
  for (int off = 32; off; off >>= 1) { p += __shfl_xor(p, off); p2 += __shfl_xor(p2, off); }
  float mu   = p * (1.f / DIN);
  float var  = fmaxf(p2 * (1.f / DIN) - mu * mu, 0.f);
  float rstd = rsqrtf(var + 1e-5f);

  float pr[8] = {0.f, 0.f, 0.f, 0.f, 0.f, 0.f, 0.f, 0.f};
  #pragma unroll
  for (int r = 0; r < 3; ++r) {
    int c = l + r * 64;
    float y = 0.f;
    if (c < DIN) {
      y = (v[r] - mu) * rstd * g[c] + b[c];
      float4 s4 = vs[c], d4 = vd[c];
      pr[0] += y * s4.x; pr[1] += y * s4.y; pr[2] += y * s4.z; pr[3] += y * s4.w;
      pr[4] += y * d4.x; pr[5] += y * d4.y; pr[6] += y * d4.z; pr[7] += y * d4.w;
    }
    if (c < KP1) out[(size_t)n * KP1 + c] = f2h(y);
  }
  #pragma unroll
  for (int j = 0; j < 8; ++j)
    #pragma unroll
    for (int off = 32; off; off >>= 1) pr[j] += __shfl_xor(pr[j], off);
  if (l == 0) {
    als[n * 4 + 0] = pr[0]; als[n * 4 + 1] = pr[1];
    als[n * 4 + 2] = pr[2]; als[n * 4 + 3] = pr[3];
    ald[n * 4 + 0] = pr[4]; ald[n * 4 + 1] = pr[5];
    ald[n * 4 + 2] = pr[6]; ald[n * 4 + 3] = pr[7];
  }
}

// ---------- 2. CSR build (scan + scatter) ----------
__global__ __launch_bounds__(1024)
void scan_kernel(const int* __restrict__ deg, int* __restrict__ rowptr,
                 int* __restrict__ fill, int N)
{
  __shared__ int sums[1024];
  int t = threadIdx.x;
  int CH = (N + 1023) >> 10;
  int base = t * CH;
  int s = 0;
  for (int i = 0; i < CH; ++i) if (base + i < N) s += deg[base + i];
  sums[t] = s;
  __syncthreads();
  for (int off = 1; off < 1024; off <<= 1) {
    int v = (t >= off) ? sums[t - off] : 0;
    __syncthreads();
    sums[t] += v;
    __syncthreads();
  }
  int run = sums[t] - s;  // exclusive prefix
  for (int i = 0; i < CH; ++i) {
    if (base + i < N) {
      rowptr[base + i] = run;
      fill[base + i]   = run;
      run += deg[base + i];
    }
  }
  if (t == 1023) rowptr[N] = run;
}

__global__ void scatter_kernel(const int* __restrict__ ei, int E, int N,
                               int* __restrict__ fill, int* __restrict__ csr_src)
{
  int e = blockIdx.x * blockDim.x + threadIdx.x;
  if (e < E + N) {
    int src, dst;
    if (e < E) { src = ei[e]; dst = ei[E + e]; }
    else       { src = dst = e - E; }
    int pos = atomicAdd(&fill[dst], 1);
    csr_src[pos] = src;
  }
}

// ---------- 3. layer-1 aggregation over FEATURES (fdot2, 4-edge unrolled) ----------
__global__ __launch_bounds__(256)
void agg_feat_kernel(const unsigned short* __restrict__ F,   // [N][KP1] f16
                     const float4* __restrict__ als, const float4* __restrict__ ald,
                     const int* __restrict__ rowptr, const int* __restrict__ csr_src,
                     unsigned short* __restrict__ G, int N)  // [4][N][KP1] f16
{
  int wv = threadIdx.x >> 6, lane = threadIdx.x & 63;
  int n = blockIdx.x * 4 + wv;
  if (n >= N) return;
  int rs = __builtin_amdgcn_readfirstlane(rowptr[n]);
  int re = __builtin_amdgcn_readfirstlane(rowptr[n + 1]);
  int cnt = re - rs;
  float4 ad4 = ald[n];
  float aldv[4] = { ad4.x, ad4.y, ad4.z, ad4.w };

  float acc[4][4] = {};
  bool act = lane < 48;                      // 48 lanes x 4 ch = 192
  const unsigned short* Fb = F + lane * 4;

#ifdef HAVE_FDOT2
  auto passB = [&](int srcA, unsigned pkw[4], int ccnt) {
    for (int j = 0; j < ccnt; j += 4) {      // 4 edges per iteration
      int s0 = __builtin_amdgcn_readlane(srcA, j);
      int s1 = __builtin_amdgcn_readlane(srcA, j + 1);
      int s2 = __builtin_amdgcn_readlane(srcA, j + 2);
      int s3 = __builtin_amdgcn_readlane(srcA, j + 3);
      unsigned wa0 = readlane_u(pkw[0], j), wb0 = readlane_u(pkw[0], j + 2);
      unsigned wa1 = readlane_u(pkw[1], j), wb1 = readlane_u(pkw[1], j + 2);
      unsigned wa2 = readlane_u(pkw[2], j), wb2 = readlane_u(pkw[2], j + 2);
      unsigned wa3 = readlane_u(pkw[3], j), wb3 = readlane_u(pkw[3], j + 2);
      if (act) {
        int2 a0 = *(const int2*)(Fb + (size_t)s0 * KP1);
        int2 a1 = *(const int2*)(Fb + (size_t)s1 * KP1);
        int2 a2 = *(const int2*)(Fb + (size_t)s2 * KP1);
        int2 a3 = *(const int2*)(Fb + (size_t)s3 * KP1);
        unsigned pA = __builtin_amdgcn_perm((unsigned)a0.x, (unsigned)a1.x, 0x01000504u);
        unsigned pB = __builtin_amdgcn_perm((unsigned)a0.x, (unsigned)a1.x, 0x03020706u);
        unsigned pC = __builtin_amdgcn_perm((unsigned)a0.y, (unsigned)a1.y, 0x01000504u);
        unsigned pD = __builtin_amdgcn_perm((unsigned)a0.y, (unsigned)a1.y, 0x03020706u);
        unsigned qA = __builtin_amdgcn_perm((unsigned)a2.x, (unsigned)a3.x, 0x01000504u);
        unsigned qB = __builtin_amdgcn_perm((unsigned)a2.x, (unsigned)a3.x, 0x03020706u);
        unsigned qC = __builtin_amdgcn_perm((unsigned)a2.y, (unsigned)a3.y, 0x01000504u);
        unsigned qD = __builtin_amdgcn_perm((unsigned)a2.y, (unsigned)a3.y, 0x03020706u);
        acc[0][0] = dot2(wa0, pA, acc[0][0]); acc[0][1] = dot2(wa0, pB, acc[0][1]);
        acc[0][2] = dot2(wa0, pC, acc[0][2]); acc[0][3] = dot2(wa0, pD, acc[0][3]);
        acc[1][0] = dot2(wa1, pA, acc[1][0]); acc[1][1] = dot2(wa1, pB, acc[1][1]);
        acc[1][2] = dot2(wa1, pC, acc[1][2]); acc[1][3] = dot2(wa1, pD, acc[1][3]);
        acc[2][0] = dot2(wa2, pA, acc[2][0]); acc[2][1] = dot2(wa2, pB, acc[2][1]);
        acc[2][2] = dot2(wa2, pC, acc[2][2]); acc[2][3] = dot2(wa2, pD, acc[2][3]);
        acc[3][0] = dot2(wa3, pA, acc[3][0]); acc[3][1] = dot2(wa3, pB, acc[3][1]);
        acc[3][2] = dot2(wa3, pC, acc[3][2]); acc[3][3] = dot2(wa3, pD, acc[3][3]);
        acc[0][0] = dot2(wb0, qA, acc[0][0]); acc[0][1] = dot2(wb0, qB, acc[0][1]);
        acc[0][2] = dot2(wb0, qC, acc[0][2]); acc[0][3] = dot2(wb0, qD, acc[0][3]);
        acc[1][0] = dot2(wb1, qA, acc[1][0]); acc[1][1] = dot2(wb1, qB, acc[1][1]);
        acc[1][2] = dot2(wb1, qC, acc[1][2]); acc[1][3] = dot2(wb1, qD, acc[1][3]);
        acc[2][0] = dot2(wb2, qA, acc[2][0]); acc[2][1] = dot2(wb2, qB, acc[2][1]);
        acc[2][2] = dot2(wb2, qC, acc[2][2]); acc[2][3] = dot2(wb2, qD, acc[2][3]);
        acc[3][0] = dot2(wb3, qA, acc[3][0]); acc[3][1] = dot2(wb3, qB, acc[3][1]);
        acc[3][2] = dot2(wb3, qC, acc[3][2]); acc[3][3] = dot2(wb3, qD, acc[3][3]);
      }
    }
  };
#else
  auto passB = [&](int srcA, float wf[4], int ccnt) {
    for (int j = 0; j < ccnt; ++j) {
      int src = __builtin_amdgcn_readlane(srcA, j);
      float q0 = readlane_f(wf[0], j), q1 = readlane_f(wf[1], j);
      float q2 = readlane_f(wf[2], j), q3 = readlane_f(wf[3], j);
      if (act) {
        int2 a0 = *(const int2*)(Fb + (size_t)src * KP1);
        float f0 = h2f((unsigned short)(a0.x & 0xffff));
        float f1 = h2f((unsigned short)((unsigned)a0.x >> 16));
        float f2v = h2f((unsigned short)(a0.y & 0xffff));
        float f3 = h2f((unsigned short)((unsigned)a0.y >> 16));
        acc[0][0] += q0 * f0; acc[0][1] += q0 * f1; acc[0][2] += q0 * f2v; acc[0][3] += q0 * f3;
        acc[1][0] += q1 * f0; acc[1][1] += q1 * f1; acc[1][2] += q1 * f2v; acc[1][3] += q1 * f3;
        acc[2][0] += q2 * f0; acc[2][1] += q2 * f1; acc[2][2] += q2 * f2v; acc[2][3] += q2 * f3;
        acc[3][0] += q3 * f0; acc[3][1] += q3 * f1; acc[3][2] += q3 * f2v; acc[3][3] += q3 * f3;
      }
    }
  };
#endif

  if (cnt <= 64) {
    int srcA = 0;
    float e[4] = { -1e30f, -1e30f, -1e30f, -1e30f };
    if (lane < cnt) {
      srcA = csr_src[rs + lane];
      float4 a4 = als[srcA];
      e[0] = leaky02(a4.x + aldv[0]); e[1] = leaky02(a4.y + aldv[1]);
      e[2] = leaky02(a4.z + aldv[2]); e[3] = leaky02(a4.w + aldv[3]);
    }
    float m[4] = { e[0], e[1], e[2], e[3] };
    #pragma unroll
    for (int off = 32; off; off >>= 1)
      #pragma unroll
      for (int h = 0; h < 4; ++h) m[h] = fmaxf(m[h], __shfl_xor(m[h], off));
    float w[4];
    #pragma unroll
    for (int h = 0; h < 4; ++h) w[h] = (lane < cnt) ? __expf(e[h] - m[h]) : 0.f;
    float den[4] = { w[0], w[1], w[2], w[3] };
    #pragma unroll
    for (int off = 32; off; off >>= 1)
      #pragma unroll
      for (int h = 0; h < 4; ++h) den[h] += __shfl_xor(den[h], off);
    #pragma unroll
    for (int h = 0; h < 4; ++h) w[h] /= (den[h] + 1e-16f);
#ifdef HAVE_FDOT2
    unsigned pkw[4];
    #pragma unroll
    for (int h = 0; h < 4; ++h) {
      float wn = __shfl_xor(w[h], 1);
      float we = (lane & 1) ? wn : w[h];
      float wo = (lane & 1) ? w[h] : wn;
      pkw[h] = (unsigned)f2h(we) | ((unsigned)f2h(wo) << 16);
    }
    passB(srcA, pkw, cnt);
#else
    passB(srcA, w, cnt);
#endif
  } else {
    float m[4], s[4];
    #pragma unroll
    for (int h = 0; h < 4; ++h) { m[h] = -1e30f; s[h] = 0.f; }
    for (int i = rs + lane; i < re; i += 64) {
      int src = csr_src[i];
      float4 a4 = als[src];
      float av[4] = { a4.x, a4.y, a4.z, a4.w };
      #pragma unroll
      for (int h = 0; h < 4; ++h) {
        float e = leaky02(av[h] + aldv[h]);
        float Mx = fmaxf(m[h], e);
        s[h] = s[h] * __expf(m[h] - Mx) + __expf(e - Mx);
        m[h] = Mx;
      }
    }
    #pragma unroll
    for (int off = 32; off; off >>= 1) {
      #pragma unroll
      for (int h = 0; h < 4; ++h) {
        float m2 = __shfl_xor(m[h], off);
        float s2 = __shfl_xor(s[h], off);
        float Mx = fmaxf(m[h], m2);
        s[h] = s[h] * __expf(m[h] - Mx) + s2 * __expf(m2 - Mx);
        m[h] = Mx;
      }
    }
    float inv[4];
    #pragma unroll
    for (int h = 0; h < 4; ++h) inv[h] = 1.f / (s[h] + 1e-16f);
    for (int b0 = rs; b0 < re; b0 += 64) {
      int bcnt = min(64, re - b0);
      int srcA = 0;
      float w[4] = {0.f, 0.f, 0.f, 0.f};
      if (lane < bcnt) {
        srcA = csr_src[b0 + lane];
        float4 a4 = als[srcA];
        w[0] = __expf(leaky02(a4.x + aldv[0]) - m[0]) * inv[0];
        w[1] = __expf(leaky02(a4.y + aldv[1]) - m[1]) * inv[1];
        w[2] = __expf(leaky02(a4.z + aldv[2]) - m[2]) * inv[2];
        w[3] = __expf(leaky02(a4.w + aldv[3]) - m[3]) * inv[3];
      }
#ifdef HAVE_FDOT2
      unsigned pkw[4];
      #pragma unroll
      for (int h = 0; h < 4; ++h) {
        float wn = __shfl_xor(w[h], 1);
        float we = (lane & 1) ? wn : w[h];
        float wo = (lane & 1) ? w[h] : wn;
        pkw[h] = (unsigned)f2h(we) | ((unsigned)f2h(wo) << 16);
      }
      passB(srcA, pkw, bcnt);
#else
      passB(srcA, w, bcnt);
#endif
    }
  }

  if (act) {
    #pragma unroll
    for (int h = 0; h < 4; ++h) {
      int2 o;
      o.x = (int)f2h(acc[h][0]) | ((int)f2h(acc[h][1]) << 16);
      o.y = (int)f2h(acc[h][2]) | ((int)f2h(acc[h][3]) << 16);
      *(int2*)&G[((size_t)h * N + n) * KP1 + lane * 4] = o;
    }
  }
}

// ---------- 4. MFMA f16 GEMM, 64x64 tile, DOUBLE-BUFFERED LDS (1 barrier/K-step) ----------
template<int KPad, int BIAS_ELU, int LOGITS>
__global__ __launch_bounds__(256)
void gemm64_kernel(const unsigned short* __restrict__ A,
                   const unsigned short* __restrict__ Bt,
                   unsigned short* __restrict__ C,
                   int M, int Nc,
                   size_t aStrideZ, size_t bStrideZ, int cColStrideZ,
                   const float* __restrict__ bias,
                   const float* __restrict__ la_s, const float* __restrict__ la_d,
                   float* __restrict__ lout_s, float* __restrict__ lout_d)
{
  A  += blockIdx.z * aStrideZ;
  Bt += blockIdx.z * bStrideZ;
  const int colZ = blockIdx.z * cColStrideZ;

  __shared__ __align__(16) unsigned short As[2][4][520];
  __shared__ __align__(16) unsigned short Bs[2][4][520];

  const int tid  = threadIdx.x;
  const int lane = tid & 63, wv = tid >> 6;
  const int bm = blockIdx.y << 6, bn = blockIdx.x << 6;
  const int wm = (wv >> 1) << 5, wn = (wv & 1) << 5;
  const int kc = lane >> 4, r16 = lane & 15;

  const int srow = lane, skc = wv;
  const unsigned short* Ap = A + (size_t)(bm + srow) * KPad + skc * 8;
  const unsigned short* Bp = Bt + (size_t)(bn + srow) * KPad + skc * 8;
  const bool aok = (bm + srow) < M;

  f32x4 acc[2][2];
  #pragma unroll
  for (int m = 0; m < 2; ++m)
    #pragma unroll
    for (int n2 = 0; n2 < 2; ++n2) acc[m][n2] = (f32x4){0.f, 0.f, 0.f, 0.f};

  constexpr int NT = KPad / 32;
  int4 av = aok ? *(const int4*)Ap : make_int4(0, 0, 0, 0);
  int4 bv = *(const int4*)Bp;

  for (int t = 0; t < NT; ++t) {
    const int cur = t & 1;
    *(int4*)&As[cur][skc][srow * 8] = av;
    *(int4*)&Bs[cur][skc][srow * 8] = bv;
    if (t + 1 < NT) {
      av = aok ? *(const int4*)(Ap + (t + 1) * 32) : make_int4(0, 0, 0, 0);
      bv = *(const int4*)(Bp + (t + 1) * 32);
    }
    __syncthreads();
    f16x8 af0 = *(const f16x8*)&As[cur][kc][(wm + r16) * 8];
    f16x8 af1 = *(const f16x8*)&As[cur][kc][(wm + 16 + r16) * 8];
    f16x8 bf0 = *(const f16x8*)&Bs[cur][kc][(wn + r16) * 8];
    f16x8 bf1 = *(const f16x8*)&Bs[cur][kc][(wn + 16 + r16) * 8];
    acc[0][0] = __builtin_amdgcn_mfma_f32_16x16x32_f16(af0, bf0, acc[0][0], 0, 0, 0);
    acc[0][1] = __builtin_amdgcn_mfma_f32_16x16x32_f16(af0, bf1, acc[0][1], 0, 0, 0);
    acc[1][0] = __builtin_amdgcn_mfma_f32_16x16x32_f16(af1, bf0, acc[1][0], 0, 0, 0);
    acc[1][1] = __builtin_amdgcn_mfma_f32_16x16x32_f16(af1, bf1, acc[1][1], 0, 0, 0);
  }

  const int rq = lane >> 4;
  #pragma unroll
  for (int m = 0; m < 2; ++m) {
    #pragma unroll
    for (int r = 0; r < 4; ++r) {
      int row = bm + wm + m * 16 + rq * 4 + r;
      if (row < M) {
        #pragma unroll
        for (int n2 = 0; n2 < 2; ++n2) {
          int col = colZ + bn + wn + n2 * 16 + r16;
          float val = acc[m][n2][r];
          if (BIAS_ELU) { val += bias[col]; val = eluf(val); }
          C[(size_t)row * Nc + col] = f2h(val);
        }
      }
    }
  }

  if (LOGITS) {
    #pragma unroll
    for (int m = 0; m < 2; ++m) {
      #pragma unroll
      for (int r = 0; r < 4; ++r) {
        float ps = 0.f, pd = 0.f;
        #pragma unroll
        for (int n2 = 0; n2 < 2; ++n2) {
          int col = bn + wn + n2 * 16 + r16;
          float val = acc[m][n2][r];
          ps += val * la_s[col];
          pd += val * la_d[col];
        }
        #pragma unroll
        for (int off = 1; off < 16; off <<= 1) {
          ps += __shfl_xor(ps, off);
          pd += __shfl_xor(pd, off);
        }
        int row = bm + wm + m * 16 + rq * 4 + r;
        if (r16 == 0 && row < M) {
          atomicAdd(&lout_s[row], ps);
          atomicAdd(&lout_d[row], pd);
        }
      }
    }
  }
}

// ---------- 6. layer-2 aggregation; fdot2 4-edge unrolled, lane owns 2 channels ----------
__global__ __launch_bounds__(256)
void agg_h2_kernel(const unsigned short* __restrict__ H,
                   const float* __restrict__ al_s, const float* __restrict__ al_d,
                   const int* __restrict__ rowptr, const int* __restrict__ csr_src,
                   const float* __restrict__ bias, unsigned short* __restrict__ out, int N)
{
  int wv = threadIdx.x >> 6, lane = threadIdx.x & 63;
  int n = blockIdx.x * 4 + wv;
  if (n >= N) return;
  int rs = __builtin_amdgcn_readfirstlane(rowptr[n]);
  int re = __builtin_amdgcn_readfirstlane(rowptr[n + 1]);
  int cnt = re - rs;
  float ald = al_d[n];
  float acc0 = 0.f, acc1 = 0.f;
  const unsigned short* Hb = H + lane * 2;   // lane owns channels {2l, 2l+1}

#ifdef HAVE_FDOT2
  auto passB = [&](int srcA, unsigned pkw, int ccnt) {
    for (int j = 0; j < ccnt; j += 4) {
      int s0 = __builtin_amdgcn_readlane(srcA, j);
      int s1 = __builtin_amdgcn_readlane(srcA, j + 1);
      int s2 = __builtin_amdgcn_readlane(srcA, j + 2);
      int s3 = __builtin_amdgcn_readlane(srcA, j + 3);
      unsigned pw0 = readlane_u(pkw, j);
      unsigned pw1 = readlane_u(pkw, j + 2);
      unsigned a0 = *(const unsigned*)(Hb + (size_t)s0 * HC);
      unsigned a1 = *(const unsigned*)(Hb + (size_t)s1 * HC);
      unsigned a2 = *(const unsigned*)(Hb + (size_t)s2 * HC);
      unsigned a3 = *(const unsigned*)(Hb + (size_t)s3 * HC);
      unsigned p0 = __builtin_amdgcn_perm(a0, a1, 0x01000504u);
      unsigned p1 = __builtin_amdgcn_perm(a0, a1, 0x03020706u);
      unsigned q0 = __builtin_amdgcn_perm(a2, a3, 0x01000504u);
      unsigned q1 = __builtin_amdgcn_perm(a2, a3, 0x03020706u);
      acc0 = dot2(pw0, p0, acc0);
      acc1 = dot2(pw0, p1, acc1);
      acc0 = dot2(pw1, q0, acc0);
      acc1 = dot2(pw1, q1, acc1);
    }
  };
#else
  auto passB = [&](int srcA, float wf, int ccnt) {
    for (int j = 0; j < ccnt; ++j) {
      int src = __builtin_amdgcn_readlane(srcA, j);
      float wgt = readlane_f(wf, j);
      unsigned a0 = *(const unsigned*)(Hb + (size_t)src * HC);
      acc0 += wgt * h2f((unsigned short)(a0 & 0xffff));
      acc1 += wgt * h2f((unsigned short)(a0 >> 16));
    }
  };
#endif

  if (cnt <= 64) {
    int srcA = 0;
    float e = -1e30f;
    if (lane < cnt) {
      srcA = csr_src[rs + lane];
      e = leaky02(al_s[srcA] + ald);
    }
    float m = e;
    #pragma unroll
    for (int off = 32; off; off >>= 1) m = fmaxf(m, __shfl_xor(m, off));
    float w = (lane < cnt) ? __expf(e - m) : 0.f;
    float den = w;
    #pragma unroll
    for (int off = 32; off; off >>= 1) den += __shfl_xor(den, off);
    w /= (den + 1e-16f);
#ifdef HAVE_FDOT2
    float wn2 = __shfl_xor(w, 1);
    float we = (lane & 1) ? wn2 : w;
    float wo = (lane & 1) ? w : wn2;
    unsigned pkw = (unsigned)f2h(we) | ((unsigned)f2h(wo) << 16);
    passB(srcA, pkw, cnt);
#else
    passB(srcA, w, cnt);
#endif
  } else {
    float m = -1e30f, s = 0.f;
    for (int i = rs + lane; i < re; i += 64) {
      int src = csr_src[i];
      float e = leaky02(al_s[src] + ald);
      float Mx = fmaxf(m, e);
      s = s * __expf(m - Mx) + __expf(e - Mx);
      m = Mx;
    }
    #pragma unroll
    for (int off = 32; off; off >>= 1) {
      float m2 = __shfl_xor(m, off);
      float s2 = __shfl_xor(s, off);
      float Mx = fmaxf(m, m2);
      s = s * __expf(m - Mx) + s2 * __expf(m2 - Mx);
      m = Mx;
    }
    float inv_den = 1.f / (s + 1e-16f);
    for (int c0 = rs; c0 < re; c0 += 64) {
      int ccnt = min(64, re - c0);
      int srcA = 0;
      float w = 0.f;
      if (lane < ccnt) {
        srcA = csr_src[c0 + lane];
        w = __expf(leaky02(al_s[srcA] + ald) - m) * inv_den;
      }
#ifdef HAVE_FDOT2
      float wn2 = __shfl_xor(w, 1);
      float we = (lane & 1) ? wn2 : w;
      float wo = (lane & 1) ? w : wn2;
      unsigned pkw = (unsigned)f2h(we) | ((unsigned)f2h(wo) << 16);
      passB(srcA, pkw, ccnt);
#else
      passB(srcA, w, ccnt);
#endif
    }
  }

  float o0 = eluf(acc0 + bias[lane * 2 + 0]);
  float o1 = eluf(acc1 + bias[lane * 2 + 1]);
  unsigned o = (unsigned)f2h(o0) | ((unsigned)f2h(o1) << 16);
  *(unsigned*)&out[(size_t)n * HC + lane * 2] = o;
}

// ---------- 7. global max pool (segmented over sorted batch) ----------
static __device__ __forceinline__ unsigned enc_f(float f)
{
  unsigned u = __float_as_uint(f);
  return (u & 0x80000000u) ? ~u : (u | 0x80000000u);
}
static __device__ __forceinline__ float dec_f(unsigned u)
{
  return (u & 0x80000000u) ? __uint_as_float(u & 0x7fffffffu) : __uint_as_float(~u);
}

#define PNPB 128   // nodes per pool block
__global__ __launch_bounds__(256)
void pool_seg_kernel(const unsigned short* __restrict__ x, const int* __restrict__ batch,
                     unsigned* __restrict__ pool, int N)
{
  int cp = (threadIdx.x & 63) * 2;     // channel pair
  int g  = threadIdx.x >> 6;           // node group 0..3
  int n0 = blockIdx.x * PNPB;
  int n1 = min(n0 + PNPB, N);
  int curb = -1;
  float m0 = 0.f, m1 = 0.f;
  for (int n = n0 + g; n < n1; n += 4) {
    int bg = batch[n];
    ushort2 v = *(const ushort2*)&x[(size_t)n * HC + cp];
    float v0 = h2f(v.x), v1 = h2f(v.y);
    if (bg != curb) {
      if (curb >= 0) {
        atomicMax(&pool[curb * HC + cp],     enc_f(m0));
        atomicMax(&pool[curb * HC + cp + 1], enc_f(m1));
      }
      curb = bg; m0 = v0; m1 = v1;
    } else {
      m0 = fmaxf(m0, v0);
      m1 = fmaxf(m1, v1);
    }
  }
  if (curb >= 0) {
    atomicMax(&pool[curb * HC + cp],     enc_f(m0));
    atomicMax(&pool[curb * HC + cp + 1], enc_f(m1));
  }
}

__global__ void pool_final_kernel(const unsigned* __restrict__ pool, float* __restrict__ out, int n)
{
  int i = blockIdx.x * blockDim.x + threadIdx.x;
  if (i < n) out[i] = dec_f(pool[i]);
}

// ---------- launch ----------
extern "C" void kernel_launch(void* const* d_in, const int* in_sizes, int n_in,
                              void* d_out, int out_size, void* d_ws, size_t ws_size,
                              hipStream_t stream)
{
  const float* x_scalar = (const float*)d_in[0];
  const int* i0 = (const int*)d_in[1];
  const int* i1 = (const int*)d_in[2];
  const int* i2 = (const int*)d_in[3];
  const int* i3 = (const int*)d_in[4];
  const int* i4 = (const int*)d_in[5];
  const int* ei = (const int*)d_in[6];
  const int* batch = (const int*)d_in[7];
  const float* e0 = (const float*)d_in[8];
  const float* e1 = (const float*)d_in[9];
  const float* e2 = (const float*)d_in[10];
  const float* e3 = (const float*)d_in[11];
  const float* e4 = (const float*)d_in[12];
  const float* ln_g = (const float*)d_in[13];
  const float* ln_b = (const float*)d_in[14];
  const float* W1 = (const float*)d_in[15];
  const float* as1 = (const float*)d_in[16];
  const float* ad1 = (const float*)d_in[17];
  const float* b1 = (const float*)d_in[18];
  const float* W2 = (const float*)d_in[19];
  const float* as2 = (const float*)d_in[20];
  const float* ad2 = (const float*)d_in[21];
  const float* b2 = (const float*)d_in[22];

  const int N  = in_sizes[0] / SF;
  const int E  = in_sizes[6] / 2;
  const int Et = E + N;
  const int Bg = out_size / HC;
  const int MT64 = (N + 63) / 64;

  char* w = (char*)d_ws;
  auto alloc = [&](size_t bytes) -> char* {
    char* p = w;
    w += (bytes + 255) & ~(size_t)255;
    return p;
  };
  unsigned short* featsb = (unsigned short*)alloc((size_t)N * KP1 * 2);
  unsigned short* G      = (unsigned short*)alloc((size_t)4 * N * KP1 * 2);
  unsigned short* X2b    = (unsigned short*)alloc((size_t)N * 512 * 2);
  unsigned short* H2b    = (unsigned short*)alloc((size_t)N * HC * 2);
  unsigned short* X3b    = (unsigned short*)alloc((size_t)N * HC * 2);
  unsigned short* W1t    = (unsigned short*)alloc((size_t)512 * KP1 * 2);
  unsigned short* W2t    = (unsigned short*)alloc((size_t)HC * 512 * 2);
  float* vs      = (float*)alloc((size_t)KP1 * 4 * 4);
  float* vd      = (float*)alloc((size_t)KP1 * 4 * 4);
  float* als1    = (float*)alloc((size_t)N * 4 * 4);
  float* ald1    = (float*)alloc((size_t)N * 4 * 4);
  float* als2    = (float*)alloc((size_t)N * 4);
  float* ald2    = (float*)alloc((size_t)N * 4);
  int*   deg     = (int*)alloc((size_t)N * 4);
  int*   rowptr  = (int*)alloc((size_t)(N + 1) * 4);
  int*   fill    = (int*)alloc((size_t)N * 4);
  int*   csr_src = (int*)alloc((size_t)Et * 4);
  unsigned* pool = (unsigned*)alloc((size_t)Bg * HC * 4);

  // combined prep: W packs, vs/vd, deg+als2/ald2 zero, pool init (one launch)
  {
    int nb1 = (512 * KP1 + 255) / 256;
    int nb2 = (HC * 512 + 255) / 256;
    int nb3 = (N + 255) / 256;
    int nb4 = (Bg * HC + 255) / 256;
    prep_combined_kernel<<<nb1 + nb2 + nb3 + nb4 + DIN, 256, 0, stream>>>(
        W1, W2, W1t, W2t, as1, ad1, vs, vd, deg, pool, als2, ald2, N, Bg * HC);
  }

  // features + LN + fused layer-1 logits + fused degree count
  {
    int nodeBlocks  = (N + 3) / 4;
    int countBlocks = (Et + 255) / 256;
    feat_ln_kernel<<<nodeBlocks + countBlocks, 256, 0, stream>>>(
        x_scalar, i0, i1, i2, i3, i4, e0, e1, e2, e3, e4, ln_g, ln_b,
        (const float4*)vs, (const float4*)vd, featsb, als1, ald1,
        ei, E, deg, nodeBlocks, N);
  }

  // CSR scan + scatter
  scan_kernel<<<1, 1024, 0, stream>>>(deg, rowptr, fill, N);
  scatter_kernel<<<(Et + 255) / 256, 256, 0, stream>>>(ei, E, N, fill, csr_src);

  // layer 1: aggregate feats, then per-head GEMM (+b1, ELU); 64x64 dbuf tiles
  agg_feat_kernel<<<(N + 3) / 4, 256, 0, stream>>>(featsb, (const float4*)als1,
                                                   (const float4*)ald1,
                                                   rowptr, csr_src, G, N);
  gemm64_kernel<KP1, 1, 0><<<dim3(2, MT64, 4), 256, 0, stream>>>(
      G, W1t, X2b, N, 512, (size_t)N * KP1, (size_t)HC * KP1, HC, b1,
      nullptr, nullptr, nullptr, nullptr);

  // layer 2: GEMM with fused logits (atomicAdd), then aggregate (+b2, ELU)
  gemm64_kernel<512, 0, 1><<<dim3(2, MT64, 1), 256, 0, stream>>>(
      X2b, W2t, H2b, N, HC, 0, 0, 0, nullptr,
      as2, ad2, als2, ald2);
  agg_h2_kernel<<<(N + 3) / 4, 256, 0, stream>>>(H2b, als2, ald2, rowptr, csr_src, b2, X3b, N);

  // pool
  pool_seg_kernel<<<(N + PNPB - 1) / PNPB, 256, 0, stream>>>(X3b, batch, pool, N);
  pool_final_kernel<<<(Bg * HC + 255) / 256, 256, 0, stream>>>(pool, (float*)d_out, Bg * HC);
}